// Round 2
// baseline (11029.560 us; speedup 1.0000x reference)
//
#include <hip/hip_runtime.h>

// DecoupleModel: 3x GIN-style MP layers (d=128) + injected MLP folded to
//   z0  = relu( relu(h)@fcW0 + fcb0 + h@pW0 + pb0 )
//   out = relu(z0)@(fcW1@outW) + h@(pW1@outW) + ((fcb1+pb1)@outW + outb)
// z0 is never materialized: fused_out_kernel computes it chunk-wise in LDS.
// ws usage (N=100000): norm 0.4MB + 3x51.2MB h ping-pong + 0.2MB Wc ~= 147MiB

constexpr float SQRT2   = 1.41421356237309515f;
constexpr float ONE_EPS = 1.0f + SQRT2;          // (1 + eps)
constexpr float RS      = 0.08838834764831845f;  // 1/sqrt(128)

__global__ void init_norm_kernel(float* __restrict__ norm, int n) {
  int i = blockIdx.x * blockDim.x + threadIdx.x;
  if (i < n) norm[i] = 1.0f + SQRT2;   // 1 + eps + deg(=0 so far)
}

__global__ void deg_kernel(float* __restrict__ norm, const int* __restrict__ ei, int E) {
  int e = blockIdx.x * blockDim.x + threadIdx.x;
  if (e < E) atomicAdd(&norm[ei[E + e]], 1.0f);  // row 1 = source
}

// Wc1[512x64]=fcW1@outW ; Wc2[128x64]=pW1@outW ; bc[64]=(fcb1+pb1)@outW+outb
__global__ void combine_kernel(const float* __restrict__ fcW1, const float* __restrict__ fcb1,
                               const float* __restrict__ pW1,  const float* __restrict__ pb1,
                               const float* __restrict__ outW, const float* __restrict__ outb,
                               float* __restrict__ Wc1, float* __restrict__ Wc2,
                               float* __restrict__ bc) {
  int gid = blockIdx.x * blockDim.x + threadIdx.x;
  if (gid < 512 * 64) {
    int k = gid >> 6, j = gid & 63;
    float s = 0.f;
    for (int m = 0; m < 512; ++m) s = fmaf(fcW1[k * 512 + m], outW[m * 64 + j], s);
    Wc1[gid] = s;
  } else if (gid < 512 * 64 + 128 * 64) {
    int t = gid - 512 * 64, k = t >> 6, j = t & 63;
    float s = 0.f;
    for (int m = 0; m < 512; ++m) s = fmaf(pW1[k * 512 + m], outW[m * 64 + j], s);
    Wc2[t] = s;
  } else if (gid < 512 * 64 + 128 * 64 + 64) {
    int j = gid - (512 * 64 + 128 * 64);
    float s = outb[j];
    for (int m = 0; m < 512; ++m) s = fmaf(fcb1[m] + pb1[m], outW[m * 64 + j], s);
    bc[j] = s;
  }
}

// h2 = relu(A@W + b) * RS / norm[row];  hout = (1+eps)*h2   (scatter-dest init)
__global__ __launch_bounds__(256) void mp_gemm_kernel(
    const float* __restrict__ A, const float* __restrict__ W,
    const float* __restrict__ bias, const float* __restrict__ norm,
    float* __restrict__ h2, float* __restrict__ hout, int nrows)
{
  __shared__ __attribute__((aligned(16))) float As[16][68];  // [k][m]
  __shared__ __attribute__((aligned(16))) float Bs[16][64];  // [k][n]
  const int tid = threadIdx.x;
  const int tx = tid & 15, ty = tid >> 4;
  const int row0 = blockIdx.x * 64;
  const int col0 = blockIdx.y * 64;
  float acc[4][4] = {};
  const int arow = row0 + (tid >> 2);
  const int ak   = (tid & 3) * 4;
  const int brow = tid >> 4;
  const int bcol = (tid & 15) * 4;

  for (int k0 = 0; k0 < 128; k0 += 16) {
    float4 av = make_float4(0.f, 0.f, 0.f, 0.f);
    if (arow < nrows) av = *(const float4*)(A + (size_t)arow * 128 + k0 + ak);
    As[ak + 0][tid >> 2] = av.x;
    As[ak + 1][tid >> 2] = av.y;
    As[ak + 2][tid >> 2] = av.z;
    As[ak + 3][tid >> 2] = av.w;
    *(float4*)&Bs[brow][bcol] = *(const float4*)(W + (size_t)(k0 + brow) * 128 + col0 + bcol);
    __syncthreads();
#pragma unroll
    for (int k = 0; k < 16; ++k) {
      const float4 a = *(const float4*)&As[k][ty * 4];
      const float4 b = *(const float4*)&Bs[k][tx * 4];
      const float ar[4] = {a.x, a.y, a.z, a.w};
      const float br[4] = {b.x, b.y, b.z, b.w};
#pragma unroll
      for (int i = 0; i < 4; ++i)
#pragma unroll
        for (int j = 0; j < 4; ++j)
          acc[i][j] = fmaf(ar[i], br[j], acc[i][j]);
    }
    __syncthreads();
  }
#pragma unroll
  for (int i = 0; i < 4; ++i) {
    const int r = row0 + ty * 4 + i;
    if (r < nrows) {
      const float sc = RS / norm[r];
      const int c = col0 + tx * 4;
      float4 v;
      v.x = fmaxf(acc[i][0] + bias[c + 0], 0.f) * sc;
      v.y = fmaxf(acc[i][1] + bias[c + 1], 0.f) * sc;
      v.z = fmaxf(acc[i][2] + bias[c + 2], 0.f) * sc;
      v.w = fmaxf(acc[i][3] + bias[c + 3], 0.f) * sc;
      *(float4*)(h2 + (size_t)r * 128 + c) = v;
      float4 w = make_float4(v.x * ONE_EPS, v.y * ONE_EPS, v.z * ONE_EPS, v.w * ONE_EPS);
      *(float4*)(hout + (size_t)r * 128 + c) = w;
    }
  }
}

// out[tgt] += h2[src]  (Ah) ; out pre-initialized to (1+eps)*h2 by mp_gemm
__global__ __launch_bounds__(256) void scatter_kernel(
    const float* __restrict__ h2, float* __restrict__ out,
    const int* __restrict__ ei, int E)
{
  long long gid = (long long)blockIdx.x * blockDim.x + threadIdx.x;
  int e = (int)(gid >> 5);
  int q = ((int)gid & 31) * 4;
  if (e < E) {
    const int dst = ei[e];           // row 0 = target
    const int src = ei[E + e];       // row 1 = source
    const float4 v = *(const float4*)(h2 + (size_t)src * 128 + q);
    float* o = out + (size_t)dst * 128 + q;
    atomicAdd(o + 0, v.x);
    atomicAdd(o + 1, v.y);
    atomicAdd(o + 2, v.z);
    atomicAdd(o + 3, v.w);
  }
}

// out = relu( relu(h)@fcW0 + fcb0 + h@pW0 + pb0 ) @ Wc1 + h@Wc2 + bc
// One block = 64 rows. z0 computed chunk-wise (8 x 64 cols) entirely in LDS.
__global__ __launch_bounds__(256) void fused_out_kernel(
    const float* __restrict__ h, const float* __restrict__ fcW0,
    const float* __restrict__ pW0, const float* __restrict__ fcb0,
    const float* __restrict__ pb0, const float* __restrict__ Wc1,
    const float* __restrict__ Wc2, const float* __restrict__ bc,
    float* __restrict__ out, int nrows)
{
  __shared__ __attribute__((aligned(16))) float As[128][68];  // h tile, [k][m]
  __shared__ __attribute__((aligned(16))) float Zs[64][68];   // z chunk, [kk][m]
  __shared__ __attribute__((aligned(16))) float B0s[16][64];
  __shared__ __attribute__((aligned(16))) float B1s[16][64];
  const int tid = threadIdx.x;
  const int tx = tid & 15, ty = tid >> 4;
  const int row0 = blockIdx.x * 64;
  const int brow = tid >> 4;          // 0..15
  const int bcol = (tid & 15) * 4;

  // stage full 64x128 h tile once: As[k][m] (transposed)
  {
    const int m = tid >> 2;           // 0..63
    const int r = row0 + m;
    const int kb = (tid & 3) * 4;     // 0,4,8,12
#pragma unroll
    for (int t = 0; t < 8; ++t) {
      const int k = kb + t * 16;
      float4 v = make_float4(0.f, 0.f, 0.f, 0.f);
      if (r < nrows) v = *(const float4*)(h + (size_t)r * 128 + k);
      As[k + 0][m] = v.x;
      As[k + 1][m] = v.y;
      As[k + 2][m] = v.z;
      As[k + 3][m] = v.w;
    }
  }
  __syncthreads();

  float oacc[4][4] = {};

  for (int c0 = 0; c0 < 512; c0 += 64) {
    // ---- phase 1: z chunk [64 rows x 64 cols] = relu(h)@fcW0 + h@pW0 (cols c0..c0+63)
    float zacc[4][4] = {};
    for (int k0 = 0; k0 < 128; k0 += 16) {
      *(float4*)&B0s[brow][bcol] = *(const float4*)(fcW0 + (size_t)(k0 + brow) * 512 + c0 + bcol);
      *(float4*)&B1s[brow][bcol] = *(const float4*)(pW0  + (size_t)(k0 + brow) * 512 + c0 + bcol);
      __syncthreads();
#pragma unroll
      for (int k = 0; k < 16; ++k) {
        const float4 a  = *(const float4*)&As[k0 + k][ty * 4];
        const float4 b0 = *(const float4*)&B0s[k][tx * 4];
        const float4 b1 = *(const float4*)&B1s[k][tx * 4];
        const float ar[4] = {a.x, a.y, a.z, a.w};
        const float rr[4] = {fmaxf(a.x, 0.f), fmaxf(a.y, 0.f), fmaxf(a.z, 0.f), fmaxf(a.w, 0.f)};
        const float b0r[4] = {b0.x, b0.y, b0.z, b0.w};
        const float b1r[4] = {b1.x, b1.y, b1.z, b1.w};
#pragma unroll
        for (int i = 0; i < 4; ++i)
#pragma unroll
          for (int j = 0; j < 4; ++j)
            zacc[i][j] = fmaf(rr[i], b0r[j], fmaf(ar[i], b1r[j], zacc[i][j]));
      }
      __syncthreads();
    }
    // write relu(z + bias) into Zs[cc][m]  (cc = col within chunk -> k of phase 2)
#pragma unroll
    for (int i = 0; i < 4; ++i)
#pragma unroll
      for (int j = 0; j < 4; ++j) {
        const int cc = tx * 4 + j;
        const float b = fcb0[c0 + cc] + pb0[c0 + cc];
        Zs[cc][ty * 4 + i] = fmaxf(zacc[i][j] + b, 0.f);
      }
    __syncthreads();
    // ---- phase 2: oacc += Zs(64-K) @ Wc1[c0:c0+64, :]
    for (int kk0 = 0; kk0 < 64; kk0 += 16) {
      *(float4*)&B0s[brow][bcol] = *(const float4*)(Wc1 + (size_t)(c0 + kk0 + brow) * 64 + bcol);
      __syncthreads();
#pragma unroll
      for (int k = 0; k < 16; ++k) {
        const float4 a = *(const float4*)&Zs[kk0 + k][ty * 4];
        const float4 b = *(const float4*)&B0s[k][tx * 4];
        const float ar[4] = {a.x, a.y, a.z, a.w};
        const float br[4] = {b.x, b.y, b.z, b.w};
#pragma unroll
        for (int i = 0; i < 4; ++i)
#pragma unroll
          for (int j = 0; j < 4; ++j)
            oacc[i][j] = fmaf(ar[i], br[j], oacc[i][j]);
      }
      __syncthreads();
    }
  }

  // ---- phase 3: oacc += h(128-K) @ Wc2
  for (int k0 = 0; k0 < 128; k0 += 16) {
    *(float4*)&B0s[brow][bcol] = *(const float4*)(Wc2 + (size_t)(k0 + brow) * 64 + bcol);
    __syncthreads();
#pragma unroll
    for (int k = 0; k < 16; ++k) {
      const float4 a = *(const float4*)&As[k0 + k][ty * 4];
      const float4 b = *(const float4*)&B0s[k][tx * 4];
      const float ar[4] = {a.x, a.y, a.z, a.w};
      const float br[4] = {b.x, b.y, b.z, b.w};
#pragma unroll
      for (int i = 0; i < 4; ++i)
#pragma unroll
        for (int j = 0; j < 4; ++j)
          oacc[i][j] = fmaf(ar[i], br[j], oacc[i][j]);
    }
    __syncthreads();
  }

#pragma unroll
  for (int i = 0; i < 4; ++i) {
    const int r = row0 + ty * 4 + i;
    if (r < nrows) {
      const int c = tx * 4;
      float4 v;
      v.x = oacc[i][0] + bc[c + 0];
      v.y = oacc[i][1] + bc[c + 1];
      v.z = oacc[i][2] + bc[c + 2];
      v.w = oacc[i][3] + bc[c + 3];
      *(float4*)(out + (size_t)r * 64 + c) = v;
    }
  }
}

extern "C" void kernel_launch(void* const* d_in, const int* in_sizes, int n_in,
                              void* d_out, int out_size, void* d_ws, size_t ws_size,
                              hipStream_t stream) {
  const float* x    = (const float*)d_in[0];
  const int*   ei   = (const int*)d_in[1];   // [2][E] int32
  const float* mpW0 = (const float*)d_in[2];
  const float* mpb0 = (const float*)d_in[3];
  const float* mpW1 = (const float*)d_in[4];
  const float* mpb1 = (const float*)d_in[5];
  const float* mpW2 = (const float*)d_in[6];
  const float* mpb2 = (const float*)d_in[7];
  const float* fcW0 = (const float*)d_in[8];
  const float* fcb0 = (const float*)d_in[9];
  const float* fcW1 = (const float*)d_in[10];
  const float* fcb1 = (const float*)d_in[11];
  const float* pW0  = (const float*)d_in[12];
  const float* pb0  = (const float*)d_in[13];
  const float* pW1  = (const float*)d_in[14];
  const float* pb1  = (const float*)d_in[15];
  const float* outW = (const float*)d_in[16];
  const float* outb = (const float*)d_in[17];

  const int N = in_sizes[0] / 128;
  const int E = in_sizes[1] / 2;

  char* ws = (char*)d_ws;
  size_t off = 0;
  auto alloc = [&](size_t bytes) -> char* {
    char* p = ws + off;
    off += (bytes + 255) & ~(size_t)255;
    return p;
  };
  float* norm = (float*)alloc((size_t)N * 4);
  float* buf0 = (float*)alloc((size_t)N * 128 * 4);
  float* buf1 = (float*)alloc((size_t)N * 128 * 4);
  float* buf2 = (float*)alloc((size_t)N * 128 * 4);
  float* Wc1  = (float*)alloc(512 * 64 * 4);
  float* Wc2  = (float*)alloc(128 * 64 * 4);
  float* bc   = (float*)alloc(64 * 4);
  // total ~147 MiB

  init_norm_kernel<<<(N + 255) / 256, 256, 0, stream>>>(norm, N);
  deg_kernel<<<(E + 255) / 256, 256, 0, stream>>>(norm, ei, E);
  combine_kernel<<<(512 * 64 + 128 * 64 + 64 + 255) / 256, 256, 0, stream>>>(
      fcW1, fcb1, pW1, pb1, outW, outb, Wc1, Wc2, bc);

  const int gx = (N + 63) / 64;
  const long long sthreads = (long long)E * 32;
  const int sblocks = (int)((sthreads + 255) / 256);

  // layer 0: in=x       h2=buf0  out=buf1
  mp_gemm_kernel<<<dim3(gx, 2), 256, 0, stream>>>(x, mpW0, mpb0, norm, buf0, buf1, N);
  scatter_kernel<<<sblocks, 256, 0, stream>>>(buf0, buf1, ei, E);
  // layer 1: in=buf1    h2=buf0  out=buf2
  mp_gemm_kernel<<<dim3(gx, 2), 256, 0, stream>>>(buf1, mpW1, mpb1, norm, buf0, buf2, N);
  scatter_kernel<<<sblocks, 256, 0, stream>>>(buf0, buf2, ei, E);
  // layer 2: in=buf2    h2=buf0  out=buf1   -> h_final = buf1
  mp_gemm_kernel<<<dim3(gx, 2), 256, 0, stream>>>(buf2, mpW2, mpb2, norm, buf0, buf1, N);
  scatter_kernel<<<sblocks, 256, 0, stream>>>(buf0, buf1, ei, E);

  fused_out_kernel<<<dim3(gx, 1), 256, 0, stream>>>(
      buf1, fcW0, pW0, fcb0, pb0, Wc1, Wc2, bc, (float*)d_out, N);
}

// Round 3
// 1805.875 us; speedup vs baseline: 6.1076x; 6.1076x over previous
//
#include <hip/hip_runtime.h>

// DecoupleModel: 3x GIN-style MP layers (d=128) + injected MLP folded to
//   z0  = relu( relu(h)@fcW0 + fcb0 + h@pW0 + pb0 )
//   out = relu(z0)@(fcW1@outW) + h@(pW1@outW) + ((fcb1+pb1)@outW + outb)
// MP aggregation via CSR gather (one wave per target node), no fp32 atomics.
// ws: norm .4 + cnt/rowptr/cursor ~1.2 + ssrc 8 + 2x51.2 h bufs + Wc ~= 112MiB

constexpr float SQRT2   = 1.41421356237309515f;
constexpr float ONE_EPS = 1.0f + SQRT2;          // (1 + eps)
constexpr float RS      = 0.08838834764831845f;  // 1/sqrt(128)

// norm = 1+eps (deg added later); cnt = 0
__global__ void init_kernel(float* __restrict__ norm, int* __restrict__ cnt, int n) {
  int i = blockIdx.x * blockDim.x + threadIdx.x;
  if (i < n) { norm[i] = ONE_EPS; cnt[i] = 0; }
}

// cnt[target]++ (CSR histogram) ; norm[source] += 1 (degree for GIN norm)
__global__ void hist_kernel(const int* __restrict__ ei, int E,
                            int* __restrict__ cnt, float* __restrict__ norm) {
  int e = blockIdx.x * blockDim.x + threadIdx.x;
  if (e < E) {
    atomicAdd(&cnt[ei[e]], 1);         // row 0 = target
    atomicAdd(&norm[ei[E + e]], 1.0f); // row 1 = source
  }
}

// single-block exclusive scan of cnt[0..N) -> rowptr[0..N], cursor copy
__global__ __launch_bounds__(1024) void scan_kernel(
    const int* __restrict__ cnt, int* __restrict__ rowptr,
    int* __restrict__ cursor, int N) {
  __shared__ int sums[1024];
  const int t = threadIdx.x;
  const int C = (N + 1023) / 1024;
  const int lo = t * C, hi = (lo + C < N) ? lo + C : N;
  int s = 0;
  for (int i = lo; i < hi; ++i) s += cnt[i];
  sums[t] = s;
  __syncthreads();
  for (int off = 1; off < 1024; off <<= 1) {
    int v = (t >= off) ? sums[t - off] : 0;
    __syncthreads();
    sums[t] += v;
    __syncthreads();
  }
  int base = (t == 0) ? 0 : sums[t - 1];
  for (int i = lo; i < hi; ++i) {
    rowptr[i] = base; cursor[i] = base; base += cnt[i];
  }
  if (t == 1023) rowptr[N] = sums[1023];
}

// ssrc[pos] = src, grouped by target
__global__ void fill_kernel(const int* __restrict__ ei, int E,
                            int* __restrict__ cursor, int* __restrict__ ssrc) {
  int e = blockIdx.x * blockDim.x + threadIdx.x;
  if (e < E) {
    int pos = atomicAdd(&cursor[ei[e]], 1);
    ssrc[pos] = ei[E + e];
  }
}

// Wc1[512x64]=fcW1@outW ; Wc2[128x64]=pW1@outW ; bc[64]=(fcb1+pb1)@outW+outb
__global__ void combine_kernel(const float* __restrict__ fcW1, const float* __restrict__ fcb1,
                               const float* __restrict__ pW1,  const float* __restrict__ pb1,
                               const float* __restrict__ outW, const float* __restrict__ outb,
                               float* __restrict__ Wc1, float* __restrict__ Wc2,
                               float* __restrict__ bc) {
  int gid = blockIdx.x * blockDim.x + threadIdx.x;
  if (gid < 512 * 64) {
    int k = gid >> 6, j = gid & 63;
    float s = 0.f;
    for (int m = 0; m < 512; ++m) s = fmaf(fcW1[k * 512 + m], outW[m * 64 + j], s);
    Wc1[gid] = s;
  } else if (gid < 512 * 64 + 128 * 64) {
    int t = gid - 512 * 64, k = t >> 6, j = t & 63;
    float s = 0.f;
    for (int m = 0; m < 512; ++m) s = fmaf(pW1[k * 512 + m], outW[m * 64 + j], s);
    Wc2[t] = s;
  } else if (gid < 512 * 64 + 128 * 64 + 64) {
    int j = gid - (512 * 64 + 128 * 64);
    float s = outb[j];
    for (int m = 0; m < 512; ++m) s = fmaf(fcb1[m] + pb1[m], outW[m * 64 + j], s);
    bc[j] = s;
  }
}

// h2 = relu(A@W + b) * RS / norm[row]
__global__ __launch_bounds__(256) void mp_gemm_kernel(
    const float* __restrict__ A, const float* __restrict__ W,
    const float* __restrict__ bias, const float* __restrict__ norm,
    float* __restrict__ h2, int nrows)
{
  __shared__ __attribute__((aligned(16))) float As[16][68];  // [k][m]
  __shared__ __attribute__((aligned(16))) float Bs[16][64];  // [k][n]
  const int tid = threadIdx.x;
  const int tx = tid & 15, ty = tid >> 4;
  const int row0 = blockIdx.x * 64;
  const int col0 = blockIdx.y * 64;
  float acc[4][4] = {};
  const int arow = row0 + (tid >> 2);
  const int ak   = (tid & 3) * 4;
  const int brow = tid >> 4;
  const int bcol = (tid & 15) * 4;

  for (int k0 = 0; k0 < 128; k0 += 16) {
    float4 av = make_float4(0.f, 0.f, 0.f, 0.f);
    if (arow < nrows) av = *(const float4*)(A + (size_t)arow * 128 + k0 + ak);
    As[ak + 0][tid >> 2] = av.x;
    As[ak + 1][tid >> 2] = av.y;
    As[ak + 2][tid >> 2] = av.z;
    As[ak + 3][tid >> 2] = av.w;
    *(float4*)&Bs[brow][bcol] = *(const float4*)(W + (size_t)(k0 + brow) * 128 + col0 + bcol);
    __syncthreads();
#pragma unroll
    for (int k = 0; k < 16; ++k) {
      const float4 a = *(const float4*)&As[k][ty * 4];
      const float4 b = *(const float4*)&Bs[k][tx * 4];
      const float ar[4] = {a.x, a.y, a.z, a.w};
      const float br[4] = {b.x, b.y, b.z, b.w};
#pragma unroll
      for (int i = 0; i < 4; ++i)
#pragma unroll
        for (int j = 0; j < 4; ++j)
          acc[i][j] = fmaf(ar[i], br[j], acc[i][j]);
    }
    __syncthreads();
  }
#pragma unroll
  for (int i = 0; i < 4; ++i) {
    const int r = row0 + ty * 4 + i;
    if (r < nrows) {
      const float sc = RS / norm[r];
      const int c = col0 + tx * 4;
      float4 v;
      v.x = fmaxf(acc[i][0] + bias[c + 0], 0.f) * sc;
      v.y = fmaxf(acc[i][1] + bias[c + 1], 0.f) * sc;
      v.z = fmaxf(acc[i][2] + bias[c + 2], 0.f) * sc;
      v.w = fmaxf(acc[i][3] + bias[c + 3], 0.f) * sc;
      *(float4*)(h2 + (size_t)r * 128 + c) = v;
    }
  }
}

// out[t] = (1+eps)*h2[t] + sum_{e in CSR[t]} h2[src[e]]   (one wave per node)
__global__ __launch_bounds__(256) void agg_kernel(
    const float* __restrict__ h2, const int* __restrict__ rowptr,
    const int* __restrict__ ssrc, float* __restrict__ out, int N)
{
  const int wid  = (blockIdx.x * 256 + threadIdx.x) >> 6;
  const int lane = threadIdx.x & 63;
  if (wid >= N) return;
  float2 acc = *(const float2*)(h2 + (size_t)wid * 128 + lane * 2);
  acc.x *= ONE_EPS; acc.y *= ONE_EPS;
  const int beg = rowptr[wid], end = rowptr[wid + 1];
  int i = beg;
  for (; i + 1 < end; i += 2) {
    const int s0 = ssrc[i], s1 = ssrc[i + 1];
    const float2 v0 = *(const float2*)(h2 + (size_t)s0 * 128 + lane * 2);
    const float2 v1 = *(const float2*)(h2 + (size_t)s1 * 128 + lane * 2);
    acc.x += v0.x + v1.x; acc.y += v0.y + v1.y;
  }
  if (i < end) {
    const int s = ssrc[i];
    const float2 v = *(const float2*)(h2 + (size_t)s * 128 + lane * 2);
    acc.x += v.x; acc.y += v.y;
  }
  *(float2*)(out + (size_t)wid * 128 + lane * 2) = acc;
}

// out = relu( relu(h)@fcW0 + fcb0 + h@pW0 + pb0 ) @ Wc1 + h@Wc2 + bc
__global__ __launch_bounds__(256) void fused_out_kernel(
    const float* __restrict__ h, const float* __restrict__ fcW0,
    const float* __restrict__ pW0, const float* __restrict__ fcb0,
    const float* __restrict__ pb0, const float* __restrict__ Wc1,
    const float* __restrict__ Wc2, const float* __restrict__ bc,
    float* __restrict__ out, int nrows)
{
  __shared__ __attribute__((aligned(16))) float As[128][68];  // h tile, [k][m]
  __shared__ __attribute__((aligned(16))) float Zs[64][68];   // z chunk, [kk][m]
  __shared__ __attribute__((aligned(16))) float B0s[16][64];
  __shared__ __attribute__((aligned(16))) float B1s[16][64];
  const int tid = threadIdx.x;
  const int tx = tid & 15, ty = tid >> 4;
  const int row0 = blockIdx.x * 64;
  const int brow = tid >> 4;
  const int bcol = (tid & 15) * 4;

  {
    const int m = tid >> 2;
    const int r = row0 + m;
    const int kb = (tid & 3) * 4;
#pragma unroll
    for (int t = 0; t < 8; ++t) {
      const int k = kb + t * 16;
      float4 v = make_float4(0.f, 0.f, 0.f, 0.f);
      if (r < nrows) v = *(const float4*)(h + (size_t)r * 128 + k);
      As[k + 0][m] = v.x;
      As[k + 1][m] = v.y;
      As[k + 2][m] = v.z;
      As[k + 3][m] = v.w;
    }
  }
  __syncthreads();

  float oacc[4][4] = {};

  for (int c0 = 0; c0 < 512; c0 += 64) {
    float zacc[4][4] = {};
    for (int k0 = 0; k0 < 128; k0 += 16) {
      *(float4*)&B0s[brow][bcol] = *(const float4*)(fcW0 + (size_t)(k0 + brow) * 512 + c0 + bcol);
      *(float4*)&B1s[brow][bcol] = *(const float4*)(pW0  + (size_t)(k0 + brow) * 512 + c0 + bcol);
      __syncthreads();
#pragma unroll
      for (int k = 0; k < 16; ++k) {
        const float4 a  = *(const float4*)&As[k0 + k][ty * 4];
        const float4 b0 = *(const float4*)&B0s[k][tx * 4];
        const float4 b1 = *(const float4*)&B1s[k][tx * 4];
        const float ar[4] = {a.x, a.y, a.z, a.w};
        const float rr[4] = {fmaxf(a.x, 0.f), fmaxf(a.y, 0.f), fmaxf(a.z, 0.f), fmaxf(a.w, 0.f)};
        const float b0r[4] = {b0.x, b0.y, b0.z, b0.w};
        const float b1r[4] = {b1.x, b1.y, b1.z, b1.w};
#pragma unroll
        for (int i = 0; i < 4; ++i)
#pragma unroll
          for (int j = 0; j < 4; ++j)
            zacc[i][j] = fmaf(rr[i], b0r[j], fmaf(ar[i], b1r[j], zacc[i][j]));
      }
      __syncthreads();
    }
#pragma unroll
    for (int i = 0; i < 4; ++i)
#pragma unroll
      for (int j = 0; j < 4; ++j) {
        const int cc = tx * 4 + j;
        const float b = fcb0[c0 + cc] + pb0[c0 + cc];
        Zs[cc][ty * 4 + i] = fmaxf(zacc[i][j] + b, 0.f);
      }
    __syncthreads();
    for (int kk0 = 0; kk0 < 64; kk0 += 16) {
      *(float4*)&B0s[brow][bcol] = *(const float4*)(Wc1 + (size_t)(c0 + kk0 + brow) * 64 + bcol);
      __syncthreads();
#pragma unroll
      for (int k = 0; k < 16; ++k) {
        const float4 a = *(const float4*)&Zs[kk0 + k][ty * 4];
        const float4 b = *(const float4*)&B0s[k][tx * 4];
        const float ar[4] = {a.x, a.y, a.z, a.w};
        const float br[4] = {b.x, b.y, b.z, b.w};
#pragma unroll
        for (int i = 0; i < 4; ++i)
#pragma unroll
          for (int j = 0; j < 4; ++j)
            oacc[i][j] = fmaf(ar[i], br[j], oacc[i][j]);
      }
      __syncthreads();
    }
  }

  for (int k0 = 0; k0 < 128; k0 += 16) {
    *(float4*)&B0s[brow][bcol] = *(const float4*)(Wc2 + (size_t)(k0 + brow) * 64 + bcol);
    __syncthreads();
#pragma unroll
    for (int k = 0; k < 16; ++k) {
      const float4 a = *(const float4*)&As[k0 + k][ty * 4];
      const float4 b = *(const float4*)&B0s[k][tx * 4];
      const float ar[4] = {a.x, a.y, a.z, a.w};
      const float br[4] = {b.x, b.y, b.z, b.w};
#pragma unroll
      for (int i = 0; i < 4; ++i)
#pragma unroll
        for (int j = 0; j < 4; ++j)
          oacc[i][j] = fmaf(ar[i], br[j], oacc[i][j]);
    }
    __syncthreads();
  }

#pragma unroll
  for (int i = 0; i < 4; ++i) {
    const int r = row0 + ty * 4 + i;
    if (r < nrows) {
      const int c = tx * 4;
      float4 v;
      v.x = oacc[i][0] + bc[c + 0];
      v.y = oacc[i][1] + bc[c + 1];
      v.z = oacc[i][2] + bc[c + 2];
      v.w = oacc[i][3] + bc[c + 3];
      *(float4*)(out + (size_t)r * 64 + c) = v;
    }
  }
}

extern "C" void kernel_launch(void* const* d_in, const int* in_sizes, int n_in,
                              void* d_out, int out_size, void* d_ws, size_t ws_size,
                              hipStream_t stream) {
  const float* x    = (const float*)d_in[0];
  const int*   ei   = (const int*)d_in[1];   // [2][E] int32
  const float* mpW0 = (const float*)d_in[2];
  const float* mpb0 = (const float*)d_in[3];
  const float* mpW1 = (const float*)d_in[4];
  const float* mpb1 = (const float*)d_in[5];
  const float* mpW2 = (const float*)d_in[6];
  const float* mpb2 = (const float*)d_in[7];
  const float* fcW0 = (const float*)d_in[8];
  const float* fcb0 = (const float*)d_in[9];
  const float* fcW1 = (const float*)d_in[10];
  const float* fcb1 = (const float*)d_in[11];
  const float* pW0  = (const float*)d_in[12];
  const float* pb0  = (const float*)d_in[13];
  const float* pW1  = (const float*)d_in[14];
  const float* pb1  = (const float*)d_in[15];
  const float* outW = (const float*)d_in[16];
  const float* outb = (const float*)d_in[17];

  const int N = in_sizes[0] / 128;
  const int E = in_sizes[1] / 2;

  char* ws = (char*)d_ws;
  size_t off = 0;
  auto alloc = [&](size_t bytes) -> char* {
    char* p = ws + off;
    off += (bytes + 255) & ~(size_t)255;
    return p;
  };
  float* norm   = (float*)alloc((size_t)N * 4);
  int*   cnt    = (int*)alloc((size_t)N * 4);
  int*   rowptr = (int*)alloc((size_t)(N + 1) * 4);
  int*   cursor = (int*)alloc((size_t)N * 4);
  int*   ssrc   = (int*)alloc((size_t)E * 4);
  float* buf0   = (float*)alloc((size_t)N * 128 * 4);
  float* buf1   = (float*)alloc((size_t)N * 128 * 4);
  float* Wc1    = (float*)alloc(512 * 64 * 4);
  float* Wc2    = (float*)alloc(128 * 64 * 4);
  float* bc     = (float*)alloc(64 * 4);
  // total ~= 112 MiB

  init_kernel<<<(N + 255) / 256, 256, 0, stream>>>(norm, cnt, N);
  hist_kernel<<<(E + 255) / 256, 256, 0, stream>>>(ei, E, cnt, norm);
  scan_kernel<<<1, 1024, 0, stream>>>(cnt, rowptr, cursor, N);
  fill_kernel<<<(E + 255) / 256, 256, 0, stream>>>(ei, E, cursor, ssrc);
  combine_kernel<<<(512 * 64 + 128 * 64 + 64 + 255) / 256, 256, 0, stream>>>(
      fcW1, fcb1, pW1, pb1, outW, outb, Wc1, Wc2, bc);

  const int gx = (N + 63) / 64;
  const int ablocks = (N + 3) / 4;   // 4 waves/block, 1 wave/node

  // layer 0: gemm(x)->buf0 ; agg(buf0)->buf1
  mp_gemm_kernel<<<dim3(gx, 2), 256, 0, stream>>>(x, mpW0, mpb0, norm, buf0, N);
  agg_kernel<<<ablocks, 256, 0, stream>>>(buf0, rowptr, ssrc, buf1, N);
  // layer 1: gemm(buf1)->buf0 ; agg(buf0)->buf1
  mp_gemm_kernel<<<dim3(gx, 2), 256, 0, stream>>>(buf1, mpW1, mpb1, norm, buf0, N);
  agg_kernel<<<ablocks, 256, 0, stream>>>(buf0, rowptr, ssrc, buf1, N);
  // layer 2: gemm(buf1)->buf0 ; agg(buf0)->buf1   -> h_final = buf1
  mp_gemm_kernel<<<dim3(gx, 2), 256, 0, stream>>>(buf1, mpW2, mpb2, norm, buf0, N);
  agg_kernel<<<ablocks, 256, 0, stream>>>(buf0, rowptr, ssrc, buf1, N);

  fused_out_kernel<<<dim3(gx, 1), 256, 0, stream>>>(
      buf1, fcW0, pW0, fcb0, pb0, Wc1, Wc2, bc, (float*)d_out, N);
}

// Round 4
// 1284.260 us; speedup vs baseline: 8.5883x; 1.4062x over previous
//
#include <hip/hip_runtime.h>

// DecoupleModel: 3x GIN MP layers (d=128, fp32 VALU) + fused output MLP via
// split-bf16 MFMA (hi/lo, 3-product):
//   z0  = relu( relu(h)@fcW0 + bsum + h@pW0 )
//   out = z0@(fcW1@outW) + h@(pW1@outW) + bc
// fused_out_mfma: block=64 rows, 4 waves; wave w owns z-cols [w*128,w*128+128).
// A(h) in LDS frag-linear bf16 hi/lo; B mats preconverted to frag-linear bf16
// in ws (read from L2, no redundancy); per-wave z scratch in LDS; 3 barriers.

typedef __attribute__((ext_vector_type(8))) short short8;
typedef __attribute__((ext_vector_type(4))) float f32x4;

constexpr float SQRT2   = 1.41421356237309515f;
constexpr float ONE_EPS = 1.0f + SQRT2;          // (1 + eps)
constexpr float RS      = 0.08838834764831845f;  // 1/sqrt(128)

__device__ inline unsigned short bf16rne(float f) {
  unsigned int u = __float_as_uint(f);
  return (unsigned short)((u + 0x7FFFu + ((u >> 16) & 1u)) >> 16);
}
__device__ inline float bf16tof(unsigned short h) {
  return __uint_as_float(((unsigned int)h) << 16);
}

// ---------------- graph preprocessing (unchanged, known good) --------------
__global__ void init_kernel(float* __restrict__ norm, int* __restrict__ cnt, int n) {
  int i = blockIdx.x * blockDim.x + threadIdx.x;
  if (i < n) { norm[i] = ONE_EPS; cnt[i] = 0; }
}

__global__ void hist_kernel(const int* __restrict__ ei, int E,
                            int* __restrict__ cnt, float* __restrict__ norm) {
  int e = blockIdx.x * blockDim.x + threadIdx.x;
  if (e < E) {
    atomicAdd(&cnt[ei[e]], 1);         // row 0 = target
    atomicAdd(&norm[ei[E + e]], 1.0f); // row 1 = source
  }
}

__global__ __launch_bounds__(1024) void scan_kernel(
    const int* __restrict__ cnt, int* __restrict__ rowptr,
    int* __restrict__ cursor, int N) {
  __shared__ int sums[1024];
  const int t = threadIdx.x;
  const int C = (N + 1023) / 1024;
  const int lo = t * C, hi = (lo + C < N) ? lo + C : N;
  int s = 0;
  for (int i = lo; i < hi; ++i) s += cnt[i];
  sums[t] = s;
  __syncthreads();
  for (int off = 1; off < 1024; off <<= 1) {
    int v = (t >= off) ? sums[t - off] : 0;
    __syncthreads();
    sums[t] += v;
    __syncthreads();
  }
  int base = (t == 0) ? 0 : sums[t - 1];
  for (int i = lo; i < hi; ++i) {
    rowptr[i] = base; cursor[i] = base; base += cnt[i];
  }
  if (t == 1023) rowptr[N] = sums[1023];
}

__global__ void fill_kernel(const int* __restrict__ ei, int E,
                            int* __restrict__ cursor, int* __restrict__ ssrc) {
  int e = blockIdx.x * blockDim.x + threadIdx.x;
  if (e < E) {
    int pos = atomicAdd(&cursor[ei[e]], 1);
    ssrc[pos] = ei[E + e];
  }
}

// ---------------- weight folding -------------------------------------------
// Wc1[512x64]=fcW1@outW ; Wc2[128x64]=pW1@outW ; bc[64]=(fcb1+pb1)@outW+outb
__global__ void combine_kernel(const float* __restrict__ fcW1, const float* __restrict__ fcb1,
                               const float* __restrict__ pW1,  const float* __restrict__ pb1,
                               const float* __restrict__ outW, const float* __restrict__ outb,
                               float* __restrict__ Wc1, float* __restrict__ Wc2,
                               float* __restrict__ bc) {
  int gid = blockIdx.x * blockDim.x + threadIdx.x;
  if (gid < 512 * 64) {
    int k = gid >> 6, j = gid & 63;
    float s = 0.f;
    for (int m = 0; m < 512; ++m) s = fmaf(fcW1[k * 512 + m], outW[m * 64 + j], s);
    Wc1[gid] = s;
  } else if (gid < 512 * 64 + 128 * 64) {
    int t = gid - 512 * 64, k = t >> 6, j = t & 63;
    float s = 0.f;
    for (int m = 0; m < 512; ++m) s = fmaf(pW1[k * 512 + m], outW[m * 64 + j], s);
    Wc2[t] = s;
  } else if (gid < 512 * 64 + 128 * 64 + 64) {
    int j = gid - (512 * 64 + 128 * 64);
    float s = outb[j];
    for (int m = 0; m < 512; ++m) s = fmaf(fcb1[m] + pb1[m], outW[m * 64 + j], s);
    bc[j] = s;
  }
}

// Convert B matrices to MFMA-fragment-linear bf16 hi/lo.
// Layout for K x Ncols matrix, S = K/32:
//   idx = ((((t*S + s)*4 + kg)*16 + c)*8) + e ; k = s*32+kg*8+e ; n = t*16+c
// fcW0/pW0: K=128,N=512 (S=4, 65536 el). Wc1: K=512,N=64 (S=16, 32768).
// Wc2: K=128,N=64 (S=4, 8192). bsum[512]=fcb0+pb0.
__global__ void convw_kernel(const float* __restrict__ fcW0, const float* __restrict__ pW0,
                             const float* __restrict__ Wc1,  const float* __restrict__ Wc2,
                             const float* __restrict__ fcb0, const float* __restrict__ pb0,
                             unsigned short* __restrict__ FW0h, unsigned short* __restrict__ FW0l,
                             unsigned short* __restrict__ PW0h, unsigned short* __restrict__ PW0l,
                             unsigned short* __restrict__ WC1h, unsigned short* __restrict__ WC1l,
                             unsigned short* __restrict__ WC2h, unsigned short* __restrict__ WC2l,
                             float* __restrict__ bsum) {
  int gid = blockIdx.x * blockDim.x + threadIdx.x;
  if (gid < 65536) {
    int e = gid & 7, c = (gid >> 3) & 15, kg = (gid >> 7) & 3, s = (gid >> 9) & 3, t = gid >> 11;
    int k = s * 32 + kg * 8 + e, n = t * 16 + c;
    float f = fcW0[k * 512 + n];
    unsigned short h = bf16rne(f);
    FW0h[gid] = h; FW0l[gid] = bf16rne(f - bf16tof(h));
    f = pW0[k * 512 + n];
    h = bf16rne(f);
    PW0h[gid] = h; PW0l[gid] = bf16rne(f - bf16tof(h));
  } else if (gid < 65536 + 32768) {
    int g = gid - 65536;
    int e = g & 7, c = (g >> 3) & 15, kg = (g >> 7) & 3, s = (g >> 9) & 15, t = g >> 13;
    int k = s * 32 + kg * 8 + e, n = t * 16 + c;
    float f = Wc1[k * 64 + n];
    unsigned short h = bf16rne(f);
    WC1h[g] = h; WC1l[g] = bf16rne(f - bf16tof(h));
  } else if (gid < 65536 + 32768 + 8192) {
    int g = gid - 98304;
    int e = g & 7, c = (g >> 3) & 15, kg = (g >> 7) & 3, s = (g >> 9) & 3, t = (g >> 11) & 3;
    int k = s * 32 + kg * 8 + e, n = t * 16 + c;
    float f = Wc2[k * 64 + n];
    unsigned short h = bf16rne(f);
    WC2h[g] = h; WC2l[g] = bf16rne(f - bf16tof(h));
  } else if (gid < 65536 + 32768 + 8192 + 512) {
    int j = gid - 106496;
    bsum[j] = fcb0[j] + pb0[j];
  }
}

// ---------------- MP layer GEMM (fp32, unchanged) --------------------------
__global__ __launch_bounds__(256) void mp_gemm_kernel(
    const float* __restrict__ A, const float* __restrict__ W,
    const float* __restrict__ bias, const float* __restrict__ norm,
    float* __restrict__ h2, int nrows)
{
  __shared__ __attribute__((aligned(16))) float As[16][68];
  __shared__ __attribute__((aligned(16))) float Bs[16][64];
  const int tid = threadIdx.x;
  const int tx = tid & 15, ty = tid >> 4;
  const int row0 = blockIdx.x * 64;
  const int col0 = blockIdx.y * 64;
  float acc[4][4] = {};
  const int arow = row0 + (tid >> 2);
  const int ak   = (tid & 3) * 4;
  const int brow = tid >> 4;
  const int bcol = (tid & 15) * 4;

  for (int k0 = 0; k0 < 128; k0 += 16) {
    float4 av = make_float4(0.f, 0.f, 0.f, 0.f);
    if (arow < nrows) av = *(const float4*)(A + (size_t)arow * 128 + k0 + ak);
    As[ak + 0][tid >> 2] = av.x;
    As[ak + 1][tid >> 2] = av.y;
    As[ak + 2][tid >> 2] = av.z;
    As[ak + 3][tid >> 2] = av.w;
    *(float4*)&Bs[brow][bcol] = *(const float4*)(W + (size_t)(k0 + brow) * 128 + col0 + bcol);
    __syncthreads();
#pragma unroll
    for (int k = 0; k < 16; ++k) {
      const float4 a = *(const float4*)&As[k][ty * 4];
      const float4 b = *(const float4*)&Bs[k][tx * 4];
      const float ar[4] = {a.x, a.y, a.z, a.w};
      const float br[4] = {b.x, b.y, b.z, b.w};
#pragma unroll
      for (int i = 0; i < 4; ++i)
#pragma unroll
        for (int j = 0; j < 4; ++j)
          acc[i][j] = fmaf(ar[i], br[j], acc[i][j]);
    }
    __syncthreads();
  }
#pragma unroll
  for (int i = 0; i < 4; ++i) {
    const int r = row0 + ty * 4 + i;
    if (r < nrows) {
      const float sc = RS / norm[r];
      const int c = col0 + tx * 4;
      float4 v;
      v.x = fmaxf(acc[i][0] + bias[c + 0], 0.f) * sc;
      v.y = fmaxf(acc[i][1] + bias[c + 1], 0.f) * sc;
      v.z = fmaxf(acc[i][2] + bias[c + 2], 0.f) * sc;
      v.w = fmaxf(acc[i][3] + bias[c + 3], 0.f) * sc;
      *(float4*)(h2 + (size_t)r * 128 + c) = v;
    }
  }
}

// out[t] = (1+eps)*h2[t] + sum_{e in CSR[t]} h2[src[e]]   (one wave per node)
__global__ __launch_bounds__(256) void agg_kernel(
    const float* __restrict__ h2, const int* __restrict__ rowptr,
    const int* __restrict__ ssrc, float* __restrict__ out, int N)
{
  const int wid  = (blockIdx.x * 256 + threadIdx.x) >> 6;
  const int lane = threadIdx.x & 63;
  if (wid >= N) return;
  float2 acc = *(const float2*)(h2 + (size_t)wid * 128 + lane * 2);
  acc.x *= ONE_EPS; acc.y *= ONE_EPS;
  const int beg = rowptr[wid], end = rowptr[wid + 1];
  int i = beg;
  for (; i + 1 < end; i += 2) {
    const int s0 = ssrc[i], s1 = ssrc[i + 1];
    const float2 v0 = *(const float2*)(h2 + (size_t)s0 * 128 + lane * 2);
    const float2 v1 = *(const float2*)(h2 + (size_t)s1 * 128 + lane * 2);
    acc.x += v0.x + v1.x; acc.y += v0.y + v1.y;
  }
  if (i < end) {
    const int s = ssrc[i];
    const float2 v = *(const float2*)(h2 + (size_t)s * 128 + lane * 2);
    acc.x += v.x; acc.y += v.y;
  }
  *(float2*)(out + (size_t)wid * 128 + lane * 2) = acc;
}

// ---------------- fused output MLP, split-bf16 MFMA ------------------------
// LDS map (65536 B, 2 blocks/CU):
//   [0,16384)      hAhi  frag-linear [Mt4][ks4][lane64][16B]
//   [16384,32768)  hAlo
//   [32768,49152)  zh    per-wave [w4][Mt4][lane64][16B]
//   [49152,65536)  zl
//   red overlay (after barrier): [w4][row64][col64] f32
__global__ __launch_bounds__(256) void fused_out_mfma(
    const float* __restrict__ h,
    const unsigned short* __restrict__ FW0h, const unsigned short* __restrict__ FW0l,
    const unsigned short* __restrict__ PW0h, const unsigned short* __restrict__ PW0l,
    const unsigned short* __restrict__ WC1h, const unsigned short* __restrict__ WC1l,
    const unsigned short* __restrict__ WC2h, const unsigned short* __restrict__ WC2l,
    const float* __restrict__ bsum, const float* __restrict__ bc,
    float* __restrict__ out, int nrows)
{
  __shared__ __attribute__((aligned(16))) char smem[65536];
  const int tid  = threadIdx.x;
  const int row0 = blockIdx.x * 64;

  // ---- stage h tile (64x128) as frag-linear bf16 hi/lo ----
  {
    const int m = tid >> 2, q = tid & 3;
    const int gr = row0 + m;
    const int Mt = m >> 4, r16 = m & 15;
#pragma unroll
    for (int it = 0; it < 8; ++it) {
      const int k  = it * 16 + q * 4;
      float4 v = make_float4(0.f, 0.f, 0.f, 0.f);
      if (gr < nrows) v = *(const float4*)(h + (size_t)gr * 128 + k);
      const unsigned short h0 = bf16rne(v.x), h1 = bf16rne(v.y);
      const unsigned short h2 = bf16rne(v.z), h3 = bf16rne(v.w);
      const unsigned short l0 = bf16rne(v.x - bf16tof(h0));
      const unsigned short l1 = bf16rne(v.y - bf16tof(h1));
      const unsigned short l2 = bf16rne(v.z - bf16tof(h2));
      const unsigned short l3 = bf16rne(v.w - bf16tof(h3));
      const int k3 = it * 2 + (q >> 1);
      const int kg = k3 & 3, ks = k3 >> 2;
      const int eb = (q & 1) * 8;          // e*2 bytes
      const int fb = ((Mt * 4 + ks) * 64 + kg * 16 + r16) * 16 + eb;
      *(uint2*)(smem + fb) =
          make_uint2((unsigned)h0 | ((unsigned)h1 << 16), (unsigned)h2 | ((unsigned)h3 << 16));
      *(uint2*)(smem + 16384 + fb) =
          make_uint2((unsigned)l0 | ((unsigned)l1 << 16), (unsigned)l2 | ((unsigned)l3 << 16));
    }
  }
  __syncthreads();

  const int w = tid >> 6, lane = tid & 63;
  union U8 { short8 s; unsigned int u[4]; };

  f32x4 oacc[4][4] = {};   // [Mt][outNt]

  // ---- z0 + phase2, per sub-chunk of 32 z-cols (wave owns z-cols w*128..+127)
  for (int sc = 0; sc < 4; ++sc) {
    f32x4 zacc[4][2] = {};
#pragma unroll
    for (int ks = 0; ks < 4; ++ks) {
      short8 w0h[2], w0l[2], p0h[2], p0l[2];
#pragma unroll
      for (int nt = 0; nt < 2; ++nt) {
        const int t = w * 8 + sc * 2 + nt;
        const size_t ofs = (size_t)(t * 4 + ks) * 512 + lane * 8;
        w0h[nt] = *(const short8*)(FW0h + ofs);
        w0l[nt] = *(const short8*)(FW0l + ofs);
        p0h[nt] = *(const short8*)(PW0h + ofs);
        p0l[nt] = *(const short8*)(PW0l + ofs);
      }
#pragma unroll
      for (int Mt = 0; Mt < 4; ++Mt) {
        const int fb = ((Mt * 4 + ks) * 64 + lane) * 16;
        U8 hh, hl, rh, rl;
        hh.s = *(const short8*)(smem + fb);
        hl.s = *(const short8*)(smem + 16384 + fb);
#pragma unroll
        for (int u = 0; u < 4; ++u) {
          unsigned int msk = ((hh.u[u] & 0x80008000u) >> 15) * 0xFFFFu;
          rh.u[u] = hh.u[u] & ~msk;
          rl.u[u] = hl.u[u] & ~msk;
        }
#pragma unroll
        for (int nt = 0; nt < 2; ++nt) {
          f32x4 a = zacc[Mt][nt];
          a = __builtin_amdgcn_mfma_f32_16x16x32_bf16(rh.s, w0h[nt], a, 0, 0, 0);
          a = __builtin_amdgcn_mfma_f32_16x16x32_bf16(rh.s, w0l[nt], a, 0, 0, 0);
          a = __builtin_amdgcn_mfma_f32_16x16x32_bf16(rl.s, w0h[nt], a, 0, 0, 0);
          a = __builtin_amdgcn_mfma_f32_16x16x32_bf16(hh.s, p0h[nt], a, 0, 0, 0);
          a = __builtin_amdgcn_mfma_f32_16x16x32_bf16(hh.s, p0l[nt], a, 0, 0, 0);
          a = __builtin_amdgcn_mfma_f32_16x16x32_bf16(hl.s, p0h[nt], a, 0, 0, 0);
          zacc[Mt][nt] = a;
        }
      }
    }
    // relu(z + bias) -> per-wave z LDS scratch (frag-linear, K=32)
    const float bs0 = bsum[w * 128 + sc * 32 + (lane & 15)];
    const float bs1 = bsum[w * 128 + sc * 32 + 16 + (lane & 15)];
#pragma unroll
    for (int Mt = 0; Mt < 4; ++Mt) {
#pragma unroll
      for (int nt = 0; nt < 2; ++nt) {
        const float bs = nt ? bs1 : bs0;
        const int kg = nt * 2 + ((lane >> 3) & 1);
        const int eb = (lane & 7) * 2;
#pragma unroll
        for (int reg = 0; reg < 4; ++reg) {
          const float zv = fmaxf(zacc[Mt][nt][reg] + bs, 0.f);
          const unsigned short zhi = bf16rne(zv);
          const unsigned short zlo = bf16rne(zv - bf16tof(zhi));
          const int r16 = (lane >> 4) * 4 + reg;
          const int fb = ((w * 4 + Mt) * 64 + kg * 16 + r16) * 16 + eb;
          *(unsigned short*)(smem + 32768 + fb) = zhi;
          *(unsigned short*)(smem + 49152 + fb) = zlo;
        }
      }
    }
    asm volatile("s_waitcnt lgkmcnt(0)" ::: "memory");
    // phase2: oacc += z(K=32 slice) @ Wc1[w*128+sc*32 .. +32, :]
    const int s2 = w * 4 + sc;
    short8 c1h[4], c1l[4];
#pragma unroll
    for (int t2 = 0; t2 < 4; ++t2) {
      const size_t ofs = (size_t)(t2 * 16 + s2) * 512 + lane * 8;
      c1h[t2] = *(const short8*)(WC1h + ofs);
      c1l[t2] = *(const short8*)(WC1l + ofs);
    }
#pragma unroll
    for (int Mt = 0; Mt < 4; ++Mt) {
      const int fb = ((w * 4 + Mt) * 64 + lane) * 16;
      short8 zh8 = *(const short8*)(smem + 32768 + fb);
      short8 zl8 = *(const short8*)(smem + 49152 + fb);
#pragma unroll
      for (int t2 = 0; t2 < 4; ++t2) {
        f32x4 a = oacc[Mt][t2];
        a = __builtin_amdgcn_mfma_f32_16x16x32_bf16(zh8, c1h[t2], a, 0, 0, 0);
        a = __builtin_amdgcn_mfma_f32_16x16x32_bf16(zh8, c1l[t2], a, 0, 0, 0);
        a = __builtin_amdgcn_mfma_f32_16x16x32_bf16(zl8, c1h[t2], a, 0, 0, 0);
        oacc[Mt][t2] = a;
      }
    }
  }

  // ---- phase3: oacc += h @ Wc2, K-step w per wave ----
  {
    short8 c2h[4], c2l[4];
#pragma unroll
    for (int t = 0; t < 4; ++t) {
      const size_t ofs = (size_t)(t * 4 + w) * 512 + lane * 8;
      c2h[t] = *(const short8*)(WC2h + ofs);
      c2l[t] = *(const short8*)(WC2l + ofs);
    }
#pragma unroll
    for (int Mt = 0; Mt < 4; ++Mt) {
      const int fb = ((Mt * 4 + w) * 64 + lane) * 16;
      short8 hh = *(const short8*)(smem + fb);
      short8 hl = *(const short8*)(smem + 16384 + fb);
#pragma unroll
      for (int t = 0; t < 4; ++t) {
        f32x4 a = oacc[Mt][t];
        a = __builtin_amdgcn_mfma_f32_16x16x32_bf16(hh, c2h[t], a, 0, 0, 0);
        a = __builtin_amdgcn_mfma_f32_16x16x32_bf16(hh, c2l[t], a, 0, 0, 0);
        a = __builtin_amdgcn_mfma_f32_16x16x32_bf16(hl, c2h[t], a, 0, 0, 0);
        oacc[Mt][t] = a;
      }
    }
  }

  // ---- cross-wave reduction (overlay red[4][64][64] on smem) ----
  __syncthreads();
  float* red = (float*)smem;
#pragma unroll
  for (int Mt = 0; Mt < 4; ++Mt)
#pragma unroll
    for (int Nt = 0; Nt < 4; ++Nt)
#pragma unroll
      for (int reg = 0; reg < 4; ++reg) {
        const int row = Mt * 16 + (lane >> 4) * 4 + reg;
        const int col = Nt * 16 + (lane & 15);
        red[(w * 64 + row) * 64 + col] = oacc[Mt][Nt][reg];
      }
  __syncthreads();
  {
    const int c4 = (tid & 15) * 4;
    const int rb = tid >> 4;
    const float4 bcv = *(const float4*)(bc + c4);
#pragma unroll
    for (int rr = 0; rr < 4; ++rr) {
      const int r = rr * 16 + rb;
      const int gr = row0 + r;
      if (gr < nrows) {
        float4 s = bcv;
#pragma unroll
        for (int wv = 0; wv < 4; ++wv) {
          const float4 p = *(const float4*)&red[(wv * 64 + r) * 64 + c4];
          s.x += p.x; s.y += p.y; s.z += p.z; s.w += p.w;
        }
        *(float4*)(out + (size_t)gr * 64 + c4) = s;
      }
    }
  }
}

// ---------------------------------------------------------------------------
extern "C" void kernel_launch(void* const* d_in, const int* in_sizes, int n_in,
                              void* d_out, int out_size, void* d_ws, size_t ws_size,
                              hipStream_t stream) {
  const float* x    = (const float*)d_in[0];
  const int*   ei   = (const int*)d_in[1];   // [2][E] int32
  const float* mpW0 = (const float*)d_in[2];
  const float* mpb0 = (const float*)d_in[3];
  const float* mpW1 = (const float*)d_in[4];
  const float* mpb1 = (const float*)d_in[5];
  const float* mpW2 = (const float*)d_in[6];
  const float* mpb2 = (const float*)d_in[7];
  const float* fcW0 = (const float*)d_in[8];
  const float* fcb0 = (const float*)d_in[9];
  const float* fcW1 = (const float*)d_in[10];
  const float* fcb1 = (const float*)d_in[11];
  const float* pW0  = (const float*)d_in[12];
  const float* pb0  = (const float*)d_in[13];
  const float* pW1  = (const float*)d_in[14];
  const float* pb1  = (const float*)d_in[15];
  const float* outW = (const float*)d_in[16];
  const float* outb = (const float*)d_in[17];

  const int N = in_sizes[0] / 128;
  const int E = in_sizes[1] / 2;

  char* ws = (char*)d_ws;
  size_t off = 0;
  auto alloc = [&](size_t bytes) -> char* {
    char* p = ws + off;
    off += (bytes + 255) & ~(size_t)255;
    return p;
  };
  float* norm   = (float*)alloc((size_t)N * 4);
  int*   cnt    = (int*)alloc((size_t)N * 4);
  int*   rowptr = (int*)alloc((size_t)(N + 1) * 4);
  int*   cursor = (int*)alloc((size_t)N * 4);
  int*   ssrc   = (int*)alloc((size_t)E * 4);
  float* buf0   = (float*)alloc((size_t)N * 128 * 4);
  float* buf1   = (float*)alloc((size_t)N * 128 * 4);
  float* Wc1    = (float*)alloc(512 * 64 * 4);
  float* Wc2    = (float*)alloc(128 * 64 * 4);
  float* bc     = (float*)alloc(64 * 4);
  unsigned short* FW0h = (unsigned short*)alloc(65536 * 2);
  unsigned short* FW0l = (unsigned short*)alloc(65536 * 2);
  unsigned short* PW0h = (unsigned short*)alloc(65536 * 2);
  unsigned short* PW0l = (unsigned short*)alloc(65536 * 2);
  unsigned short* WC1h = (unsigned short*)alloc(32768 * 2);
  unsigned short* WC1l = (unsigned short*)alloc(32768 * 2);
  unsigned short* WC2h = (unsigned short*)alloc(8192 * 2);
  unsigned short* WC2l = (unsigned short*)alloc(8192 * 2);
  float* bsum   = (float*)alloc(512 * 4);
  // total ~= 113 MiB

  init_kernel<<<(N + 255) / 256, 256, 0, stream>>>(norm, cnt, N);
  hist_kernel<<<(E + 255) / 256, 256, 0, stream>>>(ei, E, cnt, norm);
  scan_kernel<<<1, 1024, 0, stream>>>(cnt, rowptr, cursor, N);
  fill_kernel<<<(E + 255) / 256, 256, 0, stream>>>(ei, E, cursor, ssrc);
  combine_kernel<<<(512 * 64 + 128 * 64 + 64 + 255) / 256, 256, 0, stream>>>(
      fcW1, fcb1, pW1, pb1, outW, outb, Wc1, Wc2, bc);
  convw_kernel<<<(65536 + 32768 + 8192 + 512 + 255) / 256, 256, 0, stream>>>(
      fcW0, pW0, Wc1, Wc2, fcb0, pb0,
      FW0h, FW0l, PW0h, PW0l, WC1h, WC1l, WC2h, WC2l, bsum);

  const int gx = (N + 63) / 64;
  const int ablocks = (N + 3) / 4;

  mp_gemm_kernel<<<dim3(gx, 2), 256, 0, stream>>>(x, mpW0, mpb0, norm, buf0, N);
  agg_kernel<<<ablocks, 256, 0, stream>>>(buf0, rowptr, ssrc, buf1, N);
  mp_gemm_kernel<<<dim3(gx, 2), 256, 0, stream>>>(buf1, mpW1, mpb1, norm, buf0, N);
  agg_kernel<<<ablocks, 256, 0, stream>>>(buf0, rowptr, ssrc, buf1, N);
  mp_gemm_kernel<<<dim3(gx, 2), 256, 0, stream>>>(buf1, mpW2, mpb2, norm, buf0, N);
  agg_kernel<<<ablocks, 256, 0, stream>>>(buf0, rowptr, ssrc, buf1, N);

  fused_out_mfma<<<gx, 256, 0, stream>>>(
      buf1, FW0h, FW0l, PW0h, PW0l, WC1h, WC1l, WC2h, WC2l, bsum, bc,
      (float*)d_out, N);
}

// Round 5
// 1028.924 us; speedup vs baseline: 10.7195x; 1.2482x over previous
//
#include <hip/hip_runtime.h>

// DecoupleModel: 3x GIN MP layers (split-bf16 MFMA) + CSR-gather aggregation
// + fused output MLP (split-bf16 MFMA):
//   z0  = relu( relu(h)@fcW0 + bsum + h@pW0 )
//   out = z0@(fcW1@outW) + h@(pW1@outW) + bc
// Split-bf16: a = ah + al (bf16 hi/lo), product ah*bh + ah*bl + al*bh ~ fp32.
// Frag-linear layout verified in R4 (absmax parity with fp32 path).

typedef __attribute__((ext_vector_type(8))) short short8;
typedef __attribute__((ext_vector_type(4))) float f32x4;

constexpr float SQRT2   = 1.41421356237309515f;
constexpr float ONE_EPS = 1.0f + SQRT2;          // (1 + eps)
constexpr float RS      = 0.08838834764831845f;  // 1/sqrt(128)

__device__ inline unsigned short bf16rne(float f) {
  unsigned int u = __float_as_uint(f);
  return (unsigned short)((u + 0x7FFFu + ((u >> 16) & 1u)) >> 16);
}
__device__ inline float bf16tof(unsigned short h) {
  return __uint_as_float(((unsigned int)h) << 16);
}

// ---------------- graph preprocessing --------------------------------------
__global__ void init_kernel(float* __restrict__ norm, int* __restrict__ cnt, int n) {
  int i = blockIdx.x * blockDim.x + threadIdx.x;
  if (i < n) { norm[i] = ONE_EPS; cnt[i] = 0; }
}

__global__ void hist_kernel(const int* __restrict__ ei, int E,
                            int* __restrict__ cnt, float* __restrict__ norm) {
  int e = blockIdx.x * blockDim.x + threadIdx.x;
  if (e < E) {
    atomicAdd(&cnt[ei[e]], 1);         // row 0 = target
    atomicAdd(&norm[ei[E + e]], 1.0f); // row 1 = source
  }
}

// 3-stage device-wide exclusive scan (1024 items / block)
__global__ __launch_bounds__(256) void scan1_kernel(
    const int* __restrict__ cnt, int* __restrict__ bsum, int N) {
  __shared__ int red[256];
  const int t = threadIdx.x;
  const int base = blockIdx.x * 1024;
  int s = 0;
#pragma unroll
  for (int j = 0; j < 4; ++j) {
    const int i = base + t + j * 256;
    if (i < N) s += cnt[i];
  }
  red[t] = s;
  __syncthreads();
  for (int o = 128; o > 0; o >>= 1) {
    if (t < o) red[t] += red[t + o];
    __syncthreads();
  }
  if (t == 0) bsum[blockIdx.x] = red[0];
}

__global__ __launch_bounds__(1024) void scan2_kernel(int* __restrict__ bsum, int nb) {
  __shared__ int sh[1024];
  const int t = threadIdx.x;
  const int v = (t < nb) ? bsum[t] : 0;
  sh[t] = v;
  __syncthreads();
  for (int o = 1; o < 1024; o <<= 1) {
    int u = (t >= o) ? sh[t - o] : 0;
    __syncthreads();
    sh[t] += u;
    __syncthreads();
  }
  if (t < nb) bsum[t] = sh[t] - v;   // exclusive
}

__global__ __launch_bounds__(256) void scan3_kernel(
    const int* __restrict__ cnt, const int* __restrict__ bofs,
    int* __restrict__ rowptr, int* __restrict__ cursor, int N) {
  __shared__ int sh[256];
  const int t = threadIdx.x;
  const int base = blockIdx.x * 1024 + t * 4;
  int c[4];
#pragma unroll
  for (int j = 0; j < 4; ++j) c[j] = (base + j < N) ? cnt[base + j] : 0;
  const int tsum = c[0] + c[1] + c[2] + c[3];
  sh[t] = tsum;
  __syncthreads();
  for (int o = 1; o < 256; o <<= 1) {
    int u = (t >= o) ? sh[t - o] : 0;
    __syncthreads();
    sh[t] += u;
    __syncthreads();
  }
  int run = bofs[blockIdx.x] + sh[t] - tsum;
#pragma unroll
  for (int j = 0; j < 4; ++j) {
    const int i = base + j;
    if (i < N) { rowptr[i] = run; cursor[i] = run; run += c[j]; }
    if (i == N - 1) rowptr[N] = run;
  }
}

__global__ void fill_kernel(const int* __restrict__ ei, int E,
                            int* __restrict__ cursor, int* __restrict__ ssrc) {
  int e = blockIdx.x * blockDim.x + threadIdx.x;
  if (e < E) {
    int pos = atomicAdd(&cursor[ei[e]], 1);
    ssrc[pos] = ei[E + e];
  }
}

// ---------------- weight folding -------------------------------------------
__global__ void combine_kernel(const float* __restrict__ fcW1, const float* __restrict__ fcb1,
                               const float* __restrict__ pW1,  const float* __restrict__ pb1,
                               const float* __restrict__ outW, const float* __restrict__ outb,
                               float* __restrict__ Wc1, float* __restrict__ Wc2,
                               float* __restrict__ bc) {
  int gid = blockIdx.x * blockDim.x + threadIdx.x;
  if (gid < 512 * 64) {
    int k = gid >> 6, j = gid & 63;
    float s = 0.f;
    for (int m = 0; m < 512; ++m) s = fmaf(fcW1[k * 512 + m], outW[m * 64 + j], s);
    Wc1[gid] = s;
  } else if (gid < 512 * 64 + 128 * 64) {
    int t = gid - 512 * 64, k = t >> 6, j = t & 63;
    float s = 0.f;
    for (int m = 0; m < 512; ++m) s = fmaf(pW1[k * 512 + m], outW[m * 64 + j], s);
    Wc2[t] = s;
  } else if (gid < 512 * 64 + 128 * 64 + 64) {
    int j = gid - (512 * 64 + 128 * 64);
    float s = outb[j];
    for (int m = 0; m < 512; ++m) s = fmaf(fcb1[m] + pb1[m], outW[m * 64 + j], s);
    bc[j] = s;
  }
}

// frag-linear hi/lo conversion: idx = ((((t*S+s)*4+kg)*16+c)*8)+e ; k=s*32+kg*8+e ; n=t*16+c
__global__ void convw_kernel(const float* __restrict__ fcW0, const float* __restrict__ pW0,
                             const float* __restrict__ Wc1,  const float* __restrict__ Wc2,
                             const float* __restrict__ fcb0, const float* __restrict__ pb0,
                             unsigned short* __restrict__ FW0h, unsigned short* __restrict__ FW0l,
                             unsigned short* __restrict__ PW0h, unsigned short* __restrict__ PW0l,
                             unsigned short* __restrict__ WC1h, unsigned short* __restrict__ WC1l,
                             unsigned short* __restrict__ WC2h, unsigned short* __restrict__ WC2l,
                             float* __restrict__ bsum) {
  int gid = blockIdx.x * blockDim.x + threadIdx.x;
  if (gid < 65536) {
    int e = gid & 7, c = (gid >> 3) & 15, kg = (gid >> 7) & 3, s = (gid >> 9) & 3, t = gid >> 11;
    int k = s * 32 + kg * 8 + e, n = t * 16 + c;
    float f = fcW0[k * 512 + n];
    unsigned short h = bf16rne(f);
    FW0h[gid] = h; FW0l[gid] = bf16rne(f - bf16tof(h));
    f = pW0[k * 512 + n];
    h = bf16rne(f);
    PW0h[gid] = h; PW0l[gid] = bf16rne(f - bf16tof(h));
  } else if (gid < 65536 + 32768) {
    int g = gid - 65536;
    int e = g & 7, c = (g >> 3) & 15, kg = (g >> 7) & 3, s = (g >> 9) & 15, t = g >> 13;
    int k = s * 32 + kg * 8 + e, n = t * 16 + c;
    float f = Wc1[k * 64 + n];
    unsigned short h = bf16rne(f);
    WC1h[g] = h; WC1l[g] = bf16rne(f - bf16tof(h));
  } else if (gid < 65536 + 32768 + 8192) {
    int g = gid - 98304;
    int e = g & 7, c = (g >> 3) & 15, kg = (g >> 7) & 3, s = (g >> 9) & 3, t = (g >> 11) & 3;
    int k = s * 32 + kg * 8 + e, n = t * 16 + c;
    float f = Wc2[k * 64 + n];
    unsigned short h = bf16rne(f);
    WC2h[g] = h; WC2l[g] = bf16rne(f - bf16tof(h));
  } else if (gid < 65536 + 32768 + 8192 + 512) {
    int j = gid - 106496;
    bsum[j] = fcb0[j] + pb0[j];
  }
}

// mpW0/1/2 (128x128) -> frag-linear hi/lo (S=4, t<8)
__global__ void convmp_kernel(const float* __restrict__ W0, const float* __restrict__ W1,
                              const float* __restrict__ W2,
                              unsigned short* __restrict__ M0h, unsigned short* __restrict__ M0l,
                              unsigned short* __restrict__ M1h, unsigned short* __restrict__ M1l,
                              unsigned short* __restrict__ M2h, unsigned short* __restrict__ M2l) {
  int gid = blockIdx.x * blockDim.x + threadIdx.x;
  if (gid >= 3 * 16384) return;
  const int m = gid >> 14, g = gid & 16383;
  int e = g & 7, c = (g >> 3) & 15, kg = (g >> 7) & 3, s = (g >> 9) & 3, t = g >> 11;
  int k = s * 32 + kg * 8 + e, n = t * 16 + c;
  const float* W = (m == 0) ? W0 : (m == 1) ? W1 : W2;
  unsigned short* Mh = (m == 0) ? M0h : (m == 1) ? M1h : M2h;
  unsigned short* Ml = (m == 0) ? M0l : (m == 1) ? M1l : M2l;
  float f = W[k * 128 + n];
  unsigned short h = bf16rne(f);
  Mh[g] = h; Ml[g] = bf16rne(f - bf16tof(h));
}

// ---------------- MP layer GEMM, split-bf16 MFMA ---------------------------
// h2 = relu(A@W + b) * RS / norm[row]. 64 rows/block, 4 waves; wave w owns
// cols [w*32, w*32+32). LDS: [0,16K) Ahi, [16K,32K) Alo; after barrier
// overlay out[64][132] f32 (33792 B) for coalesced epilogue.
__global__ __launch_bounds__(256) void mp_gemm_mfma(
    const float* __restrict__ A,
    const unsigned short* __restrict__ Wh, const unsigned short* __restrict__ Wl,
    const float* __restrict__ bias, const float* __restrict__ norm,
    float* __restrict__ h2, int nrows)
{
  __shared__ __attribute__((aligned(16))) char smem[33792];
  const int tid  = threadIdx.x;
  const int row0 = blockIdx.x * 64;

  // stage A tile (64x128) as frag-linear bf16 hi/lo (verified R4 pattern)
  {
    const int m = tid >> 2, q = tid & 3;
    const int gr = row0 + m;
    const int Mt = m >> 4, r16 = m & 15;
#pragma unroll
    for (int it = 0; it < 8; ++it) {
      const int k = it * 16 + q * 4;
      float4 v = make_float4(0.f, 0.f, 0.f, 0.f);
      if (gr < nrows) v = *(const float4*)(A + (size_t)gr * 128 + k);
      const unsigned short h0 = bf16rne(v.x), h1 = bf16rne(v.y);
      const unsigned short h2v = bf16rne(v.z), h3 = bf16rne(v.w);
      const unsigned short l0 = bf16rne(v.x - bf16tof(h0));
      const unsigned short l1 = bf16rne(v.y - bf16tof(h1));
      const unsigned short l2 = bf16rne(v.z - bf16tof(h2v));
      const unsigned short l3 = bf16rne(v.w - bf16tof(h3));
      const int k3 = it * 2 + (q >> 1);
      const int kg = k3 & 3, ks = k3 >> 2;
      const int eb = (q & 1) * 8;
      const int fb = ((Mt * 4 + ks) * 64 + kg * 16 + r16) * 16 + eb;
      *(uint2*)(smem + fb) =
          make_uint2((unsigned)h0 | ((unsigned)h1 << 16), (unsigned)h2v | ((unsigned)h3 << 16));
      *(uint2*)(smem + 16384 + fb) =
          make_uint2((unsigned)l0 | ((unsigned)l1 << 16), (unsigned)l2 | ((unsigned)l3 << 16));
    }
  }
  __syncthreads();

  const int w = tid >> 6, lane = tid & 63;
  f32x4 acc[4][2] = {};   // [Mt][nt]

#pragma unroll
  for (int ks = 0; ks < 4; ++ks) {
    short8 bh[2], bl[2];
#pragma unroll
    for (int nt = 0; nt < 2; ++nt) {
      const int t = w * 2 + nt;
      const size_t ofs = (size_t)(t * 4 + ks) * 512 + lane * 8;
      bh[nt] = *(const short8*)(Wh + ofs);
      bl[nt] = *(const short8*)(Wl + ofs);
    }
#pragma unroll
    for (int Mt = 0; Mt < 4; ++Mt) {
      const int fb = ((Mt * 4 + ks) * 64 + lane) * 16;
      short8 hh = *(const short8*)(smem + fb);
      short8 hl = *(const short8*)(smem + 16384 + fb);
#pragma unroll
      for (int nt = 0; nt < 2; ++nt) {
        f32x4 a = acc[Mt][nt];
        a = __builtin_amdgcn_mfma_f32_16x16x32_bf16(hh, bh[nt], a, 0, 0, 0);
        a = __builtin_amdgcn_mfma_f32_16x16x32_bf16(hh, bl[nt], a, 0, 0, 0);
        a = __builtin_amdgcn_mfma_f32_16x16x32_bf16(hl, bh[nt], a, 0, 0, 0);
        acc[Mt][nt] = a;
      }
    }
  }

  // overlay raw acc into LDS out[64][132] f32, then coalesced epilogue
  __syncthreads();
  float* ob = (float*)smem;
#pragma unroll
  for (int Mt = 0; Mt < 4; ++Mt)
#pragma unroll
    for (int nt = 0; nt < 2; ++nt) {
      const int col = w * 32 + nt * 16 + (lane & 15);
#pragma unroll
      for (int reg = 0; reg < 4; ++reg) {
        const int row = Mt * 16 + (lane >> 4) * 4 + reg;
        ob[row * 132 + col] = acc[Mt][nt][reg];
      }
    }
  __syncthreads();
  {
    const int r = tid >> 2;
    const int gr = row0 + r;
    if (gr < nrows) {
      const float sc = RS / norm[gr];
      const int cb = (tid & 3) * 32;
#pragma unroll
      for (int j = 0; j < 32; j += 4) {
        float4 v = *(const float4*)&ob[r * 132 + cb + j];
        const float4 b = *(const float4*)&bias[cb + j];
        v.x = fmaxf(v.x + b.x, 0.f) * sc;
        v.y = fmaxf(v.y + b.y, 0.f) * sc;
        v.z = fmaxf(v.z + b.z, 0.f) * sc;
        v.w = fmaxf(v.w + b.w, 0.f) * sc;
        *(float4*)(h2 + (size_t)gr * 128 + cb + j) = v;
      }
    }
  }
}

// out[t] = (1+eps)*h2[t] + sum_{e in CSR[t]} h2[src[e]]   (one wave per node)
__global__ __launch_bounds__(256) void agg_kernel(
    const float* __restrict__ h2, const int* __restrict__ rowptr,
    const int* __restrict__ ssrc, float* __restrict__ out, int N)
{
  const int wid  = (blockIdx.x * 256 + threadIdx.x) >> 6;
  const int lane = threadIdx.x & 63;
  if (wid >= N) return;
  float2 acc = *(const float2*)(h2 + (size_t)wid * 128 + lane * 2);
  acc.x *= ONE_EPS; acc.y *= ONE_EPS;
  const int beg = rowptr[wid], end = rowptr[wid + 1];
  int i = beg;
  for (; i + 1 < end; i += 2) {
    const int s0 = ssrc[i], s1 = ssrc[i + 1];
    const float2 v0 = *(const float2*)(h2 + (size_t)s0 * 128 + lane * 2);
    const float2 v1 = *(const float2*)(h2 + (size_t)s1 * 128 + lane * 2);
    acc.x += v0.x + v1.x; acc.y += v0.y + v1.y;
  }
  if (i < end) {
    const int s = ssrc[i];
    const float2 v = *(const float2*)(h2 + (size_t)s * 128 + lane * 2);
    acc.x += v.x; acc.y += v.y;
  }
  *(float2*)(out + (size_t)wid * 128 + lane * 2) = acc;
}

// ---------------- fused output MLP, split-bf16 MFMA (verified R4) ----------
__global__ __launch_bounds__(256) void fused_out_mfma(
    const float* __restrict__ h,
    const unsigned short* __restrict__ FW0h, const unsigned short* __restrict__ FW0l,
    const unsigned short* __restrict__ PW0h, const unsigned short* __restrict__ PW0l,
    const unsigned short* __restrict__ WC1h, const unsigned short* __restrict__ WC1l,
    const unsigned short* __restrict__ WC2h, const unsigned short* __restrict__ WC2l,
    const float* __restrict__ bsum, const float* __restrict__ bc,
    float* __restrict__ out, int nrows)
{
  __shared__ __attribute__((aligned(16))) char smem[65536];
  const int tid  = threadIdx.x;
  const int row0 = blockIdx.x * 64;

  {
    const int m = tid >> 2, q = tid & 3;
    const int gr = row0 + m;
    const int Mt = m >> 4, r16 = m & 15;
#pragma unroll
    for (int it = 0; it < 8; ++it) {
      const int k  = it * 16 + q * 4;
      float4 v = make_float4(0.f, 0.f, 0.f, 0.f);
      if (gr < nrows) v = *(const float4*)(h + (size_t)gr * 128 + k);
      const unsigned short h0 = bf16rne(v.x), h1 = bf16rne(v.y);
      const unsigned short h2 = bf16rne(v.z), h3 = bf16rne(v.w);
      const unsigned short l0 = bf16rne(v.x - bf16tof(h0));
      const unsigned short l1 = bf16rne(v.y - bf16tof(h1));
      const unsigned short l2 = bf16rne(v.z - bf16tof(h2));
      const unsigned short l3 = bf16rne(v.w - bf16tof(h3));
      const int k3 = it * 2 + (q >> 1);
      const int kg = k3 & 3, ks = k3 >> 2;
      const int eb = (q & 1) * 8;
      const int fb = ((Mt * 4 + ks) * 64 + kg * 16 + r16) * 16 + eb;
      *(uint2*)(smem + fb) =
          make_uint2((unsigned)h0 | ((unsigned)h1 << 16), (unsigned)h2 | ((unsigned)h3 << 16));
      *(uint2*)(smem + 16384 + fb) =
          make_uint2((unsigned)l0 | ((unsigned)l1 << 16), (unsigned)l2 | ((unsigned)l3 << 16));
    }
  }
  __syncthreads();

  const int w = tid >> 6, lane = tid & 63;
  union U8 { short8 s; unsigned int u[4]; };

  f32x4 oacc[4][4] = {};

  for (int sc = 0; sc < 4; ++sc) {
    f32x4 zacc[4][2] = {};
#pragma unroll
    for (int ks = 0; ks < 4; ++ks) {
      short8 w0h[2], w0l[2], p0h[2], p0l[2];
#pragma unroll
      for (int nt = 0; nt < 2; ++nt) {
        const int t = w * 8 + sc * 2 + nt;
        const size_t ofs = (size_t)(t * 4 + ks) * 512 + lane * 8;
        w0h[nt] = *(const short8*)(FW0h + ofs);
        w0l[nt] = *(const short8*)(FW0l + ofs);
        p0h[nt] = *(const short8*)(PW0h + ofs);
        p0l[nt] = *(const short8*)(PW0l + ofs);
      }
#pragma unroll
      for (int Mt = 0; Mt < 4; ++Mt) {
        const int fb = ((Mt * 4 + ks) * 64 + lane) * 16;
        U8 hh, hl, rh, rl;
        hh.s = *(const short8*)(smem + fb);
        hl.s = *(const short8*)(smem + 16384 + fb);
#pragma unroll
        for (int u = 0; u < 4; ++u) {
          unsigned int msk = ((hh.u[u] & 0x80008000u) >> 15) * 0xFFFFu;
          rh.u[u] = hh.u[u] & ~msk;
          rl.u[u] = hl.u[u] & ~msk;
        }
#pragma unroll
        for (int nt = 0; nt < 2; ++nt) {
          f32x4 a = zacc[Mt][nt];
          a = __builtin_amdgcn_mfma_f32_16x16x32_bf16(rh.s, w0h[nt], a, 0, 0, 0);
          a = __builtin_amdgcn_mfma_f32_16x16x32_bf16(rh.s, w0l[nt], a, 0, 0, 0);
          a = __builtin_amdgcn_mfma_f32_16x16x32_bf16(rl.s, w0h[nt], a, 0, 0, 0);
          a = __builtin_amdgcn_mfma_f32_16x16x32_bf16(hh.s, p0h[nt], a, 0, 0, 0);
          a = __builtin_amdgcn_mfma_f32_16x16x32_bf16(hh.s, p0l[nt], a, 0, 0, 0);
          a = __builtin_amdgcn_mfma_f32_16x16x32_bf16(hl.s, p0h[nt], a, 0, 0, 0);
          zacc[Mt][nt] = a;
        }
      }
    }
    const float bs0 = bsum[w * 128 + sc * 32 + (lane & 15)];
    const float bs1 = bsum[w * 128 + sc * 32 + 16 + (lane & 15)];
#pragma unroll
    for (int Mt = 0; Mt < 4; ++Mt) {
#pragma unroll
      for (int nt = 0; nt < 2; ++nt) {
        const float bs = nt ? bs1 : bs0;
        const int kg = nt * 2 + ((lane >> 3) & 1);
        const int eb = (lane & 7) * 2;
#pragma unroll
        for (int reg = 0; reg < 4; ++reg) {
          const float zv = fmaxf(zacc[Mt][nt][reg] + bs, 0.f);
          const unsigned short zhi = bf16rne(zv);
          const unsigned short zlo = bf16rne(zv - bf16tof(zhi));
          const int r16 = (lane >> 4) * 4 + reg;
          const int fb = ((w * 4 + Mt) * 64 + kg * 16 + r16) * 16 + eb;
          *(unsigned short*)(smem + 32768 + fb) = zhi;
          *(unsigned short*)(smem + 49152 + fb) = zlo;
        }
      }
    }
    asm volatile("s_waitcnt lgkmcnt(0)" ::: "memory");
    const int s2 = w * 4 + sc;
    short8 c1h[4], c1l[4];
#pragma unroll
    for (int t2 = 0; t2 < 4; ++t2) {
      const size_t ofs = (size_t)(t2 * 16 + s2) * 512 + lane * 8;
      c1h[t2] = *(const short8*)(WC1h + ofs);
      c1l[t2] = *(const short8*)(WC1l + ofs);
    }
#pragma unroll
    for (int Mt = 0; Mt < 4; ++Mt) {
      const int fb = ((w * 4 + Mt) * 64 + lane) * 16;
      short8 zh8 = *(const short8*)(smem + 32768 + fb);
      short8 zl8 = *(const short8*)(smem + 49152 + fb);
#pragma unroll
      for (int t2 = 0; t2 < 4; ++t2) {
        f32x4 a = oacc[Mt][t2];
        a = __builtin_amdgcn_mfma_f32_16x16x32_bf16(zh8, c1h[t2], a, 0, 0, 0);
        a = __builtin_amdgcn_mfma_f32_16x16x32_bf16(zh8, c1l[t2], a, 0, 0, 0);
        a = __builtin_amdgcn_mfma_f32_16x16x32_bf16(zl8, c1h[t2], a, 0, 0, 0);
        oacc[Mt][t2] = a;
      }
    }
  }

  {
    short8 c2h[4], c2l[4];
#pragma unroll
    for (int t = 0; t < 4; ++t) {
      const size_t ofs = (size_t)(t * 4 + w) * 512 + lane * 8;
      c2h[t] = *(const short8*)(WC2h + ofs);
      c2l[t] = *(const short8*)(WC2l + ofs);
    }
#pragma unroll
    for (int Mt = 0; Mt < 4; ++Mt) {
      const int fb = ((Mt * 4 + w) * 64 + lane) * 16;
      short8 hh = *(const short8*)(smem + fb);
      short8 hl = *(const short8*)(smem + 16384 + fb);
#pragma unroll
      for (int t = 0; t < 4; ++t) {
        f32x4 a = oacc[Mt][t];
        a = __builtin_amdgcn_mfma_f32_16x16x32_bf16(hh, c2h[t], a, 0, 0, 0);
        a = __builtin_amdgcn_mfma_f32_16x16x32_bf16(hh, c2l[t], a, 0, 0, 0);
        a = __builtin_amdgcn_mfma_f32_16x16x32_bf16(hl, c2h[t], a, 0, 0, 0);
        oacc[Mt][t] = a;
      }
    }
  }

  __syncthreads();
  float* red = (float*)smem;
#pragma unroll
  for (int Mt = 0; Mt < 4; ++Mt)
#pragma unroll
    for (int Nt = 0; Nt < 4; ++Nt)
#pragma unroll
      for (int reg = 0; reg < 4; ++reg) {
        const int row = Mt * 16 + (lane >> 4) * 4 + reg;
        const int col = Nt * 16 + (lane & 15);
        red[(w * 64 + row) * 64 + col] = oacc[Mt][Nt][reg];
      }
  __syncthreads();
  {
    const int c4 = (tid & 15) * 4;
    const int rb = tid >> 4;
    const float4 bcv = *(const float4*)(bc + c4);
#pragma unroll
    for (int rr = 0; rr < 4; ++rr) {
      const int r = rr * 16 + rb;
      const int gr = row0 + r;
      if (gr < nrows) {
        float4 s = bcv;
#pragma unroll
        for (int wv = 0; wv < 4; ++wv) {
          const float4 p = *(const float4*)&red[(wv * 64 + r) * 64 + c4];
          s.x += p.x; s.y += p.y; s.z += p.z; s.w += p.w;
        }
        *(float4*)(out + (size_t)gr * 64 + c4) = s;
      }
    }
  }
}

// ---------------------------------------------------------------------------
extern "C" void kernel_launch(void* const* d_in, const int* in_sizes, int n_in,
                              void* d_out, int out_size, void* d_ws, size_t ws_size,
                              hipStream_t stream) {
  const float* x    = (const float*)d_in[0];
  const int*   ei   = (const int*)d_in[1];   // [2][E] int32
  const float* mpW0 = (const float*)d_in[2];
  const float* mpb0 = (const float*)d_in[3];
  const float* mpW1 = (const float*)d_in[4];
  const float* mpb1 = (const float*)d_in[5];
  const float* mpW2 = (const float*)d_in[6];
  const float* mpb2 = (const float*)d_in[7];
  const float* fcW0 = (const float*)d_in[8];
  const float* fcb0 = (const float*)d_in[9];
  const float* fcW1 = (const float*)d_in[10];
  const float* fcb1 = (const float*)d_in[11];
  const float* pW0  = (const float*)d_in[12];
  const float* pb0  = (const float*)d_in[13];
  const float* pW1  = (const float*)d_in[14];
  const float* pb1  = (const float*)d_in[15];
  const float* outW = (const float*)d_in[16];
  const float* outb = (const float*)d_in[17];

  const int N = in_sizes[0] / 128;
  const int E = in_sizes[1] / 2;
  const int nb = (N + 1023) / 1024;

  char* ws = (char*)d_ws;
  size_t off = 0;
  auto alloc = [&](size_t bytes) -> char* {
    char* p = ws + off;
    off += (bytes + 255) & ~(size_t)255;
    return p;
  };
  float* norm   = (float*)alloc((size_t)N * 4);
  int*   cnt    = (int*)alloc((size_t)N * 4);
  int*   rowptr = (int*)alloc((size_t)(N + 1) * 4);
  int*   cursor = (int*)alloc((size_t)N * 4);
  int*   bofs   = (int*)alloc((size_t)nb * 4);
  int*   ssrc   = (int*)alloc((size_t)E * 4);
  float* buf0   = (float*)alloc((size_t)N * 128 * 4);
  float* buf1   = (float*)alloc((size_t)N * 128 * 4);
  float* Wc1    = (float*)alloc(512 * 64 * 4);
  float* Wc2    = (float*)alloc(128 * 64 * 4);
  float* bc     = (float*)alloc(64 * 4);
  unsigned short* FW0h = (unsigned short*)alloc(65536 * 2);
  unsigned short* FW0l = (unsigned short*)alloc(65536 * 2);
  unsigned short* PW0h = (unsigned short*)alloc(65536 * 2);
  unsigned short* PW0l = (unsigned short*)alloc(65536 * 2);
  unsigned short* WC1h = (unsigned short*)alloc(32768 * 2);
  unsigned short* WC1l = (unsigned short*)alloc(32768 * 2);
  unsigned short* WC2h = (unsigned short*)alloc(8192 * 2);
  unsigned short* WC2l = (unsigned short*)alloc(8192 * 2);
  float* bsum   = (float*)alloc(512 * 4);
  unsigned short* M0h = (unsigned short*)alloc(16384 * 2);
  unsigned short* M0l = (unsigned short*)alloc(16384 * 2);
  unsigned short* M1h = (unsigned short*)alloc(16384 * 2);
  unsigned short* M1l = (unsigned short*)alloc(16384 * 2);
  unsigned short* M2h = (unsigned short*)alloc(16384 * 2);
  unsigned short* M2l = (unsigned short*)alloc(16384 * 2);
  // total ~= 113 MiB

  init_kernel<<<(N + 255) / 256, 256, 0, stream>>>(norm, cnt, N);
  hist_kernel<<<(E + 255) / 256, 256, 0, stream>>>(ei, E, cnt, norm);
  scan1_kernel<<<nb, 256, 0, stream>>>(cnt, bofs, N);
  scan2_kernel<<<1, 1024, 0, stream>>>(bofs, nb);
  scan3_kernel<<<nb, 256, 0, stream>>>(cnt, bofs, rowptr, cursor, N);
  fill_kernel<<<(E + 255) / 256, 256, 0, stream>>>(ei, E, cursor, ssrc);
  combine_kernel<<<(512 * 64 + 128 * 64 + 64 + 255) / 256, 256, 0, stream>>>(
      fcW1, fcb1, pW1, pb1, outW, outb, Wc1, Wc2, bc);
  convw_kernel<<<(65536 + 32768 + 8192 + 512 + 255) / 256, 256, 0, stream>>>(
      fcW0, pW0, Wc1, Wc2, fcb0, pb0,
      FW0h, FW0l, PW0h, PW0l, WC1h, WC1l, WC2h, WC2l, bsum);
  convmp_kernel<<<(3 * 16384 + 255) / 256, 256, 0, stream>>>(
      mpW0, mpW1, mpW2, M0h, M0l, M1h, M1l, M2h, M2l);

  const int gx = (N + 63) / 64;
  const int ablocks = (N + 3) / 4;

  mp_gemm_mfma<<<gx, 256, 0, stream>>>(x,    M0h, M0l, mpb0, norm, buf0, N);
  agg_kernel<<<ablocks, 256, 0, stream>>>(buf0, rowptr, ssrc, buf1, N);
  mp_gemm_mfma<<<gx, 256, 0, stream>>>(buf1, M1h, M1l, mpb1, norm, buf0, N);
  agg_kernel<<<ablocks, 256, 0, stream>>>(buf0, rowptr, ssrc, buf1, N);
  mp_gemm_mfma<<<gx, 256, 0, stream>>>(buf1, M2h, M2l, mpb2, norm, buf0, N);
  agg_kernel<<<ablocks, 256, 0, stream>>>(buf0, rowptr, ssrc, buf1, N);

  fused_out_mfma<<<gx, 256, 0, stream>>>(
      buf1, FW0h, FW0l, PW0h, PW0l, WC1h, WC1l, WC2h, WC2l, bsum, bc,
      (float*)d_out, N);
}

// Round 6
// 910.591 us; speedup vs baseline: 12.1125x; 1.1300x over previous
//
#include <hip/hip_runtime.h>

// DecoupleModel: 3x GIN MP layers (split-bf16 MFMA) + CSR-gather aggregation
// + fused output MLP (split-bf16 MFMA).
// CSR build via 2-level LDS-binned counting sort by target (no global RMW
// atomics except the norm histogram). Verified math path from R4/R5.

typedef __attribute__((ext_vector_type(8))) short short8;
typedef __attribute__((ext_vector_type(4))) float f32x4;

constexpr float SQRT2   = 1.41421356237309515f;
constexpr float ONE_EPS = 1.0f + SQRT2;          // (1 + eps)
constexpr float RS      = 0.08838834764831845f;  // 1/sqrt(128)
constexpr int   CH      = 16384;                 // edges per P1/P3 block

__device__ inline unsigned short bf16rne(float f) {
  unsigned int u = __float_as_uint(f);
  return (unsigned short)((u + 0x7FFFu + ((u >> 16) & 1u)) >> 16);
}
__device__ inline float bf16tof(unsigned short h) {
  return __uint_as_float(((unsigned int)h) << 16);
}

// ---------------- graph preprocessing --------------------------------------
__global__ void init_kernel(float* __restrict__ norm, int n) {
  int i = blockIdx.x * blockDim.x + threadIdx.x;
  if (i < n) norm[i] = ONE_EPS;
}

// norm[source] += 1 (GIN degree norm) — random-line atomic bound (~90us)
__global__ void nhist_kernel(const int* __restrict__ ei, int E, float* __restrict__ norm) {
  int e = blockIdx.x * blockDim.x + threadIdx.x;
  if (e < E) atomicAdd(&norm[ei[E + e]], 1.0f);  // row 1 = source
}

// P1: per-block coarse histogram of tgt>>7 into bcnt[blk][NB]
__global__ __launch_bounds__(256) void p1_kernel(
    const int* __restrict__ ei, int E, int NB, int* __restrict__ bcnt) {
  __shared__ int cb[1024];
  for (int i = threadIdx.x; i < NB; i += 256) cb[i] = 0;
  __syncthreads();
  const int base = blockIdx.x * CH;
#pragma unroll 4
  for (int it = 0; it < CH / 256; ++it) {
    const int e = base + it * 256 + threadIdx.x;
    if (e < E) atomicAdd(&cb[ei[e] >> 7], 1);
  }
  __syncthreads();
  for (int i = threadIdx.x; i < NB; i += 256)
    bcnt[blockIdx.x * NB + i] = cb[i];
}

// P2: bucket bases (exclusive scan of totals) + per-(block,bucket) offsets
__global__ __launch_bounds__(1024) void p2_kernel(
    const int* __restrict__ bcnt, int* __restrict__ ofs, int* __restrict__ barr,
    int* __restrict__ rowptr, int NBLK, int NB, int E, int N) {
  __shared__ int sh[1024];
  const int t = threadIdx.x;
  int tot = 0;
  if (t < NB)
    for (int b = 0; b < NBLK; ++b) tot += bcnt[b * NB + t];
  sh[t] = (t < NB) ? tot : 0;
  __syncthreads();
  for (int o = 1; o < 1024; o <<= 1) {
    int v = (t >= o) ? sh[t - o] : 0;
    __syncthreads();
    sh[t] += v;
    __syncthreads();
  }
  if (t < NB) {
    int run = sh[t] - tot;   // exclusive
    barr[t] = run;
    for (int b = 0; b < NBLK; ++b) { ofs[b * NB + t] = run; run += bcnt[b * NB + t]; }
  }
  if (t == 0) { barr[NB] = E; rowptr[N] = E; }
}

// P3: scatter packed (tgt,src) into bucket-grouped sorted[] (plain stores)
__global__ __launch_bounds__(256) void p3_kernel(
    const int* __restrict__ ei, int E, int NB, const int* __restrict__ ofs,
    unsigned long long* __restrict__ sorted) {
  __shared__ int cur[1024];
  for (int i = threadIdx.x; i < NB; i += 256) cur[i] = ofs[blockIdx.x * NB + i];
  __syncthreads();
  const int base = blockIdx.x * CH;
  for (int it = 0; it < CH / 256; ++it) {
    const int e = base + it * 256 + threadIdx.x;
    if (e < E) {
      const int tgt = ei[e], src = ei[E + e];
      const int pos = atomicAdd(&cur[tgt >> 7], 1);
      sorted[pos] = ((unsigned long long)(unsigned)tgt << 32) | (unsigned)src;
    }
  }
}

// P4: per bucket (128 nodes): fine hist -> rowptr, then scatter ssrc
__global__ __launch_bounds__(256) void p4_kernel(
    const unsigned long long* __restrict__ sorted, const int* __restrict__ barr,
    int* __restrict__ rowptr, int* __restrict__ ssrc, int N) {
  __shared__ int fcnt[128], fcur[128], sh[128];
  const int B = blockIdx.x, t = threadIdx.x;
  const int lo = barr[B], hi = barr[B + 1];
  if (t < 128) fcnt[t] = 0;
  __syncthreads();
  for (int i = lo + t; i < hi; i += 256)
    atomicAdd(&fcnt[(int)(sorted[i] >> 32) & 127], 1);
  __syncthreads();
  if (t < 128) sh[t] = fcnt[t];
  __syncthreads();
  for (int o = 1; o < 128; o <<= 1) {
    int v = 0;
    if (t < 128 && t >= o) v = sh[t - o];
    __syncthreads();
    if (t < 128) sh[t] += v;
    __syncthreads();
  }
  if (t < 128) {
    const int base = lo + sh[t] - fcnt[t];   // exclusive
    fcur[t] = base;
    const int node = B * 128 + t;
    if (node < N) rowptr[node] = base;
  }
  __syncthreads();
  for (int i = lo + t; i < hi; i += 256) {
    const unsigned long long p = sorted[i];
    const int pos = atomicAdd(&fcur[(int)(p >> 32) & 127], 1);
    ssrc[pos] = (int)(unsigned)(p & 0xffffffffu);
  }
}

// ---------------- weight folding (unchanged, verified) ---------------------
__global__ void combine_kernel(const float* __restrict__ fcW1, const float* __restrict__ fcb1,
                               const float* __restrict__ pW1,  const float* __restrict__ pb1,
                               const float* __restrict__ outW, const float* __restrict__ outb,
                               float* __restrict__ Wc1, float* __restrict__ Wc2,
                               float* __restrict__ bc) {
  int gid = blockIdx.x * blockDim.x + threadIdx.x;
  if (gid < 512 * 64) {
    int k = gid >> 6, j = gid & 63;
    float s = 0.f;
    for (int m = 0; m < 512; ++m) s = fmaf(fcW1[k * 512 + m], outW[m * 64 + j], s);
    Wc1[gid] = s;
  } else if (gid < 512 * 64 + 128 * 64) {
    int t = gid - 512 * 64, k = t >> 6, j = t & 63;
    float s = 0.f;
    for (int m = 0; m < 512; ++m) s = fmaf(pW1[k * 512 + m], outW[m * 64 + j], s);
    Wc2[t] = s;
  } else if (gid < 512 * 64 + 128 * 64 + 64) {
    int j = gid - (512 * 64 + 128 * 64);
    float s = outb[j];
    for (int m = 0; m < 512; ++m) s = fmaf(fcb1[m] + pb1[m], outW[m * 64 + j], s);
    bc[j] = s;
  }
}

__global__ void convw_kernel(const float* __restrict__ fcW0, const float* __restrict__ pW0,
                             const float* __restrict__ Wc1,  const float* __restrict__ Wc2,
                             const float* __restrict__ fcb0, const float* __restrict__ pb0,
                             unsigned short* __restrict__ FW0h, unsigned short* __restrict__ FW0l,
                             unsigned short* __restrict__ PW0h, unsigned short* __restrict__ PW0l,
                             unsigned short* __restrict__ WC1h, unsigned short* __restrict__ WC1l,
                             unsigned short* __restrict__ WC2h, unsigned short* __restrict__ WC2l,
                             float* __restrict__ bsum) {
  int gid = blockIdx.x * blockDim.x + threadIdx.x;
  if (gid < 65536) {
    int e = gid & 7, c = (gid >> 3) & 15, kg = (gid >> 7) & 3, s = (gid >> 9) & 3, t = gid >> 11;
    int k = s * 32 + kg * 8 + e, n = t * 16 + c;
    float f = fcW0[k * 512 + n];
    unsigned short h = bf16rne(f);
    FW0h[gid] = h; FW0l[gid] = bf16rne(f - bf16tof(h));
    f = pW0[k * 512 + n];
    h = bf16rne(f);
    PW0h[gid] = h; PW0l[gid] = bf16rne(f - bf16tof(h));
  } else if (gid < 65536 + 32768) {
    int g = gid - 65536;
    int e = g & 7, c = (g >> 3) & 15, kg = (g >> 7) & 3, s = (g >> 9) & 15, t = g >> 13;
    int k = s * 32 + kg * 8 + e, n = t * 16 + c;
    float f = Wc1[k * 64 + n];
    unsigned short h = bf16rne(f);
    WC1h[g] = h; WC1l[g] = bf16rne(f - bf16tof(h));
  } else if (gid < 65536 + 32768 + 8192) {
    int g = gid - 98304;
    int e = g & 7, c = (g >> 3) & 15, kg = (g >> 7) & 3, s = (g >> 9) & 3, t = (g >> 11) & 3;
    int k = s * 32 + kg * 8 + e, n = t * 16 + c;
    float f = Wc2[k * 64 + n];
    unsigned short h = bf16rne(f);
    WC2h[g] = h; WC2l[g] = bf16rne(f - bf16tof(h));
  } else if (gid < 65536 + 32768 + 8192 + 512) {
    int j = gid - 106496;
    bsum[j] = fcb0[j] + pb0[j];
  }
}

__global__ void convmp_kernel(const float* __restrict__ W0, const float* __restrict__ W1,
                              const float* __restrict__ W2,
                              unsigned short* __restrict__ M0h, unsigned short* __restrict__ M0l,
                              unsigned short* __restrict__ M1h, unsigned short* __restrict__ M1l,
                              unsigned short* __restrict__ M2h, unsigned short* __restrict__ M2l) {
  int gid = blockIdx.x * blockDim.x + threadIdx.x;
  if (gid >= 3 * 16384) return;
  const int m = gid >> 14, g = gid & 16383;
  int e = g & 7, c = (g >> 3) & 15, kg = (g >> 7) & 3, s = (g >> 9) & 3, t = g >> 11;
  int k = s * 32 + kg * 8 + e, n = t * 16 + c;
  const float* W = (m == 0) ? W0 : (m == 1) ? W1 : W2;
  unsigned short* Mh = (m == 0) ? M0h : (m == 1) ? M1h : M2h;
  unsigned short* Ml = (m == 0) ? M0l : (m == 1) ? M1l : M2l;
  float f = W[k * 128 + n];
  unsigned short h = bf16rne(f);
  Mh[g] = h; Ml[g] = bf16rne(f - bf16tof(h));
}

// ---------------- MP layer GEMM, split-bf16 MFMA (verified R5) -------------
__global__ __launch_bounds__(256) void mp_gemm_mfma(
    const float* __restrict__ A,
    const unsigned short* __restrict__ Wh, const unsigned short* __restrict__ Wl,
    const float* __restrict__ bias, const float* __restrict__ norm,
    float* __restrict__ h2, int nrows)
{
  __shared__ __attribute__((aligned(16))) char smem[33792];
  const int tid  = threadIdx.x;
  const int row0 = blockIdx.x * 64;

  {
    const int m = tid >> 2, q = tid & 3;
    const int gr = row0 + m;
    const int Mt = m >> 4, r16 = m & 15;
#pragma unroll
    for (int it = 0; it < 8; ++it) {
      const int k = it * 16 + q * 4;
      float4 v = make_float4(0.f, 0.f, 0.f, 0.f);
      if (gr < nrows) v = *(const float4*)(A + (size_t)gr * 128 + k);
      const unsigned short h0 = bf16rne(v.x), h1 = bf16rne(v.y);
      const unsigned short h2v = bf16rne(v.z), h3 = bf16rne(v.w);
      const unsigned short l0 = bf16rne(v.x - bf16tof(h0));
      const unsigned short l1 = bf16rne(v.y - bf16tof(h1));
      const unsigned short l2 = bf16rne(v.z - bf16tof(h2v));
      const unsigned short l3 = bf16rne(v.w - bf16tof(h3));
      const int k3 = it * 2 + (q >> 1);
      const int kg = k3 & 3, ks = k3 >> 2;
      const int eb = (q & 1) * 8;
      const int fb = ((Mt * 4 + ks) * 64 + kg * 16 + r16) * 16 + eb;
      *(uint2*)(smem + fb) =
          make_uint2((unsigned)h0 | ((unsigned)h1 << 16), (unsigned)h2v | ((unsigned)h3 << 16));
      *(uint2*)(smem + 16384 + fb) =
          make_uint2((unsigned)l0 | ((unsigned)l1 << 16), (unsigned)l2 | ((unsigned)l3 << 16));
    }
  }
  __syncthreads();

  const int w = tid >> 6, lane = tid & 63;
  f32x4 acc[4][2] = {};

#pragma unroll
  for (int ks = 0; ks < 4; ++ks) {
    short8 bh[2], bl[2];
#pragma unroll
    for (int nt = 0; nt < 2; ++nt) {
      const int t = w * 2 + nt;
      const size_t ofs = (size_t)(t * 4 + ks) * 512 + lane * 8;
      bh[nt] = *(const short8*)(Wh + ofs);
      bl[nt] = *(const short8*)(Wl + ofs);
    }
#pragma unroll
    for (int Mt = 0; Mt < 4; ++Mt) {
      const int fb = ((Mt * 4 + ks) * 64 + lane) * 16;
      short8 hh = *(const short8*)(smem + fb);
      short8 hl = *(const short8*)(smem + 16384 + fb);
#pragma unroll
      for (int nt = 0; nt < 2; ++nt) {
        f32x4 a = acc[Mt][nt];
        a = __builtin_amdgcn_mfma_f32_16x16x32_bf16(hh, bh[nt], a, 0, 0, 0);
        a = __builtin_amdgcn_mfma_f32_16x16x32_bf16(hh, bl[nt], a, 0, 0, 0);
        a = __builtin_amdgcn_mfma_f32_16x16x32_bf16(hl, bh[nt], a, 0, 0, 0);
        acc[Mt][nt] = a;
      }
    }
  }

  __syncthreads();
  float* ob = (float*)smem;
#pragma unroll
  for (int Mt = 0; Mt < 4; ++Mt)
#pragma unroll
    for (int nt = 0; nt < 2; ++nt) {
      const int col = w * 32 + nt * 16 + (lane & 15);
#pragma unroll
      for (int reg = 0; reg < 4; ++reg) {
        const int row = Mt * 16 + (lane >> 4) * 4 + reg;
        ob[row * 132 + col] = acc[Mt][nt][reg];
      }
    }
  __syncthreads();
  {
    const int r = tid >> 2;
    const int gr = row0 + r;
    if (gr < nrows) {
      const float sc = RS / norm[gr];
      const int cb = (tid & 3) * 32;
#pragma unroll
      for (int j = 0; j < 32; j += 4) {
        float4 v = *(const float4*)&ob[r * 132 + cb + j];
        const float4 b = *(const float4*)&bias[cb + j];
        v.x = fmaxf(v.x + b.x, 0.f) * sc;
        v.y = fmaxf(v.y + b.y, 0.f) * sc;
        v.z = fmaxf(v.z + b.z, 0.f) * sc;
        v.w = fmaxf(v.w + b.w, 0.f) * sc;
        *(float4*)(h2 + (size_t)gr * 128 + cb + j) = v;
      }
    }
  }
}

// out[t] = (1+eps)*h2[t] + sum_{e in CSR[t]} h2[src[e]]   (one wave per node)
__global__ __launch_bounds__(256) void agg_kernel(
    const float* __restrict__ h2, const int* __restrict__ rowptr,
    const int* __restrict__ ssrc, float* __restrict__ out, int N)
{
  const int wid  = (blockIdx.x * 256 + threadIdx.x) >> 6;
  const int lane = threadIdx.x & 63;
  if (wid >= N) return;
  float2 acc = *(const float2*)(h2 + (size_t)wid * 128 + lane * 2);
  acc.x *= ONE_EPS; acc.y *= ONE_EPS;
  const int beg = rowptr[wid], end = rowptr[wid + 1];
  int i = beg;
  for (; i + 1 < end; i += 2) {
    const int s0 = ssrc[i], s1 = ssrc[i + 1];
    const float2 v0 = *(const float2*)(h2 + (size_t)s0 * 128 + lane * 2);
    const float2 v1 = *(const float2*)(h2 + (size_t)s1 * 128 + lane * 2);
    acc.x += v0.x + v1.x; acc.y += v0.y + v1.y;
  }
  if (i < end) {
    const int s = ssrc[i];
    const float2 v = *(const float2*)(h2 + (size_t)s * 128 + lane * 2);
    acc.x += v.x; acc.y += v.y;
  }
  *(float2*)(out + (size_t)wid * 128 + lane * 2) = acc;
}

// ---------------- fused output MLP, split-bf16 MFMA (verified R4) ----------
__global__ __launch_bounds__(256) void fused_out_mfma(
    const float* __restrict__ h,
    const unsigned short* __restrict__ FW0h, const unsigned short* __restrict__ FW0l,
    const unsigned short* __restrict__ PW0h, const unsigned short* __restrict__ PW0l,
    const unsigned short* __restrict__ WC1h, const unsigned short* __restrict__ WC1l,
    const unsigned short* __restrict__ WC2h, const unsigned short* __restrict__ WC2l,
    const float* __restrict__ bsum, const float* __restrict__ bc,
    float* __restrict__ out, int nrows)
{
  __shared__ __attribute__((aligned(16))) char smem[65536];
  const int tid  = threadIdx.x;
  const int row0 = blockIdx.x * 64;

  {
    const int m = tid >> 2, q = tid & 3;
    const int gr = row0 + m;
    const int Mt = m >> 4, r16 = m & 15;
#pragma unroll
    for (int it = 0; it < 8; ++it) {
      const int k  = it * 16 + q * 4;
      float4 v = make_float4(0.f, 0.f, 0.f, 0.f);
      if (gr < nrows) v = *(const float4*)(h + (size_t)gr * 128 + k);
      const unsigned short h0 = bf16rne(v.x), h1 = bf16rne(v.y);
      const unsigned short h2 = bf16rne(v.z), h3 = bf16rne(v.w);
      const unsigned short l0 = bf16rne(v.x - bf16tof(h0));
      const unsigned short l1 = bf16rne(v.y - bf16tof(h1));
      const unsigned short l2 = bf16rne(v.z - bf16tof(h2));
      const unsigned short l3 = bf16rne(v.w - bf16tof(h3));
      const int k3 = it * 2 + (q >> 1);
      const int kg = k3 & 3, ks = k3 >> 2;
      const int eb = (q & 1) * 8;
      const int fb = ((Mt * 4 + ks) * 64 + kg * 16 + r16) * 16 + eb;
      *(uint2*)(smem + fb) =
          make_uint2((unsigned)h0 | ((unsigned)h1 << 16), (unsigned)h2 | ((unsigned)h3 << 16));
      *(uint2*)(smem + 16384 + fb) =
          make_uint2((unsigned)l0 | ((unsigned)l1 << 16), (unsigned)l2 | ((unsigned)l3 << 16));
    }
  }
  __syncthreads();

  const int w = tid >> 6, lane = tid & 63;
  union U8 { short8 s; unsigned int u[4]; };

  f32x4 oacc[4][4] = {};

  for (int sc = 0; sc < 4; ++sc) {
    f32x4 zacc[4][2] = {};
#pragma unroll
    for (int ks = 0; ks < 4; ++ks) {
      short8 w0h[2], w0l[2], p0h[2], p0l[2];
#pragma unroll
      for (int nt = 0; nt < 2; ++nt) {
        const int t = w * 8 + sc * 2 + nt;
        const size_t ofs = (size_t)(t * 4 + ks) * 512 + lane * 8;
        w0h[nt] = *(const short8*)(FW0h + ofs);
        w0l[nt] = *(const short8*)(FW0l + ofs);
        p0h[nt] = *(const short8*)(PW0h + ofs);
        p0l[nt] = *(const short8*)(PW0l + ofs);
      }
#pragma unroll
      for (int Mt = 0; Mt < 4; ++Mt) {
        const int fb = ((Mt * 4 + ks) * 64 + lane) * 16;
        U8 hh, hl, rh, rl;
        hh.s = *(const short8*)(smem + fb);
        hl.s = *(const short8*)(smem + 16384 + fb);
#pragma unroll
        for (int u = 0; u < 4; ++u) {
          unsigned int msk = ((hh.u[u] & 0x80008000u) >> 15) * 0xFFFFu;
          rh.u[u] = hh.u[u] & ~msk;
          rl.u[u] = hl.u[u] & ~msk;
        }
#pragma unroll
        for (int nt = 0; nt < 2; ++nt) {
          f32x4 a = zacc[Mt][nt];
          a = __builtin_amdgcn_mfma_f32_16x16x32_bf16(rh.s, w0h[nt], a, 0, 0, 0);
          a = __builtin_amdgcn_mfma_f32_16x16x32_bf16(rh.s, w0l[nt], a, 0, 0, 0);
          a = __builtin_amdgcn_mfma_f32_16x16x32_bf16(rl.s, w0h[nt], a, 0, 0, 0);
          a = __builtin_amdgcn_mfma_f32_16x16x32_bf16(hh.s, p0h[nt], a, 0, 0, 0);
          a = __builtin_amdgcn_mfma_f32_16x16x32_bf16(hh.s, p0l[nt], a, 0, 0, 0);
          a = __builtin_amdgcn_mfma_f32_16x16x32_bf16(hl.s, p0h[nt], a, 0, 0, 0);
          zacc[Mt][nt] = a;
        }
      }
    }
    const float bs0 = bsum[w * 128 + sc * 32 + (lane & 15)];
    const float bs1 = bsum[w * 128 + sc * 32 + 16 + (lane & 15)];
#pragma unroll
    for (int Mt = 0; Mt < 4; ++Mt) {
#pragma unroll
      for (int nt = 0; nt < 2; ++nt) {
        const float bs = nt ? bs1 : bs0;
        const int kg = nt * 2 + ((lane >> 3) & 1);
        const int eb = (lane & 7) * 2;
#pragma unroll
        for (int reg = 0; reg < 4; ++reg) {
          const float zv = fmaxf(zacc[Mt][nt][reg] + bs, 0.f);
          const unsigned short zhi = bf16rne(zv);
          const unsigned short zlo = bf16rne(zv - bf16tof(zhi));
          const int r16 = (lane >> 4) * 4 + reg;
          const int fb = ((w * 4 + Mt) * 64 + kg * 16 + r16) * 16 + eb;
          *(unsigned short*)(smem + 32768 + fb) = zhi;
          *(unsigned short*)(smem + 49152 + fb) = zlo;
        }
      }
    }
    asm volatile("s_waitcnt lgkmcnt(0)" ::: "memory");
    const int s2 = w * 4 + sc;
    short8 c1h[4], c1l[4];
#pragma unroll
    for (int t2 = 0; t2 < 4; ++t2) {
      const size_t ofs = (size_t)(t2 * 16 + s2) * 512 + lane * 8;
      c1h[t2] = *(const short8*)(WC1h + ofs);
      c1l[t2] = *(const short8*)(WC1l + ofs);
    }
#pragma unroll
    for (int Mt = 0; Mt < 4; ++Mt) {
      const int fb = ((w * 4 + Mt) * 64 + lane) * 16;
      short8 zh8 = *(const short8*)(smem + 32768 + fb);
      short8 zl8 = *(const short8*)(smem + 49152 + fb);
#pragma unroll
      for (int t2 = 0; t2 < 4; ++t2) {
        f32x4 a = oacc[Mt][t2];
        a = __builtin_amdgcn_mfma_f32_16x16x32_bf16(zh8, c1h[t2], a, 0, 0, 0);
        a = __builtin_amdgcn_mfma_f32_16x16x32_bf16(zh8, c1l[t2], a, 0, 0, 0);
        a = __builtin_amdgcn_mfma_f32_16x16x32_bf16(zl8, c1h[t2], a, 0, 0, 0);
        oacc[Mt][t2] = a;
      }
    }
  }

  {
    short8 c2h[4], c2l[4];
#pragma unroll
    for (int t = 0; t < 4; ++t) {
      const size_t ofs = (size_t)(t * 4 + w) * 512 + lane * 8;
      c2h[t] = *(const short8*)(WC2h + ofs);
      c2l[t] = *(const short8*)(WC2l + ofs);
    }
#pragma unroll
    for (int Mt = 0; Mt < 4; ++Mt) {
      const int fb = ((Mt * 4 + w) * 64 + lane) * 16;
      short8 hh = *(const short8*)(smem + fb);
      short8 hl = *(const short8*)(smem + 16384 + fb);
#pragma unroll
      for (int t = 0; t < 4; ++t) {
        f32x4 a = oacc[Mt][t];
        a = __builtin_amdgcn_mfma_f32_16x16x32_bf16(hh, c2h[t], a, 0, 0, 0);
        a = __builtin_amdgcn_mfma_f32_16x16x32_bf16(hh, c2l[t], a, 0, 0, 0);
        a = __builtin_amdgcn_mfma_f32_16x16x32_bf16(hl, c2h[t], a, 0, 0, 0);
        oacc[Mt][t] = a;
      }
    }
  }

  __syncthreads();
  float* red = (float*)smem;
#pragma unroll
  for (int Mt = 0; Mt < 4; ++Mt)
#pragma unroll
    for (int Nt = 0; Nt < 4; ++Nt)
#pragma unroll
      for (int reg = 0; reg < 4; ++reg) {
        const int row = Mt * 16 + (lane >> 4) * 4 + reg;
        const int col = Nt * 16 + (lane & 15);
        red[(w * 64 + row) * 64 + col] = oacc[Mt][Nt][reg];
      }
  __syncthreads();
  {
    const int c4 = (tid & 15) * 4;
    const int rb = tid >> 4;
    const float4 bcv = *(const float4*)(bc + c4);
#pragma unroll
    for (int rr = 0; rr < 4; ++rr) {
      const int r = rr * 16 + rb;
      const int gr = row0 + r;
      if (gr < nrows) {
        float4 s = bcv;
#pragma unroll
        for (int wv = 0; wv < 4; ++wv) {
          const float4 p = *(const float4*)&red[(wv * 64 + r) * 64 + c4];
          s.x += p.x; s.y += p.y; s.z += p.z; s.w += p.w;
        }
        *(float4*)(out + (size_t)gr * 64 + c4) = s;
      }
    }
  }
}

// ---------------------------------------------------------------------------
extern "C" void kernel_launch(void* const* d_in, const int* in_sizes, int n_in,
                              void* d_out, int out_size, void* d_ws, size_t ws_size,
                              hipStream_t stream) {
  const float* x    = (const float*)d_in[0];
  const int*   ei   = (const int*)d_in[1];   // [2][E] int32
  const float* mpW0 = (const float*)d_in[2];
  const float* mpb0 = (const float*)d_in[3];
  const float* mpW1 = (const float*)d_in[4];
  const float* mpb1 = (const float*)d_in[5];
  const float* mpW2 = (const float*)d_in[6];
  const float* mpb2 = (const float*)d_in[7];
  const float* fcW0 = (const float*)d_in[8];
  const float* fcb0 = (const float*)d_in[9];
  const float* fcW1 = (const float*)d_in[10];
  const float* fcb1 = (const float*)d_in[11];
  const float* pW0  = (const float*)d_in[12];
  const float* pb0  = (const float*)d_in[13];
  const float* pW1  = (const float*)d_in[14];
  const float* pb1  = (const float*)d_in[15];
  const float* outW = (const float*)d_in[16];
  const float* outb = (const float*)d_in[17];

  const int N = in_sizes[0] / 128;
  const int E = in_sizes[1] / 2;
  const int NB   = (N + 127) / 128;          // coarse buckets (<=1024)
  const int NBLK = (E + CH - 1) / CH;        // P1/P3 blocks

  char* ws = (char*)d_ws;
  size_t off = 0;
  auto alloc = [&](size_t bytes) -> char* {
    char* p = ws + off;
    off += (bytes + 255) & ~(size_t)255;
    return p;
  };
  float* norm   = (float*)alloc((size_t)N * 4);
  int*   rowptr = (int*)alloc((size_t)(N + 1) * 4);
  int*   bcnt   = (int*)alloc((size_t)NBLK * NB * 4);
  int*   ofs    = (int*)alloc((size_t)NBLK * NB * 4);
  int*   barr   = (int*)alloc((size_t)(NB + 1) * 4);
  int*   ssrc   = (int*)alloc((size_t)E * 4);
  unsigned long long* sorted = (unsigned long long*)alloc((size_t)E * 8);
  float* buf0   = (float*)alloc((size_t)N * 128 * 4);
  float* buf1   = (float*)alloc((size_t)N * 128 * 4);
  float* Wc1    = (float*)alloc(512 * 64 * 4);
  float* Wc2    = (float*)alloc(128 * 64 * 4);
  float* bc     = (float*)alloc(64 * 4);
  unsigned short* FW0h = (unsigned short*)alloc(65536 * 2);
  unsigned short* FW0l = (unsigned short*)alloc(65536 * 2);
  unsigned short* PW0h = (unsigned short*)alloc(65536 * 2);
  unsigned short* PW0l = (unsigned short*)alloc(65536 * 2);
  unsigned short* WC1h = (unsigned short*)alloc(32768 * 2);
  unsigned short* WC1l = (unsigned short*)alloc(32768 * 2);
  unsigned short* WC2h = (unsigned short*)alloc(8192 * 2);
  unsigned short* WC2l = (unsigned short*)alloc(8192 * 2);
  float* bsum   = (float*)alloc(512 * 4);
  unsigned short* M0h = (unsigned short*)alloc(16384 * 2);
  unsigned short* M0l = (unsigned short*)alloc(16384 * 2);
  unsigned short* M1h = (unsigned short*)alloc(16384 * 2);
  unsigned short* M1l = (unsigned short*)alloc(16384 * 2);
  unsigned short* M2h = (unsigned short*)alloc(16384 * 2);
  unsigned short* M2l = (unsigned short*)alloc(16384 * 2);
  // total ~= 130 MiB

  init_kernel<<<(N + 255) / 256, 256, 0, stream>>>(norm, N);
  nhist_kernel<<<(E + 255) / 256, 256, 0, stream>>>(ei, E, norm);
  p1_kernel<<<NBLK, 256, 0, stream>>>(ei, E, NB, bcnt);
  p2_kernel<<<1, 1024, 0, stream>>>(bcnt, ofs, barr, rowptr, NBLK, NB, E, N);
  p3_kernel<<<NBLK, 256, 0, stream>>>(ei, E, NB, ofs, sorted);
  p4_kernel<<<NB, 256, 0, stream>>>(sorted, barr, rowptr, ssrc, N);
  combine_kernel<<<(512 * 64 + 128 * 64 + 64 + 255) / 256, 256, 0, stream>>>(
      fcW1, fcb1, pW1, pb1, outW, outb, Wc1, Wc2, bc);
  convw_kernel<<<(65536 + 32768 + 8192 + 512 + 255) / 256, 256, 0, stream>>>(
      fcW0, pW0, Wc1, Wc2, fcb0, pb0,
      FW0h, FW0l, PW0h, PW0l, WC1h, WC1l, WC2h, WC2l, bsum);
  convmp_kernel<<<(3 * 16384 + 255) / 256, 256, 0, stream>>>(
      mpW0, mpW1, mpW2, M0h, M0l, M1h, M1l, M2h, M2l);

  const int gx = (N + 63) / 64;
  const int ablocks = (N + 3) / 4;

  mp_gemm_mfma<<<gx, 256, 0, stream>>>(x,    M0h, M0l, mpb0, norm, buf0, N);
  agg_kernel<<<ablocks, 256, 0, stream>>>(buf0, rowptr, ssrc, buf1, N);
  mp_gemm_mfma<<<gx, 256, 0, stream>>>(buf1, M1h, M1l, mpb1, norm, buf0, N);
  agg_kernel<<<ablocks, 256, 0, stream>>>(buf0, rowptr, ssrc, buf1, N);
  mp_gemm_mfma<<<gx, 256, 0, stream>>>(buf1, M2h, M2l, mpb2, norm, buf0, N);
  agg_kernel<<<ablocks, 256, 0, stream>>>(buf0, rowptr, ssrc, buf1, N);

  fused_out_mfma<<<gx, 256, 0, stream>>>(
      buf1, FW0h, FW0l, PW0h, PW0l, WC1h, WC1l, WC2h, WC2l, bsum, bc,
      (float*)d_out, N);
}

// Round 8
// 878.267 us; speedup vs baseline: 12.5583x; 1.0368x over previous
//
#include <hip/hip_runtime.h>

// DecoupleModel: 3x GIN MP layers (split-bf16 MFMA) + CSR-gather aggregation
// + fused output MLP (split-bf16 MFMA).
// R8 = R7 with the nontemporal-store type fixed (ext_vector f32x4, not HIP float4).

typedef __attribute__((ext_vector_type(8))) short short8;
typedef __attribute__((ext_vector_type(4))) float f32x4;

constexpr float SQRT2   = 1.41421356237309515f;
constexpr float ONE_EPS = 1.0f + SQRT2;          // (1 + eps)
constexpr float RS      = 0.08838834764831845f;  // 1/sqrt(128)
constexpr int   CH      = 16384;                 // edges per P1/P3 block

__device__ inline unsigned short bf16rne(float f) {
  unsigned int u = __float_as_uint(f);
  return (unsigned short)((u + 0x7FFFu + ((u >> 16) & 1u)) >> 16);
}
__device__ inline float bf16tof(unsigned short h) {
  return __uint_as_float(((unsigned int)h) << 16);
}

// ---------------- graph preprocessing --------------------------------------
__global__ void init_kernel(float* __restrict__ norm, int n) {
  int i = blockIdx.x * blockDim.x + threadIdx.x;
  if (i < n) norm[i] = ONE_EPS;
}

// P1: per-block coarse histogram of tgt>>7 into bcnt[blk][NB]
__global__ __launch_bounds__(256) void p1_kernel(
    const int* __restrict__ ei, int E, int NB, int* __restrict__ bcnt) {
  __shared__ int cb[1024];
  for (int i = threadIdx.x; i < NB; i += 256) cb[i] = 0;
  __syncthreads();
  const int base = blockIdx.x * CH;
#pragma unroll 4
  for (int it = 0; it < CH / 256; ++it) {
    const int e = base + it * 256 + threadIdx.x;
    if (e < E) atomicAdd(&cb[ei[e] >> 7], 1);
  }
  __syncthreads();
  for (int i = threadIdx.x; i < NB; i += 256)
    bcnt[blockIdx.x * NB + i] = cb[i];
}

// P2: bucket bases (exclusive scan of totals) + per-(block,bucket) offsets
__global__ __launch_bounds__(1024) void p2_kernel(
    const int* __restrict__ bcnt, int* __restrict__ ofs, int* __restrict__ barr,
    int* __restrict__ rowptr, int NBLK, int NB, int E, int N) {
  __shared__ int sh[1024];
  const int t = threadIdx.x;
  int tot = 0;
  if (t < NB)
    for (int b = 0; b < NBLK; ++b) tot += bcnt[b * NB + t];
  sh[t] = (t < NB) ? tot : 0;
  __syncthreads();
  for (int o = 1; o < 1024; o <<= 1) {
    int v = (t >= o) ? sh[t - o] : 0;
    __syncthreads();
    sh[t] += v;
    __syncthreads();
  }
  if (t < NB) {
    int run = sh[t] - tot;   // exclusive
    barr[t] = run;
    for (int b = 0; b < NBLK; ++b) { ofs[b * NB + t] = run; run += bcnt[b * NB + t]; }
  }
  if (t == 0) { barr[NB] = E; rowptr[N] = E; }
}

// P3: scatter packed (tgt,src) into bucket-grouped sorted[]; norm[src] += 1
__global__ __launch_bounds__(256) void p3_kernel(
    const int* __restrict__ ei, int E, int NB, const int* __restrict__ ofs,
    unsigned long long* __restrict__ sorted, float* __restrict__ norm) {
  __shared__ int cur[1024];
  for (int i = threadIdx.x; i < NB; i += 256) cur[i] = ofs[blockIdx.x * NB + i];
  __syncthreads();
  const int base = blockIdx.x * CH;
  for (int it = 0; it < CH / 256; ++it) {
    const int e = base + it * 256 + threadIdx.x;
    if (e < E) {
      const int tgt = ei[e], src = ei[E + e];
      const int pos = atomicAdd(&cur[tgt >> 7], 1);
      sorted[pos] = ((unsigned long long)(unsigned)tgt << 32) | (unsigned)src;
      atomicAdd(&norm[src], 1.0f);   // GIN degree norm (source occurrences)
    }
  }
}

// P4: per bucket (128 nodes): fine hist -> rowptr, then scatter ssrc
__global__ __launch_bounds__(256) void p4_kernel(
    const unsigned long long* __restrict__ sorted, const int* __restrict__ barr,
    int* __restrict__ rowptr, int* __restrict__ ssrc, int N) {
  __shared__ int fcnt[128], fcur[128], sh[128];
  const int B = blockIdx.x, t = threadIdx.x;
  const int lo = barr[B], hi = barr[B + 1];
  if (t < 128) fcnt[t] = 0;
  __syncthreads();
  for (int i = lo + t; i < hi; i += 256)
    atomicAdd(&fcnt[(int)(sorted[i] >> 32) & 127], 1);
  __syncthreads();
  if (t < 128) sh[t] = fcnt[t];
  __syncthreads();
  for (int o = 1; o < 128; o <<= 1) {
    int v = 0;
    if (t < 128 && t >= o) v = sh[t - o];
    __syncthreads();
    if (t < 128) sh[t] += v;
    __syncthreads();
  }
  if (t < 128) {
    const int base = lo + sh[t] - fcnt[t];   // exclusive
    fcur[t] = base;
    const int node = B * 128 + t;
    if (node < N) rowptr[node] = base;
  }
  __syncthreads();
  for (int i = lo + t; i < hi; i += 256) {
    const unsigned long long p = sorted[i];
    const int pos = atomicAdd(&fcur[(int)(p >> 32) & 127], 1);
    ssrc[pos] = (int)(unsigned)(p & 0xffffffffu);
  }
}

// ---------------- weight folding (unchanged, verified) ---------------------
__global__ void combine_kernel(const float* __restrict__ fcW1, const float* __restrict__ fcb1,
                               const float* __restrict__ pW1,  const float* __restrict__ pb1,
                               const float* __restrict__ outW, const float* __restrict__ outb,
                               float* __restrict__ Wc1, float* __restrict__ Wc2,
                               float* __restrict__ bc) {
  int gid = blockIdx.x * blockDim.x + threadIdx.x;
  if (gid < 512 * 64) {
    int k = gid >> 6, j = gid & 63;
    float s = 0.f;
    for (int m = 0; m < 512; ++m) s = fmaf(fcW1[k * 512 + m], outW[m * 64 + j], s);
    Wc1[gid] = s;
  } else if (gid < 512 * 64 + 128 * 64) {
    int t = gid - 512 * 64, k = t >> 6, j = t & 63;
    float s = 0.f;
    for (int m = 0; m < 512; ++m) s = fmaf(pW1[k * 512 + m], outW[m * 64 + j], s);
    Wc2[t] = s;
  } else if (gid < 512 * 64 + 128 * 64 + 64) {
    int j = gid - (512 * 64 + 128 * 64);
    float s = outb[j];
    for (int m = 0; m < 512; ++m) s = fmaf(fcb1[m] + pb1[m], outW[m * 64 + j], s);
    bc[j] = s;
  }
}

__global__ void convw_kernel(const float* __restrict__ fcW0, const float* __restrict__ pW0,
                             const float* __restrict__ Wc1,  const float* __restrict__ Wc2,
                             const float* __restrict__ fcb0, const float* __restrict__ pb0,
                             unsigned short* __restrict__ FW0h, unsigned short* __restrict__ FW0l,
                             unsigned short* __restrict__ PW0h, unsigned short* __restrict__ PW0l,
                             unsigned short* __restrict__ WC1h, unsigned short* __restrict__ WC1l,
                             unsigned short* __restrict__ WC2h, unsigned short* __restrict__ WC2l,
                             float* __restrict__ bsum) {
  int gid = blockIdx.x * blockDim.x + threadIdx.x;
  if (gid < 65536) {
    int e = gid & 7, c = (gid >> 3) & 15, kg = (gid >> 7) & 3, s = (gid >> 9) & 3, t = gid >> 11;
    int k = s * 32 + kg * 8 + e, n = t * 16 + c;
    float f = fcW0[k * 512 + n];
    unsigned short h = bf16rne(f);
    FW0h[gid] = h; FW0l[gid] = bf16rne(f - bf16tof(h));
    f = pW0[k * 512 + n];
    h = bf16rne(f);
    PW0h[gid] = h; PW0l[gid] = bf16rne(f - bf16tof(h));
  } else if (gid < 65536 + 32768) {
    int g = gid - 65536;
    int e = g & 7, c = (g >> 3) & 15, kg = (g >> 7) & 3, s = (g >> 9) & 15, t = g >> 13;
    int k = s * 32 + kg * 8 + e, n = t * 16 + c;
    float f = Wc1[k * 64 + n];
    unsigned short h = bf16rne(f);
    WC1h[g] = h; WC1l[g] = bf16rne(f - bf16tof(h));
  } else if (gid < 65536 + 32768 + 8192) {
    int g = gid - 98304;
    int e = g & 7, c = (g >> 3) & 15, kg = (g >> 7) & 3, s = (g >> 9) & 3, t = (g >> 11) & 3;
    int k = s * 32 + kg * 8 + e, n = t * 16 + c;
    float f = Wc2[k * 64 + n];
    unsigned short h = bf16rne(f);
    WC2h[g] = h; WC2l[g] = bf16rne(f - bf16tof(h));
  } else if (gid < 65536 + 32768 + 8192 + 512) {
    int j = gid - 106496;
    bsum[j] = fcb0[j] + pb0[j];
  }
}

__global__ void convmp_kernel(const float* __restrict__ W0, const float* __restrict__ W1,
                              const float* __restrict__ W2,
                              unsigned short* __restrict__ M0h, unsigned short* __restrict__ M0l,
                              unsigned short* __restrict__ M1h, unsigned short* __restrict__ M1l,
                              unsigned short* __restrict__ M2h, unsigned short* __restrict__ M2l) {
  int gid = blockIdx.x * blockDim.x + threadIdx.x;
  if (gid >= 3 * 16384) return;
  const int m = gid >> 14, g = gid & 16383;
  int e = g & 7, c = (g >> 3) & 15, kg = (g >> 7) & 3, s = (g >> 9) & 3, t = g >> 11;
  int k = s * 32 + kg * 8 + e, n = t * 16 + c;
  const float* W = (m == 0) ? W0 : (m == 1) ? W1 : W2;
  unsigned short* Mh = (m == 0) ? M0h : (m == 1) ? M1h : M2h;
  unsigned short* Ml = (m == 0) ? M0l : (m == 1) ? M1l : M2l;
  float f = W[k * 128 + n];
  unsigned short h = bf16rne(f);
  Mh[g] = h; Ml[g] = bf16rne(f - bf16tof(h));
}

// ---------------- MP layer GEMM, split-bf16 MFMA (verified R5) -------------
__global__ __launch_bounds__(256) void mp_gemm_mfma(
    const float* __restrict__ A,
    const unsigned short* __restrict__ Wh, const unsigned short* __restrict__ Wl,
    const float* __restrict__ bias, const float* __restrict__ norm,
    float* __restrict__ h2, int nrows)
{
  __shared__ __attribute__((aligned(16))) char smem[33792];
  const int tid  = threadIdx.x;
  const int row0 = blockIdx.x * 64;

  {
    const int m = tid >> 2, q = tid & 3;
    const int gr = row0 + m;
    const int Mt = m >> 4, r16 = m & 15;
#pragma unroll
    for (int it = 0; it < 8; ++it) {
      const int k = it * 16 + q * 4;
      float4 v = make_float4(0.f, 0.f, 0.f, 0.f);
      if (gr < nrows) v = *(const float4*)(A + (size_t)gr * 128 + k);
      const unsigned short h0 = bf16rne(v.x), h1 = bf16rne(v.y);
      const unsigned short h2v = bf16rne(v.z), h3 = bf16rne(v.w);
      const unsigned short l0 = bf16rne(v.x - bf16tof(h0));
      const unsigned short l1 = bf16rne(v.y - bf16tof(h1));
      const unsigned short l2 = bf16rne(v.z - bf16tof(h2v));
      const unsigned short l3 = bf16rne(v.w - bf16tof(h3));
      const int k3 = it * 2 + (q >> 1);
      const int kg = k3 & 3, ks = k3 >> 2;
      const int eb = (q & 1) * 8;
      const int fb = ((Mt * 4 + ks) * 64 + kg * 16 + r16) * 16 + eb;
      *(uint2*)(smem + fb) =
          make_uint2((unsigned)h0 | ((unsigned)h1 << 16), (unsigned)h2v | ((unsigned)h3 << 16));
      *(uint2*)(smem + 16384 + fb) =
          make_uint2((unsigned)l0 | ((unsigned)l1 << 16), (unsigned)l2 | ((unsigned)l3 << 16));
    }
  }
  __syncthreads();

  const int w = tid >> 6, lane = tid & 63;
  f32x4 acc[4][2] = {};

#pragma unroll
  for (int ks = 0; ks < 4; ++ks) {
    short8 bh[2], bl[2];
#pragma unroll
    for (int nt = 0; nt < 2; ++nt) {
      const int t = w * 2 + nt;
      const size_t ofs = (size_t)(t * 4 + ks) * 512 + lane * 8;
      bh[nt] = *(const short8*)(Wh + ofs);
      bl[nt] = *(const short8*)(Wl + ofs);
    }
#pragma unroll
    for (int Mt = 0; Mt < 4; ++Mt) {
      const int fb = ((Mt * 4 + ks) * 64 + lane) * 16;
      short8 hh = *(const short8*)(smem + fb);
      short8 hl = *(const short8*)(smem + 16384 + fb);
#pragma unroll
      for (int nt = 0; nt < 2; ++nt) {
        f32x4 a = acc[Mt][nt];
        a = __builtin_amdgcn_mfma_f32_16x16x32_bf16(hh, bh[nt], a, 0, 0, 0);
        a = __builtin_amdgcn_mfma_f32_16x16x32_bf16(hh, bl[nt], a, 0, 0, 0);
        a = __builtin_amdgcn_mfma_f32_16x16x32_bf16(hl, bh[nt], a, 0, 0, 0);
        acc[Mt][nt] = a;
      }
    }
  }

  __syncthreads();
  float* ob = (float*)smem;
#pragma unroll
  for (int Mt = 0; Mt < 4; ++Mt)
#pragma unroll
    for (int nt = 0; nt < 2; ++nt) {
      const int col = w * 32 + nt * 16 + (lane & 15);
#pragma unroll
      for (int reg = 0; reg < 4; ++reg) {
        const int row = Mt * 16 + (lane >> 4) * 4 + reg;
        ob[row * 132 + col] = acc[Mt][nt][reg];
      }
    }
  __syncthreads();
  {
    const int r = tid >> 2;
    const int gr = row0 + r;
    if (gr < nrows) {
      const float sc = RS / norm[gr];
      const int cb = (tid & 3) * 32;
#pragma unroll
      for (int j = 0; j < 32; j += 4) {
        float4 v = *(const float4*)&ob[r * 132 + cb + j];
        const float4 b = *(const float4*)&bias[cb + j];
        v.x = fmaxf(v.x + b.x, 0.f) * sc;
        v.y = fmaxf(v.y + b.y, 0.f) * sc;
        v.z = fmaxf(v.z + b.z, 0.f) * sc;
        v.w = fmaxf(v.w + b.w, 0.f) * sc;
        *(float4*)(h2 + (size_t)gr * 128 + cb + j) = v;
      }
    }
  }
}

// out[t] = (1+eps)*h2[t] + sum_{e in CSR[t]} h2[src[e]]
// 2 nodes per wave: lanes 0-31 -> node 2w, lanes 32-63 -> node 2w+1.
// f32x4/lane -> 1KB gathered per vmem instr; unroll-2 -> 4 rows in flight.
__global__ __launch_bounds__(256) void agg_kernel(
    const float* __restrict__ h2, const int* __restrict__ rowptr,
    const int* __restrict__ ssrc, float* __restrict__ out, int N)
{
  const int wv   = (blockIdx.x * 256 + threadIdx.x) >> 6;
  const int lane = threadIdx.x & 63;
  const int node = wv * 2 + (lane >> 5);
  const int col  = (lane & 31) * 4;
  if (node >= N) return;
  f32x4 acc = *(const f32x4*)(h2 + (size_t)node * 128 + col);
  acc *= ONE_EPS;
  const int beg = rowptr[node], end = rowptr[node + 1];
  int i = beg;
  for (; i + 1 < end; i += 2) {
    const int s0 = ssrc[i], s1 = ssrc[i + 1];
    const f32x4 v0 = *(const f32x4*)(h2 + (size_t)s0 * 128 + col);
    const f32x4 v1 = *(const f32x4*)(h2 + (size_t)s1 * 128 + col);
    acc += v0 + v1;
  }
  if (i < end) {
    const int s = ssrc[i];
    acc += *(const f32x4*)(h2 + (size_t)s * 128 + col);
  }
  __builtin_nontemporal_store(acc, (f32x4*)(out + (size_t)node * 128 + col));
}

// ---------------- fused output MLP, split-bf16 MFMA (verified R4) ----------
__global__ __launch_bounds__(256) void fused_out_mfma(
    const float* __restrict__ h,
    const unsigned short* __restrict__ FW0h, const unsigned short* __restrict__ FW0l,
    const unsigned short* __restrict__ PW0h, const unsigned short* __restrict__ PW0l,
    const unsigned short* __restrict__ WC1h, const unsigned short* __restrict__ WC1l,
    const unsigned short* __restrict__ WC2h, const unsigned short* __restrict__ WC2l,
    const float* __restrict__ bsum, const float* __restrict__ bc,
    float* __restrict__ out, int nrows)
{
  __shared__ __attribute__((aligned(16))) char smem[65536];
  const int tid  = threadIdx.x;
  const int row0 = blockIdx.x * 64;

  {
    const int m = tid >> 2, q = tid & 3;
    const int gr = row0 + m;
    const int Mt = m >> 4, r16 = m & 15;
#pragma unroll
    for (int it = 0; it < 8; ++it) {
      const int k  = it * 16 + q * 4;
      float4 v = make_float4(0.f, 0.f, 0.f, 0.f);
      if (gr < nrows) v = *(const float4*)(h + (size_t)gr * 128 + k);
      const unsigned short h0 = bf16rne(v.x), h1 = bf16rne(v.y);
      const unsigned short h2 = bf16rne(v.z), h3 = bf16rne(v.w);
      const unsigned short l0 = bf16rne(v.x - bf16tof(h0));
      const unsigned short l1 = bf16rne(v.y - bf16tof(h1));
      const unsigned short l2 = bf16rne(v.z - bf16tof(h2));
      const unsigned short l3 = bf16rne(v.w - bf16tof(h3));
      const int k3 = it * 2 + (q >> 1);
      const int kg = k3 & 3, ks = k3 >> 2;
      const int eb = (q & 1) * 8;
      const int fb = ((Mt * 4 + ks) * 64 + kg * 16 + r16) * 16 + eb;
      *(uint2*)(smem + fb) =
          make_uint2((unsigned)h0 | ((unsigned)h1 << 16), (unsigned)h2 | ((unsigned)h3 << 16));
      *(uint2*)(smem + 16384 + fb) =
          make_uint2((unsigned)l0 | ((unsigned)l1 << 16), (unsigned)l2 | ((unsigned)l3 << 16));
    }
  }
  __syncthreads();

  const int w = tid >> 6, lane = tid & 63;
  union U8 { short8 s; unsigned int u[4]; };

  f32x4 oacc[4][4] = {};

  for (int sc = 0; sc < 4; ++sc) {
    f32x4 zacc[4][2] = {};
#pragma unroll
    for (int ks = 0; ks < 4; ++ks) {
      short8 w0h[2], w0l[2], p0h[2], p0l[2];
#pragma unroll
      for (int nt = 0; nt < 2; ++nt) {
        const int t = w * 8 + sc * 2 + nt;
        const size_t ofs = (size_t)(t * 4 + ks) * 512 + lane * 8;
        w0h[nt] = *(const short8*)(FW0h + ofs);
        w0l[nt] = *(const short8*)(FW0l + ofs);
        p0h[nt] = *(const short8*)(PW0h + ofs);
        p0l[nt] = *(const short8*)(PW0l + ofs);
      }
#pragma unroll
      for (int Mt = 0; Mt < 4; ++Mt) {
        const int fb = ((Mt * 4 + ks) * 64 + lane) * 16;
        U8 hh, hl, rh, rl;
        hh.s = *(const short8*)(smem + fb);
        hl.s = *(const short8*)(smem + 16384 + fb);
#pragma unroll
        for (int u = 0; u < 4; ++u) {
          unsigned int msk = ((hh.u[u] & 0x80008000u) >> 15) * 0xFFFFu;
          rh.u[u] = hh.u[u] & ~msk;
          rl.u[u] = hl.u[u] & ~msk;
        }
#pragma unroll
        for (int nt = 0; nt < 2; ++nt) {
          f32x4 a = zacc[Mt][nt];
          a = __builtin_amdgcn_mfma_f32_16x16x32_bf16(rh.s, w0h[nt], a, 0, 0, 0);
          a = __builtin_amdgcn_mfma_f32_16x16x32_bf16(rh.s, w0l[nt], a, 0, 0, 0);
          a = __builtin_amdgcn_mfma_f32_16x16x32_bf16(rl.s, w0h[nt], a, 0, 0, 0);
          a = __builtin_amdgcn_mfma_f32_16x16x32_bf16(hh.s, p0h[nt], a, 0, 0, 0);
          a = __builtin_amdgcn_mfma_f32_16x16x32_bf16(hh.s, p0l[nt], a, 0, 0, 0);
          a = __builtin_amdgcn_mfma_f32_16x16x32_bf16(hl.s, p0h[nt], a, 0, 0, 0);
          zacc[Mt][nt] = a;
        }
      }
    }
    const float bs0 = bsum[w * 128 + sc * 32 + (lane & 15)];
    const float bs1 = bsum[w * 128 + sc * 32 + 16 + (lane & 15)];
#pragma unroll
    for (int Mt = 0; Mt < 4; ++Mt) {
#pragma unroll
      for (int nt = 0; nt < 2; ++nt) {
        const float bs = nt ? bs1 : bs0;
        const int kg = nt * 2 + ((lane >> 3) & 1);
        const int eb = (lane & 7) * 2;
#pragma unroll
        for (int reg = 0; reg < 4; ++reg) {
          const float zv = fmaxf(zacc[Mt][nt][reg] + bs, 0.f);
          const unsigned short zhi = bf16rne(zv);
          const unsigned short zlo = bf16rne(zv - bf16tof(zhi));
          const int r16 = (lane >> 4) * 4 + reg;
          const int fb = ((w * 4 + Mt) * 64 + kg * 16 + r16) * 16 + eb;
          *(unsigned short*)(smem + 32768 + fb) = zhi;
          *(unsigned short*)(smem + 49152 + fb) = zlo;
        }
      }
    }
    asm volatile("s_waitcnt lgkmcnt(0)" ::: "memory");
    const int s2 = w * 4 + sc;
    short8 c1h[4], c1l[4];
#pragma unroll
    for (int t2 = 0; t2 < 4; ++t2) {
      const size_t ofs = (size_t)(t2 * 16 + s2) * 512 + lane * 8;
      c1h[t2] = *(const short8*)(WC1h + ofs);
      c1l[t2] = *(const short8*)(WC1l + ofs);
    }
#pragma unroll
    for (int Mt = 0; Mt < 4; ++Mt) {
      const int fb = ((w * 4 + Mt) * 64 + lane) * 16;
      short8 zh8 = *(const short8*)(smem + 32768 + fb);
      short8 zl8 = *(const short8*)(smem + 49152 + fb);
#pragma unroll
      for (int t2 = 0; t2 < 4; ++t2) {
        f32x4 a = oacc[Mt][t2];
        a = __builtin_amdgcn_mfma_f32_16x16x32_bf16(zh8, c1h[t2], a, 0, 0, 0);
        a = __builtin_amdgcn_mfma_f32_16x16x32_bf16(zh8, c1l[t2], a, 0, 0, 0);
        a = __builtin_amdgcn_mfma_f32_16x16x32_bf16(zl8, c1h[t2], a, 0, 0, 0);
        oacc[Mt][t2] = a;
      }
    }
  }

  {
    short8 c2h[4], c2l[4];
#pragma unroll
    for (int t = 0; t < 4; ++t) {
      const size_t ofs = (size_t)(t * 4 + w) * 512 + lane * 8;
      c2h[t] = *(const short8*)(WC2h + ofs);
      c2l[t] = *(const short8*)(WC2l + ofs);
    }
#pragma unroll
    for (int Mt = 0; Mt < 4; ++Mt) {
      const int fb = ((Mt * 4 + w) * 64 + lane) * 16;
      short8 hh = *(const short8*)(smem + fb);
      short8 hl = *(const short8*)(smem + 16384 + fb);
#pragma unroll
      for (int t = 0; t < 4; ++t) {
        f32x4 a = oacc[Mt][t];
        a = __builtin_amdgcn_mfma_f32_16x16x32_bf16(hh, c2h[t], a, 0, 0, 0);
        a = __builtin_amdgcn_mfma_f32_16x16x32_bf16(hh, c2l[t], a, 0, 0, 0);
        a = __builtin_amdgcn_mfma_f32_16x16x32_bf16(hl, c2h[t], a, 0, 0, 0);
        oacc[Mt][t] = a;
      }
    }
  }

  __syncthreads();
  float* red = (float*)smem;
#pragma unroll
  for (int Mt = 0; Mt < 4; ++Mt)
#pragma unroll
    for (int Nt = 0; Nt < 4; ++Nt)
#pragma unroll
      for (int reg = 0; reg < 4; ++reg) {
        const int row = Mt * 16 + (lane >> 4) * 4 + reg;
        const int col = Nt * 16 + (lane & 15);
        red[(w * 64 + row) * 64 + col] = oacc[Mt][Nt][reg];
      }
  __syncthreads();
  {
    const int c4 = (tid & 15) * 4;
    const int rb = tid >> 4;
    const float4 bcv = *(const float4*)(bc + c4);
#pragma unroll
    for (int rr = 0; rr < 4; ++rr) {
      const int r = rr * 16 + rb;
      const int gr = row0 + r;
      if (gr < nrows) {
        float4 s = bcv;
#pragma unroll
        for (int wv = 0; wv < 4; ++wv) {
          const float4 p = *(const float4*)&red[(wv * 64 + r) * 64 + c4];
          s.x += p.x; s.y += p.y; s.z += p.z; s.w += p.w;
        }
        *(float4*)(out + (size_t)gr * 64 + c4) = s;
      }
    }
  }
}

// ---------------------------------------------------------------------------
extern "C" void kernel_launch(void* const* d_in, const int* in_sizes, int n_in,
                              void* d_out, int out_size, void* d_ws, size_t ws_size,
                              hipStream_t stream) {
  const float* x    = (const float*)d_in[0];
  const int*   ei   = (const int*)d_in[1];   // [2][E] int32
  const float* mpW0 = (const float*)d_in[2];
  const float* mpb0 = (const float*)d_in[3];
  const float* mpW1 = (const float*)d_in[4];
  const float* mpb1 = (const float*)d_in[5];
  const float* mpW2 = (const float*)d_in[6];
  const float* mpb2 = (const float*)d_in[7];
  const float* fcW0 = (const float*)d_in[8];
  const float* fcb0 = (const float*)d_in[9];
  const float* fcW1 = (const float*)d_in[10];
  const float* fcb1 = (const float*)d_in[11];
  const float* pW0  = (const float*)d_in[12];
  const float* pb0  = (const float*)d_in[13];
  const float* pW1  = (const float*)d_in[14];
  const float* pb1  = (const float*)d_in[15];
  const float* outW = (const float*)d_in[16];
  const float* outb = (const float*)d_in[17];

  const int N = in_sizes[0] / 128;
  const int E = in_sizes[1] / 2;
  const int NB   = (N + 127) / 128;          // coarse buckets (<=1024)
  const int NBLK = (E + CH - 1) / CH;        // P1/P3 blocks

  char* ws = (char*)d_ws;
  size_t off = 0;
  auto alloc = [&](size_t bytes) -> char* {
    char* p = ws + off;
    off += (bytes + 255) & ~(size_t)255;
    return p;
  };
  float* norm   = (float*)alloc((size_t)N * 4);
  int*   rowptr = (int*)alloc((size_t)(N + 1) * 4);
  int*   bcnt   = (int*)alloc((size_t)NBLK * NB * 4);
  int*   ofs    = (int*)alloc((size_t)NBLK * NB * 4);
  int*   barr   = (int*)alloc((size_t)(NB + 1) * 4);
  int*   ssrc   = (int*)alloc((size_t)E * 4);
  unsigned long long* sorted = (unsigned long long*)alloc((size_t)E * 8);
  float* buf0   = (float*)alloc((size_t)N * 128 * 4);
  float* buf1   = (float*)alloc((size_t)N * 128 * 4);
  float* Wc1    = (float*)alloc(512 * 64 * 4);
  float* Wc2    = (float*)alloc(128 * 64 * 4);
  float* bc     = (float*)alloc(64 * 4);
  unsigned short* FW0h = (unsigned short*)alloc(65536 * 2);
  unsigned short* FW0l = (unsigned short*)alloc(65536 * 2);
  unsigned short* PW0h = (unsigned short*)alloc(65536 * 2);
  unsigned short* PW0l = (unsigned short*)alloc(65536 * 2);
  unsigned short* WC1h = (unsigned short*)alloc(32768 * 2);
  unsigned short* WC1l = (unsigned short*)alloc(32768 * 2);
  unsigned short* WC2h = (unsigned short*)alloc(8192 * 2);
  unsigned short* WC2l = (unsigned short*)alloc(8192 * 2);
  float* bsum   = (float*)alloc(512 * 4);
  unsigned short* M0h = (unsigned short*)alloc(16384 * 2);
  unsigned short* M0l = (unsigned short*)alloc(16384 * 2);
  unsigned short* M1h = (unsigned short*)alloc(16384 * 2);
  unsigned short* M1l = (unsigned short*)alloc(16384 * 2);
  unsigned short* M2h = (unsigned short*)alloc(16384 * 2);
  unsigned short* M2l = (unsigned short*)alloc(16384 * 2);
  // total ~= 130 MiB

  init_kernel<<<(N + 255) / 256, 256, 0, stream>>>(norm, N);
  p1_kernel<<<NBLK, 256, 0, stream>>>(ei, E, NB, bcnt);
  p2_kernel<<<1, 1024, 0, stream>>>(bcnt, ofs, barr, rowptr, NBLK, NB, E, N);
  p3_kernel<<<NBLK, 256, 0, stream>>>(ei, E, NB, ofs, sorted, norm);
  p4_kernel<<<NB, 256, 0, stream>>>(sorted, barr, rowptr, ssrc, N);
  combine_kernel<<<(512 * 64 + 128 * 64 + 64 + 255) / 256, 256, 0, stream>>>(
      fcW1, fcb1, pW1, pb1, outW, outb, Wc1, Wc2, bc);
  convw_kernel<<<(65536 + 32768 + 8192 + 512 + 255) / 256, 256, 0, stream>>>(
      fcW0, pW0, Wc1, Wc2, fcb0, pb0,
      FW0h, FW0l, PW0h, PW0l, WC1h, WC1l, WC2h, WC2l, bsum);
  convmp_kernel<<<(3 * 16384 + 255) / 256, 256, 0, stream>>>(
      mpW0, mpW1, mpW2, M0h, M0l, M1h, M1l, M2h, M2l);

  const int gx = (N + 63) / 64;
  const int ablocks = (N + 7) / 8;   // 4 waves/block, 2 nodes/wave

  mp_gemm_mfma<<<gx, 256, 0, stream>>>(x,    M0h, M0l, mpb0, norm, buf0, N);
  agg_kernel<<<ablocks, 256, 0, stream>>>(buf0, rowptr, ssrc, buf1, N);
  mp_gemm_mfma<<<gx, 256, 0, stream>>>(buf1, M1h, M1l, mpb1, norm, buf0, N);
  agg_kernel<<<ablocks, 256, 0, stream>>>(buf0, rowptr, ssrc, buf1, N);
  mp_gemm_mfma<<<gx, 256, 0, stream>>>(buf1, M2h, M2l, mpb2, norm, buf0, N);
  agg_kernel<<<ablocks, 256, 0, stream>>>(buf0, rowptr, ssrc, buf1, N);

  fused_out_mfma<<<gx, 256, 0, stream>>>(
      buf1, FW0h, FW0l, PW0h, PW0l, WC1h, WC1l, WC2h, WC2l, bsum, bc,
      (float*)d_out, N);
}

// Round 9
// 652.938 us; speedup vs baseline: 16.8922x; 1.3451x over previous
//
#include <hip/hip_runtime.h>

// DecoupleModel: 3x GIN MP layers (split-bf16 MFMA) + CSR-gather aggregation
// + fused output MLP (split-bf16 MFMA).
// R9: h2 stored fp16 (gather traffic halved; agg was L2-miss-BW bound);
//     agg = 4 nodes/wave, fp16x8 per lane (1KB/instr); single fp32 h buffer.

typedef __attribute__((ext_vector_type(8))) short short8;
typedef __attribute__((ext_vector_type(4))) float f32x4;
typedef __attribute__((ext_vector_type(8))) _Float16 h16x8;
typedef __attribute__((ext_vector_type(4))) _Float16 h16x4;

constexpr float SQRT2   = 1.41421356237309515f;
constexpr float ONE_EPS = 1.0f + SQRT2;          // (1 + eps)
constexpr float RS      = 0.08838834764831845f;  // 1/sqrt(128)
constexpr int   CH      = 16384;                 // edges per P1/P3 block

__device__ inline unsigned short bf16rne(float f) {
  unsigned int u = __float_as_uint(f);
  return (unsigned short)((u + 0x7FFFu + ((u >> 16) & 1u)) >> 16);
}
__device__ inline float bf16tof(unsigned short h) {
  return __uint_as_float(((unsigned int)h) << 16);
}

// ---------------- graph preprocessing --------------------------------------
__global__ void init_kernel(float* __restrict__ norm, int n) {
  int i = blockIdx.x * blockDim.x + threadIdx.x;
  if (i < n) norm[i] = ONE_EPS;
}

// P1: per-block coarse histogram of tgt>>7 into bcnt[blk][NB]
__global__ __launch_bounds__(256) void p1_kernel(
    const int* __restrict__ ei, int E, int NB, int* __restrict__ bcnt) {
  __shared__ int cb[1024];
  for (int i = threadIdx.x; i < NB; i += 256) cb[i] = 0;
  __syncthreads();
  const int base = blockIdx.x * CH;
#pragma unroll 4
  for (int it = 0; it < CH / 256; ++it) {
    const int e = base + it * 256 + threadIdx.x;
    if (e < E) atomicAdd(&cb[ei[e] >> 7], 1);
  }
  __syncthreads();
  for (int i = threadIdx.x; i < NB; i += 256)
    bcnt[blockIdx.x * NB + i] = cb[i];
}

// P2: bucket bases (exclusive scan of totals) + per-(block,bucket) offsets
__global__ __launch_bounds__(1024) void p2_kernel(
    const int* __restrict__ bcnt, int* __restrict__ ofs, int* __restrict__ barr,
    int* __restrict__ rowptr, int NBLK, int NB, int E, int N) {
  __shared__ int sh[1024];
  const int t = threadIdx.x;
  int tot = 0;
  if (t < NB)
    for (int b = 0; b < NBLK; ++b) tot += bcnt[b * NB + t];
  sh[t] = (t < NB) ? tot : 0;
  __syncthreads();
  for (int o = 1; o < 1024; o <<= 1) {
    int v = (t >= o) ? sh[t - o] : 0;
    __syncthreads();
    sh[t] += v;
    __syncthreads();
  }
  if (t < NB) {
    int run = sh[t] - tot;   // exclusive
    barr[t] = run;
    for (int b = 0; b < NBLK; ++b) { ofs[b * NB + t] = run; run += bcnt[b * NB + t]; }
  }
  if (t == 0) { barr[NB] = E; rowptr[N] = E; }
}

// P3: scatter packed (tgt,src) into bucket-grouped sorted[]; norm[src] += 1
__global__ __launch_bounds__(256) void p3_kernel(
    const int* __restrict__ ei, int E, int NB, const int* __restrict__ ofs,
    unsigned long long* __restrict__ sorted, float* __restrict__ norm) {
  __shared__ int cur[1024];
  for (int i = threadIdx.x; i < NB; i += 256) cur[i] = ofs[blockIdx.x * NB + i];
  __syncthreads();
  const int base = blockIdx.x * CH;
  for (int it = 0; it < CH / 256; ++it) {
    const int e = base + it * 256 + threadIdx.x;
    if (e < E) {
      const int tgt = ei[e], src = ei[E + e];
      const int pos = atomicAdd(&cur[tgt >> 7], 1);
      sorted[pos] = ((unsigned long long)(unsigned)tgt << 32) | (unsigned)src;
      atomicAdd(&norm[src], 1.0f);   // GIN degree norm (source occurrences)
    }
  }
}

// P4: per bucket (128 nodes): fine hist -> rowptr, then scatter ssrc
__global__ __launch_bounds__(256) void p4_kernel(
    const unsigned long long* __restrict__ sorted, const int* __restrict__ barr,
    int* __restrict__ rowptr, int* __restrict__ ssrc, int N) {
  __shared__ int fcnt[128], fcur[128], sh[128];
  const int B = blockIdx.x, t = threadIdx.x;
  const int lo = barr[B], hi = barr[B + 1];
  if (t < 128) fcnt[t] = 0;
  __syncthreads();
  for (int i = lo + t; i < hi; i += 256)
    atomicAdd(&fcnt[(int)(sorted[i] >> 32) & 127], 1);
  __syncthreads();
  if (t < 128) sh[t] = fcnt[t];
  __syncthreads();
  for (int o = 1; o < 128; o <<= 1) {
    int v = 0;
    if (t < 128 && t >= o) v = sh[t - o];
    __syncthreads();
    if (t < 128) sh[t] += v;
    __syncthreads();
  }
  if (t < 128) {
    const int base = lo + sh[t] - fcnt[t];   // exclusive
    fcur[t] = base;
    const int node = B * 128 + t;
    if (node < N) rowptr[node] = base;
  }
  __syncthreads();
  for (int i = lo + t; i < hi; i += 256) {
    const unsigned long long p = sorted[i];
    const int pos = atomicAdd(&fcur[(int)(p >> 32) & 127], 1);
    ssrc[pos] = (int)(unsigned)(p & 0xffffffffu);
  }
}

// ---------------- weight folding (unchanged, verified) ---------------------
__global__ void combine_kernel(const float* __restrict__ fcW1, const float* __restrict__ fcb1,
                               const float* __restrict__ pW1,  const float* __restrict__ pb1,
                               const float* __restrict__ outW, const float* __restrict__ outb,
                               float* __restrict__ Wc1, float* __restrict__ Wc2,
                               float* __restrict__ bc) {
  int gid = blockIdx.x * blockDim.x + threadIdx.x;
  if (gid < 512 * 64) {
    int k = gid >> 6, j = gid & 63;
    float s = 0.f;
    for (int m = 0; m < 512; ++m) s = fmaf(fcW1[k * 512 + m], outW[m * 64 + j], s);
    Wc1[gid] = s;
  } else if (gid < 512 * 64 + 128 * 64) {
    int t = gid - 512 * 64, k = t >> 6, j = t & 63;
    float s = 0.f;
    for (int m = 0; m < 512; ++m) s = fmaf(pW1[k * 512 + m], outW[m * 64 + j], s);
    Wc2[t] = s;
  } else if (gid < 512 * 64 + 128 * 64 + 64) {
    int j = gid - (512 * 64 + 128 * 64);
    float s = outb[j];
    for (int m = 0; m < 512; ++m) s = fmaf(fcb1[m] + pb1[m], outW[m * 64 + j], s);
    bc[j] = s;
  }
}

__global__ void convw_kernel(const float* __restrict__ fcW0, const float* __restrict__ pW0,
                             const float* __restrict__ Wc1,  const float* __restrict__ Wc2,
                             const float* __restrict__ fcb0, const float* __restrict__ pb0,
                             unsigned short* __restrict__ FW0h, unsigned short* __restrict__ FW0l,
                             unsigned short* __restrict__ PW0h, unsigned short* __restrict__ PW0l,
                             unsigned short* __restrict__ WC1h, unsigned short* __restrict__ WC1l,
                             unsigned short* __restrict__ WC2h, unsigned short* __restrict__ WC2l,
                             float* __restrict__ bsum) {
  int gid = blockIdx.x * blockDim.x + threadIdx.x;
  if (gid < 65536) {
    int e = gid & 7, c = (gid >> 3) & 15, kg = (gid >> 7) & 3, s = (gid >> 9) & 3, t = gid >> 11;
    int k = s * 32 + kg * 8 + e, n = t * 16 + c;
    float f = fcW0[k * 512 + n];
    unsigned short h = bf16rne(f);
    FW0h[gid] = h; FW0l[gid] = bf16rne(f - bf16tof(h));
    f = pW0[k * 512 + n];
    h = bf16rne(f);
    PW0h[gid] = h; PW0l[gid] = bf16rne(f - bf16tof(h));
  } else if (gid < 65536 + 32768) {
    int g = gid - 65536;
    int e = g & 7, c = (g >> 3) & 15, kg = (g >> 7) & 3, s = (g >> 9) & 15, t = g >> 13;
    int k = s * 32 + kg * 8 + e, n = t * 16 + c;
    float f = Wc1[k * 64 + n];
    unsigned short h = bf16rne(f);
    WC1h[g] = h; WC1l[g] = bf16rne(f - bf16tof(h));
  } else if (gid < 65536 + 32768 + 8192) {
    int g = gid - 98304;
    int e = g & 7, c = (g >> 3) & 15, kg = (g >> 7) & 3, s = (g >> 9) & 3, t = (g >> 11) & 3;
    int k = s * 32 + kg * 8 + e, n = t * 16 + c;
    float f = Wc2[k * 64 + n];
    unsigned short h = bf16rne(f);
    WC2h[g] = h; WC2l[g] = bf16rne(f - bf16tof(h));
  } else if (gid < 65536 + 32768 + 8192 + 512) {
    int j = gid - 106496;
    bsum[j] = fcb0[j] + pb0[j];
  }
}

__global__ void convmp_kernel(const float* __restrict__ W0, const float* __restrict__ W1,
                              const float* __restrict__ W2,
                              unsigned short* __restrict__ M0h, unsigned short* __restrict__ M0l,
                              unsigned short* __restrict__ M1h, unsigned short* __restrict__ M1l,
                              unsigned short* __restrict__ M2h, unsigned short* __restrict__ M2l) {
  int gid = blockIdx.x * blockDim.x + threadIdx.x;
  if (gid >= 3 * 16384) return;
  const int m = gid >> 14, g = gid & 16383;
  int e = g & 7, c = (g >> 3) & 15, kg = (g >> 7) & 3, s = (g >> 9) & 3, t = g >> 11;
  int k = s * 32 + kg * 8 + e, n = t * 16 + c;
  const float* W = (m == 0) ? W0 : (m == 1) ? W1 : W2;
  unsigned short* Mh = (m == 0) ? M0h : (m == 1) ? M1h : M2h;
  unsigned short* Ml = (m == 0) ? M0l : (m == 1) ? M1l : M2l;
  float f = W[k * 128 + n];
  unsigned short h = bf16rne(f);
  Mh[g] = h; Ml[g] = bf16rne(f - bf16tof(h));
}

// ---------------- MP layer GEMM, split-bf16 MFMA (verified R5) -------------
// h2 (fp16) = relu(A@W + b) * RS / norm[row]
__global__ __launch_bounds__(256) void mp_gemm_mfma(
    const float* __restrict__ A,
    const unsigned short* __restrict__ Wh, const unsigned short* __restrict__ Wl,
    const float* __restrict__ bias, const float* __restrict__ norm,
    _Float16* __restrict__ h2h, int nrows)
{
  __shared__ __attribute__((aligned(16))) char smem[33792];
  const int tid  = threadIdx.x;
  const int row0 = blockIdx.x * 64;

  {
    const int m = tid >> 2, q = tid & 3;
    const int gr = row0 + m;
    const int Mt = m >> 4, r16 = m & 15;
#pragma unroll
    for (int it = 0; it < 8; ++it) {
      const int k = it * 16 + q * 4;
      float4 v = make_float4(0.f, 0.f, 0.f, 0.f);
      if (gr < nrows) v = *(const float4*)(A + (size_t)gr * 128 + k);
      const unsigned short h0 = bf16rne(v.x), h1 = bf16rne(v.y);
      const unsigned short h2v = bf16rne(v.z), h3 = bf16rne(v.w);
      const unsigned short l0 = bf16rne(v.x - bf16tof(h0));
      const unsigned short l1 = bf16rne(v.y - bf16tof(h1));
      const unsigned short l2 = bf16rne(v.z - bf16tof(h2v));
      const unsigned short l3 = bf16rne(v.w - bf16tof(h3));
      const int k3 = it * 2 + (q >> 1);
      const int kg = k3 & 3, ks = k3 >> 2;
      const int eb = (q & 1) * 8;
      const int fb = ((Mt * 4 + ks) * 64 + kg * 16 + r16) * 16 + eb;
      *(uint2*)(smem + fb) =
          make_uint2((unsigned)h0 | ((unsigned)h1 << 16), (unsigned)h2v | ((unsigned)h3 << 16));
      *(uint2*)(smem + 16384 + fb) =
          make_uint2((unsigned)l0 | ((unsigned)l1 << 16), (unsigned)l2 | ((unsigned)l3 << 16));
    }
  }
  __syncthreads();

  const int w = tid >> 6, lane = tid & 63;
  f32x4 acc[4][2] = {};

#pragma unroll
  for (int ks = 0; ks < 4; ++ks) {
    short8 bh[2], bl[2];
#pragma unroll
    for (int nt = 0; nt < 2; ++nt) {
      const int t = w * 2 + nt;
      const size_t ofs = (size_t)(t * 4 + ks) * 512 + lane * 8;
      bh[nt] = *(const short8*)(Wh + ofs);
      bl[nt] = *(const short8*)(Wl + ofs);
    }
#pragma unroll
    for (int Mt = 0; Mt < 4; ++Mt) {
      const int fb = ((Mt * 4 + ks) * 64 + lane) * 16;
      short8 hh = *(const short8*)(smem + fb);
      short8 hl = *(const short8*)(smem + 16384 + fb);
#pragma unroll
      for (int nt = 0; nt < 2; ++nt) {
        f32x4 a = acc[Mt][nt];
        a = __builtin_amdgcn_mfma_f32_16x16x32_bf16(hh, bh[nt], a, 0, 0, 0);
        a = __builtin_amdgcn_mfma_f32_16x16x32_bf16(hh, bl[nt], a, 0, 0, 0);
        a = __builtin_amdgcn_mfma_f32_16x16x32_bf16(hl, bh[nt], a, 0, 0, 0);
        acc[Mt][nt] = a;
      }
    }
  }

  __syncthreads();
  float* ob = (float*)smem;
#pragma unroll
  for (int Mt = 0; Mt < 4; ++Mt)
#pragma unroll
    for (int nt = 0; nt < 2; ++nt) {
      const int col = w * 32 + nt * 16 + (lane & 15);
#pragma unroll
      for (int reg = 0; reg < 4; ++reg) {
        const int row = Mt * 16 + (lane >> 4) * 4 + reg;
        ob[row * 132 + col] = acc[Mt][nt][reg];
      }
    }
  __syncthreads();
  {
    const int r = tid >> 2;
    const int gr = row0 + r;
    if (gr < nrows) {
      const float sc = RS / norm[gr];
      const int cb = (tid & 3) * 32;
#pragma unroll
      for (int j = 0; j < 32; j += 4) {
        float4 v = *(const float4*)&ob[r * 132 + cb + j];
        const float4 b = *(const float4*)&bias[cb + j];
        h16x4 pk;
        pk[0] = (_Float16)(fmaxf(v.x + b.x, 0.f) * sc);
        pk[1] = (_Float16)(fmaxf(v.y + b.y, 0.f) * sc);
        pk[2] = (_Float16)(fmaxf(v.z + b.z, 0.f) * sc);
        pk[3] = (_Float16)(fmaxf(v.w + b.w, 0.f) * sc);
        *(h16x4*)(h2h + (size_t)gr * 128 + cb + j) = pk;
      }
    }
  }
}

// out[t] = (1+eps)*h2[t] + sum_{e in CSR[t]} h2[src[e]]   (fp16 gather, fp32 acc)
// 4 nodes per wave (16 lanes each), fp16x8 per lane -> 1KB gathered per instr.
__global__ __launch_bounds__(256) void agg_kernel(
    const _Float16* __restrict__ h2h, const int* __restrict__ rowptr,
    const int* __restrict__ ssrc, float* __restrict__ out, int N)
{
  const int wv   = (blockIdx.x * 256 + threadIdx.x) >> 6;
  const int lane = threadIdx.x & 63;
  const int node = wv * 4 + (lane >> 4);
  const int col  = (lane & 15) * 8;
  if (node >= N) return;
  float acc[8];
  {
    const h16x8 sv = *(const h16x8*)(h2h + (size_t)node * 128 + col);
#pragma unroll
    for (int j = 0; j < 8; ++j) acc[j] = ONE_EPS * (float)sv[j];
  }
  const int beg = rowptr[node], end = rowptr[node + 1];
  int i = beg;
  for (; i + 1 < end; i += 2) {
    const int s0 = ssrc[i], s1 = ssrc[i + 1];
    const h16x8 v0 = *(const h16x8*)(h2h + (size_t)s0 * 128 + col);
    const h16x8 v1 = *(const h16x8*)(h2h + (size_t)s1 * 128 + col);
#pragma unroll
    for (int j = 0; j < 8; ++j) acc[j] += (float)v0[j] + (float)v1[j];
  }
  if (i < end) {
    const int s = ssrc[i];
    const h16x8 v = *(const h16x8*)(h2h + (size_t)s * 128 + col);
#pragma unroll
    for (int j = 0; j < 8; ++j) acc[j] += (float)v[j];
  }
  f32x4 o0 = {acc[0], acc[1], acc[2], acc[3]};
  f32x4 o1 = {acc[4], acc[5], acc[6], acc[7]};
  __builtin_nontemporal_store(o0, (f32x4*)(out + (size_t)node * 128 + col));
  __builtin_nontemporal_store(o1, (f32x4*)(out + (size_t)node * 128 + col + 4));
}

// ---------------- fused output MLP, split-bf16 MFMA (verified R4) ----------
__global__ __launch_bounds__(256) void fused_out_mfma(
    const float* __restrict__ h,
    const unsigned short* __restrict__ FW0h, const unsigned short* __restrict__ FW0l,
    const unsigned short* __restrict__ PW0h, const unsigned short* __restrict__ PW0l,
    const unsigned short* __restrict__ WC1h, const unsigned short* __restrict__ WC1l,
    const unsigned short* __restrict__ WC2h, const unsigned short* __restrict__ WC2l,
    const float* __restrict__ bsum, const float* __restrict__ bc,
    float* __restrict__ out, int nrows)
{
  __shared__ __attribute__((aligned(16))) char smem[65536];
  const int tid  = threadIdx.x;
  const int row0 = blockIdx.x * 64;

  {
    const int m = tid >> 2, q = tid & 3;
    const int gr = row0 + m;
    const int Mt = m >> 4, r16 = m & 15;
#pragma unroll
    for (int it = 0; it < 8; ++it) {
      const int k  = it * 16 + q * 4;
      float4 v = make_float4(0.f, 0.f, 0.f, 0.f);
      if (gr < nrows) v = *(const float4*)(h + (size_t)gr * 128 + k);
      const unsigned short h0 = bf16rne(v.x), h1 = bf16rne(v.y);
      const unsigned short h2 = bf16rne(v.z), h3 = bf16rne(v.w);
      const unsigned short l0 = bf16rne(v.x - bf16tof(h0));
      const unsigned short l1 = bf16rne(v.y - bf16tof(h1));
      const unsigned short l2 = bf16rne(v.z - bf16tof(h2));
      const unsigned short l3 = bf16rne(v.w - bf16tof(h3));
      const int k3 = it * 2 + (q >> 1);
      const int kg = k3 & 3, ks = k3 >> 2;
      const int eb = (q & 1) * 8;
      const int fb = ((Mt * 4 + ks) * 64 + kg * 16 + r16) * 16 + eb;
      *(uint2*)(smem + fb) =
          make_uint2((unsigned)h0 | ((unsigned)h1 << 16), (unsigned)h2 | ((unsigned)h3 << 16));
      *(uint2*)(smem + 16384 + fb) =
          make_uint2((unsigned)l0 | ((unsigned)l1 << 16), (unsigned)l2 | ((unsigned)l3 << 16));
    }
  }
  __syncthreads();

  const int w = tid >> 6, lane = tid & 63;
  union U8 { short8 s; unsigned int u[4]; };

  f32x4 oacc[4][4] = {};

  for (int sc = 0; sc < 4; ++sc) {
    f32x4 zacc[4][2] = {};
#pragma unroll
    for (int ks = 0; ks < 4; ++ks) {
      short8 w0h[2], w0l[2], p0h[2], p0l[2];
#pragma unroll
      for (int nt = 0; nt < 2; ++nt) {
        const int t = w * 8 + sc * 2 + nt;
        const size_t ofs = (size_t)(t * 4 + ks) * 512 + lane * 8;
        w0h[nt] = *(const short8*)(FW0h + ofs);
        w0l[nt] = *(const short8*)(FW0l + ofs);
        p0h[nt] = *(const short8*)(PW0h + ofs);
        p0l[nt] = *(const short8*)(PW0l + ofs);
      }
#pragma unroll
      for (int Mt = 0; Mt < 4; ++Mt) {
        const int fb = ((Mt * 4 + ks) * 64 + lane) * 16;
        U8 hh, hl, rh, rl;
        hh.s = *(const short8*)(smem + fb);
        hl.s = *(const short8*)(smem + 16384 + fb);
#pragma unroll
        for (int u = 0; u < 4; ++u) {
          unsigned int msk = ((hh.u[u] & 0x80008000u) >> 15) * 0xFFFFu;
          rh.u[u] = hh.u[u] & ~msk;
          rl.u[u] = hl.u[u] & ~msk;
        }
#pragma unroll
        for (int nt = 0; nt < 2; ++nt) {
          f32x4 a = zacc[Mt][nt];
          a = __builtin_amdgcn_mfma_f32_16x16x32_bf16(rh.s, w0h[nt], a, 0, 0, 0);
          a = __builtin_amdgcn_mfma_f32_16x16x32_bf16(rh.s, w0l[nt], a, 0, 0, 0);
          a = __builtin_amdgcn_mfma_f32_16x16x32_bf16(rl.s, w0h[nt], a, 0, 0, 0);
          a = __builtin_amdgcn_mfma_f32_16x16x32_bf16(hh.s, p0h[nt], a, 0, 0, 0);
          a = __builtin_amdgcn_mfma_f32_16x16x32_bf16(hh.s, p0l[nt], a, 0, 0, 0);
          a = __builtin_amdgcn_mfma_f32_16x16x32_bf16(hl.s, p0h[nt], a, 0, 0, 0);
          zacc[Mt][nt] = a;
        }
      }
    }
    const float bs0 = bsum[w * 128 + sc * 32 + (lane & 15)];
    const float bs1 = bsum[w * 128 + sc * 32 + 16 + (lane & 15)];
#pragma unroll
    for (int Mt = 0; Mt < 4; ++Mt) {
#pragma unroll
      for (int nt = 0; nt < 2; ++nt) {
        const float bs = nt ? bs1 : bs0;
        const int kg = nt * 2 + ((lane >> 3) & 1);
        const int eb = (lane & 7) * 2;
#pragma unroll
        for (int reg = 0; reg < 4; ++reg) {
          const float zv = fmaxf(zacc[Mt][nt][reg] + bs, 0.f);
          const unsigned short zhi = bf16rne(zv);
          const unsigned short zlo = bf16rne(zv - bf16tof(zhi));
          const int r16 = (lane >> 4) * 4 + reg;
          const int fb = ((w * 4 + Mt) * 64 + kg * 16 + r16) * 16 + eb;
          *(unsigned short*)(smem + 32768 + fb) = zhi;
          *(unsigned short*)(smem + 49152 + fb) = zlo;
        }
      }
    }
    asm volatile("s_waitcnt lgkmcnt(0)" ::: "memory");
    const int s2 = w * 4 + sc;
    short8 c1h[4], c1l[4];
#pragma unroll
    for (int t2 = 0; t2 < 4; ++t2) {
      const size_t ofs = (size_t)(t2 * 16 + s2) * 512 + lane * 8;
      c1h[t2] = *(const short8*)(WC1h + ofs);
      c1l[t2] = *(const short8*)(WC1l + ofs);
    }
#pragma unroll
    for (int Mt = 0; Mt < 4; ++Mt) {
      const int fb = ((w * 4 + Mt) * 64 + lane) * 16;
      short8 zh8 = *(const short8*)(smem + 32768 + fb);
      short8 zl8 = *(const short8*)(smem + 49152 + fb);
#pragma unroll
      for (int t2 = 0; t2 < 4; ++t2) {
        f32x4 a = oacc[Mt][t2];
        a = __builtin_amdgcn_mfma_f32_16x16x32_bf16(zh8, c1h[t2], a, 0, 0, 0);
        a = __builtin_amdgcn_mfma_f32_16x16x32_bf16(zh8, c1l[t2], a, 0, 0, 0);
        a = __builtin_amdgcn_mfma_f32_16x16x32_bf16(zl8, c1h[t2], a, 0, 0, 0);
        oacc[Mt][t2] = a;
      }
    }
  }

  {
    short8 c2h[4], c2l[4];
#pragma unroll
    for (int t = 0; t < 4; ++t) {
      const size_t ofs = (size_t)(t * 4 + w) * 512 + lane * 8;
      c2h[t] = *(const short8*)(WC2h + ofs);
      c2l[t] = *(const short8*)(WC2l + ofs);
    }
#pragma unroll
    for (int Mt = 0; Mt < 4; ++Mt) {
      const int fb = ((Mt * 4 + w) * 64 + lane) * 16;
      short8 hh = *(const short8*)(smem + fb);
      short8 hl = *(const short8*)(smem + 16384 + fb);
#pragma unroll
      for (int t = 0; t < 4; ++t) {
        f32x4 a = oacc[Mt][t];
        a = __builtin_amdgcn_mfma_f32_16x16x32_bf16(hh, c2h[t], a, 0, 0, 0);
        a = __builtin_amdgcn_mfma_f32_16x16x32_bf16(hh, c2l[t], a, 0, 0, 0);
        a = __builtin_amdgcn_mfma_f32_16x16x32_bf16(hl, c2h[t], a, 0, 0, 0);
        oacc[Mt][t] = a;
      }
    }
  }

  __syncthreads();
  float* red = (float*)smem;
#pragma unroll
  for (int Mt = 0; Mt < 4; ++Mt)
#pragma unroll
    for (int Nt = 0; Nt < 4; ++Nt)
#pragma unroll
      for (int reg = 0; reg < 4; ++reg) {
        const int row = Mt * 16 + (lane >> 4) * 4 + reg;
        const int col = Nt * 16 + (lane & 15);
        red[(w * 64 + row) * 64 + col] = oacc[Mt][Nt][reg];
      }
  __syncthreads();
  {
    const int c4 = (tid & 15) * 4;
    const int rb = tid >> 4;
    const float4 bcv = *(const float4*)(bc + c4);
#pragma unroll
    for (int rr = 0; rr < 4; ++rr) {
      const int r = rr * 16 + rb;
      const int gr = row0 + r;
      if (gr < nrows) {
        float4 s = bcv;
#pragma unroll
        for (int wv = 0; wv < 4; ++wv) {
          const float4 p = *(const float4*)&red[(wv * 64 + r) * 64 + c4];
          s.x += p.x; s.y += p.y; s.z += p.z; s.w += p.w;
        }
        *(float4*)(out + (size_t)gr * 64 + c4) = s;
      }
    }
  }
}

// ---------------------------------------------------------------------------
extern "C" void kernel_launch(void* const* d_in, const int* in_sizes, int n_in,
                              void* d_out, int out_size, void* d_ws, size_t ws_size,
                              hipStream_t stream) {
  const float* x    = (const float*)d_in[0];
  const int*   ei   = (const int*)d_in[1];   // [2][E] int32
  const float* mpW0 = (const float*)d_in[2];
  const float* mpb0 = (const float*)d_in[3];
  const float* mpW1 = (const float*)d_in[4];
  const float* mpb1 = (const float*)d_in[5];
  const float* mpW2 = (const float*)d_in[6];
  const float* mpb2 = (const float*)d_in[7];
  const float* fcW0 = (const float*)d_in[8];
  const float* fcb0 = (const float*)d_in[9];
  const float* fcW1 = (const float*)d_in[10];
  const float* fcb1 = (const float*)d_in[11];
  const float* pW0  = (const float*)d_in[12];
  const float* pb0  = (const float*)d_in[13];
  const float* pW1  = (const float*)d_in[14];
  const float* pb1  = (const float*)d_in[15];
  const float* outW = (const float*)d_in[16];
  const float* outb = (const float*)d_in[17];

  const int N = in_sizes[0] / 128;
  const int E = in_sizes[1] / 2;
  const int NB   = (N + 127) / 128;          // coarse buckets (<=1024)
  const int NBLK = (E + CH - 1) / CH;        // P1/P3 blocks

  char* ws = (char*)d_ws;
  size_t off = 0;
  auto alloc = [&](size_t bytes) -> char* {
    char* p = ws + off;
    off += (bytes + 255) & ~(size_t)255;
    return p;
  };
  float* norm   = (float*)alloc((size_t)N * 4);
  int*   rowptr = (int*)alloc((size_t)(N + 1) * 4);
  int*   bcnt   = (int*)alloc((size_t)NBLK * NB * 4);
  int*   ofs    = (int*)alloc((size_t)NBLK * NB * 4);
  int*   barr   = (int*)alloc((size_t)(NB + 1) * 4);
  int*   ssrc   = (int*)alloc((size_t)E * 4);
  unsigned long long* sorted = (unsigned long long*)alloc((size_t)E * 8);
  _Float16* h2h = (_Float16*)alloc((size_t)N * 128 * 2);
  float* hbuf   = (float*)alloc((size_t)N * 128 * 4);
  float* Wc1    = (float*)alloc(512 * 64 * 4);
  float* Wc2    = (float*)alloc(128 * 64 * 4);
  float* bc     = (float*)alloc(64 * 4);
  unsigned short* FW0h = (unsigned short*)alloc(65536 * 2);
  unsigned short* FW0l = (unsigned short*)alloc(65536 * 2);
  unsigned short* PW0h = (unsigned short*)alloc(65536 * 2);
  unsigned short* PW0l = (unsigned short*)alloc(65536 * 2);
  unsigned short* WC1h = (unsigned short*)alloc(32768 * 2);
  unsigned short* WC1l = (unsigned short*)alloc(32768 * 2);
  unsigned short* WC2h = (unsigned short*)alloc(8192 * 2);
  unsigned short* WC2l = (unsigned short*)alloc(8192 * 2);
  float* bsum   = (float*)alloc(512 * 4);
  unsigned short* M0h = (unsigned short*)alloc(16384 * 2);
  unsigned short* M0l = (unsigned short*)alloc(16384 * 2);
  unsigned short* M1h = (unsigned short*)alloc(16384 * 2);
  unsigned short* M1l = (unsigned short*)alloc(16384 * 2);
  unsigned short* M2h = (unsigned short*)alloc(16384 * 2);
  unsigned short* M2l = (unsigned short*)alloc(16384 * 2);
  // total ~= 105 MiB

  init_kernel<<<(N + 255) / 256, 256, 0, stream>>>(norm, N);
  p1_kernel<<<NBLK, 256, 0, stream>>>(ei, E, NB, bcnt);
  p2_kernel<<<1, 1024, 0, stream>>>(bcnt, ofs, barr, rowptr, NBLK, NB, E, N);
  p3_kernel<<<NBLK, 256, 0, stream>>>(ei, E, NB, ofs, sorted, norm);
  p4_kernel<<<NB, 256, 0, stream>>>(sorted, barr, rowptr, ssrc, N);
  combine_kernel<<<(512 * 64 + 128 * 64 + 64 + 255) / 256, 256, 0, stream>>>(
      fcW1, fcb1, pW1, pb1, outW, outb, Wc1, Wc2, bc);
  convw_kernel<<<(65536 + 32768 + 8192 + 512 + 255) / 256, 256, 0, stream>>>(
      fcW0, pW0, Wc1, Wc2, fcb0, pb0,
      FW0h, FW0l, PW0h, PW0l, WC1h, WC1l, WC2h, WC2l, bsum);
  convmp_kernel<<<(3 * 16384 + 255) / 256, 256, 0, stream>>>(
      mpW0, mpW1, mpW2, M0h, M0l, M1h, M1l, M2h, M2l);

  const int gx = (N + 63) / 64;
  const int ablocks = (N + 15) / 16;   // 4 waves/block, 4 nodes/wave

  // single fp32 h buffer: gemm consumes it fully before agg overwrites it
  mp_gemm_mfma<<<gx, 256, 0, stream>>>(x,    M0h, M0l, mpb0, norm, h2h, N);
  agg_kernel<<<ablocks, 256, 0, stream>>>(h2h, rowptr, ssrc, hbuf, N);
  mp_gemm_mfma<<<gx, 256, 0, stream>>>(hbuf, M1h, M1l, mpb1, norm, h2h, N);
  agg_kernel<<<ablocks, 256, 0, stream>>>(h2h, rowptr, ssrc, hbuf, N);
  mp_gemm_mfma<<<gx, 256, 0, stream>>>(hbuf, M2h, M2l, mpb2, norm, h2h, N);
  agg_kernel<<<ablocks, 256, 0, stream>>>(h2h, rowptr, ssrc, hbuf, N);

  fused_out_mfma<<<gx, 256, 0, stream>>>(
      hbuf, FW0h, FW0l, PW0h, PW0l, WC1h, WC1l, WC2h, WC2l, bsum, bc,
      (float*)d_out, N);
}

// Round 10
// 553.855 us; speedup vs baseline: 19.9142x; 1.1789x over previous
//
#include <hip/hip_runtime.h>

// DecoupleModel: 3x GIN MP layers (split-bf16 MFMA) + CSR-gather aggregation
// + fused output MLP (split-bf16 MFMA).
// R10: norm via src-binned count (NO random global atomics anywhere);
//      CH=8192 (2x blocks); parallel wave-per-bucket scans replace p2.

typedef __attribute__((ext_vector_type(8))) short short8;
typedef __attribute__((ext_vector_type(4))) float f32x4;
typedef __attribute__((ext_vector_type(8))) _Float16 h16x8;
typedef __attribute__((ext_vector_type(4))) _Float16 h16x4;

constexpr float SQRT2   = 1.41421356237309515f;
constexpr float ONE_EPS = 1.0f + SQRT2;          // (1 + eps)
constexpr float RS      = 0.08838834764831845f;  // 1/sqrt(128)
constexpr int   CH      = 8192;                  // edges per P1/P3 block

__device__ inline unsigned short bf16rne(float f) {
  unsigned int u = __float_as_uint(f);
  return (unsigned short)((u + 0x7FFFu + ((u >> 16) & 1u)) >> 16);
}
__device__ inline float bf16tof(unsigned short h) {
  return __uint_as_float(((unsigned int)h) << 16);
}

// ---------------- graph preprocessing --------------------------------------
// P1: per-block coarse histograms of tgt>>7 AND src>>7; layout [bucket][block]
__global__ __launch_bounds__(256) void p1_kernel(
    const int* __restrict__ ei, int E, int NB, int NBLK,
    int* __restrict__ bcnt_t, int* __restrict__ bcnt_s) {
  __shared__ int cb[1024], cb2[1024];
  for (int i = threadIdx.x; i < 1024; i += 256) { cb[i] = 0; cb2[i] = 0; }
  __syncthreads();
  const int base = blockIdx.x * CH;
#pragma unroll 4
  for (int it = 0; it < CH / 256; ++it) {
    const int e = base + it * 256 + threadIdx.x;
    if (e < E) {
      atomicAdd(&cb[ei[e] >> 7], 1);
      atomicAdd(&cb2[ei[E + e] >> 7], 1);
    }
  }
  __syncthreads();
  for (int i = threadIdx.x; i < NB; i += 256) {
    bcnt_t[(size_t)i * NBLK + blockIdx.x] = cb[i];
    bcnt_s[(size_t)i * NBLK + blockIdx.x] = cb2[i];
  }
}

// per-bucket totals (wave per bucket, coalesced reads of [bucket][block])
__global__ __launch_bounds__(256) void scan_tot(
    const int* __restrict__ bcnt, int* __restrict__ tot, int NBLK, int NB) {
  const int wid = blockIdx.x * 4 + (threadIdx.x >> 6);
  const int lane = threadIdx.x & 63;
  if (wid >= NB) return;
  int s = 0;
  for (int b = lane; b < NBLK; b += 64) s += bcnt[(size_t)wid * NBLK + b];
  for (int o = 32; o > 0; o >>= 1) s += __shfl_down(s, o);
  if (lane == 0) tot[wid] = s;
}

// exclusive scan of tot -> barr (single small block; NB <= 1024)
__global__ __launch_bounds__(1024) void scan_base(
    const int* __restrict__ tot, int* __restrict__ barr, int NB, int E,
    int* __restrict__ rowptr, int N) {
  __shared__ int sh[1024];
  const int t = threadIdx.x;
  const int v = (t < NB) ? tot[t] : 0;
  sh[t] = v;
  __syncthreads();
  for (int o = 1; o < 1024; o <<= 1) {
    int u = (t >= o) ? sh[t - o] : 0;
    __syncthreads();
    sh[t] += u;
    __syncthreads();
  }
  if (t < NB) barr[t] = sh[t] - v;
  if (t == 0) { barr[NB] = E; if (rowptr) rowptr[N] = E; }
}

// per-(bucket,block) offsets: wave-scan over NBLK per bucket
__global__ __launch_bounds__(256) void scan_ofs(
    const int* __restrict__ bcnt, const int* __restrict__ barr,
    int* __restrict__ ofs, int NBLK, int NB) {
  const int wid = blockIdx.x * 4 + (threadIdx.x >> 6);
  const int lane = threadIdx.x & 63;
  if (wid >= NB) return;
  int run = barr[wid];
  for (int c0 = 0; c0 < NBLK; c0 += 64) {
    const int idx = c0 + lane;
    const int v = (idx < NBLK) ? bcnt[(size_t)wid * NBLK + idx] : 0;
    int incl = v;
#pragma unroll
    for (int o = 1; o < 64; o <<= 1) {
      int u = __shfl_up(incl, o);
      if (lane >= o) incl += u;
    }
    if (idx < NBLK) ofs[(size_t)wid * NBLK + idx] = run + incl - v;
    run += __shfl(incl, 63);
  }
}

// P3: scatter (tgt,src) into tgt-bucket sorted[]; src into src-bucket ssbin[]
__global__ __launch_bounds__(256) void p3_kernel(
    const int* __restrict__ ei, int E, int NB, int NBLK,
    const int* __restrict__ ofs_t, const int* __restrict__ ofs_s,
    unsigned long long* __restrict__ sorted, int* __restrict__ ssbin) {
  __shared__ int cur[1024], cur2[1024];
  for (int i = threadIdx.x; i < NB; i += 256) {
    cur[i]  = ofs_t[(size_t)i * NBLK + blockIdx.x];
    cur2[i] = ofs_s[(size_t)i * NBLK + blockIdx.x];
  }
  __syncthreads();
  const int base = blockIdx.x * CH;
  for (int it = 0; it < CH / 256; ++it) {
    const int e = base + it * 256 + threadIdx.x;
    if (e < E) {
      const int tgt = ei[e], src = ei[E + e];
      const int pos = atomicAdd(&cur[tgt >> 7], 1);
      sorted[pos] = ((unsigned long long)(unsigned)tgt << 32) | (unsigned)src;
      const int pos2 = atomicAdd(&cur2[src >> 7], 1);
      ssbin[pos2] = src;
    }
  }
}

// P4: per tgt-bucket (128 nodes): fine hist -> rowptr, then scatter ssrc
__global__ __launch_bounds__(256) void p4_kernel(
    const unsigned long long* __restrict__ sorted, const int* __restrict__ barr,
    int* __restrict__ rowptr, int* __restrict__ ssrc, int N) {
  __shared__ int fcnt[128], fcur[128], sh[128];
  const int B = blockIdx.x, t = threadIdx.x;
  const int lo = barr[B], hi = barr[B + 1];
  if (t < 128) fcnt[t] = 0;
  __syncthreads();
  for (int i = lo + t; i < hi; i += 256)
    atomicAdd(&fcnt[(int)(sorted[i] >> 32) & 127], 1);
  __syncthreads();
  if (t < 128) sh[t] = fcnt[t];
  __syncthreads();
  for (int o = 1; o < 128; o <<= 1) {
    int v = 0;
    if (t < 128 && t >= o) v = sh[t - o];
    __syncthreads();
    if (t < 128) sh[t] += v;
    __syncthreads();
  }
  if (t < 128) {
    const int base = lo + sh[t] - fcnt[t];   // exclusive
    fcur[t] = base;
    const int node = B * 128 + t;
    if (node < N) rowptr[node] = base;
  }
  __syncthreads();
  for (int i = lo + t; i < hi; i += 256) {
    const unsigned long long p = sorted[i];
    const int pos = atomicAdd(&fcur[(int)(p >> 32) & 127], 1);
    ssrc[pos] = (int)(unsigned)(p & 0xffffffffu);
  }
}

// P4b: per src-bucket: fine count -> norm = 1+eps+deg (exact, no global RMW)
__global__ __launch_bounds__(256) void p4b_kernel(
    const int* __restrict__ ssbin, const int* __restrict__ barr_s,
    float* __restrict__ norm, int N) {
  __shared__ int fcnt[128];
  const int B = blockIdx.x, t = threadIdx.x;
  const int lo = barr_s[B], hi = barr_s[B + 1];
  if (t < 128) fcnt[t] = 0;
  __syncthreads();
  for (int i = lo + t; i < hi; i += 256)
    atomicAdd(&fcnt[ssbin[i] & 127], 1);
  __syncthreads();
  if (t < 128) {
    const int node = B * 128 + t;
    if (node < N) norm[node] = ONE_EPS + (float)fcnt[t];
  }
}

// ---------------- weight folding (unchanged, verified) ---------------------
__global__ void combine_kernel(const float* __restrict__ fcW1, const float* __restrict__ fcb1,
                               const float* __restrict__ pW1,  const float* __restrict__ pb1,
                               const float* __restrict__ outW, const float* __restrict__ outb,
                               float* __restrict__ Wc1, float* __restrict__ Wc2,
                               float* __restrict__ bc) {
  int gid = blockIdx.x * blockDim.x + threadIdx.x;
  if (gid < 512 * 64) {
    int k = gid >> 6, j = gid & 63;
    float s = 0.f;
    for (int m = 0; m < 512; ++m) s = fmaf(fcW1[k * 512 + m], outW[m * 64 + j], s);
    Wc1[gid] = s;
  } else if (gid < 512 * 64 + 128 * 64) {
    int t = gid - 512 * 64, k = t >> 6, j = t & 63;
    float s = 0.f;
    for (int m = 0; m < 512; ++m) s = fmaf(pW1[k * 512 + m], outW[m * 64 + j], s);
    Wc2[t] = s;
  } else if (gid < 512 * 64 + 128 * 64 + 64) {
    int j = gid - (512 * 64 + 128 * 64);
    float s = outb[j];
    for (int m = 0; m < 512; ++m) s = fmaf(fcb1[m] + pb1[m], outW[m * 64 + j], s);
    bc[j] = s;
  }
}

__global__ void convw_kernel(const float* __restrict__ fcW0, const float* __restrict__ pW0,
                             const float* __restrict__ Wc1,  const float* __restrict__ Wc2,
                             const float* __restrict__ fcb0, const float* __restrict__ pb0,
                             unsigned short* __restrict__ FW0h, unsigned short* __restrict__ FW0l,
                             unsigned short* __restrict__ PW0h, unsigned short* __restrict__ PW0l,
                             unsigned short* __restrict__ WC1h, unsigned short* __restrict__ WC1l,
                             unsigned short* __restrict__ WC2h, unsigned short* __restrict__ WC2l,
                             float* __restrict__ bsum) {
  int gid = blockIdx.x * blockDim.x + threadIdx.x;
  if (gid < 65536) {
    int e = gid & 7, c = (gid >> 3) & 15, kg = (gid >> 7) & 3, s = (gid >> 9) & 3, t = gid >> 11;
    int k = s * 32 + kg * 8 + e, n = t * 16 + c;
    float f = fcW0[k * 512 + n];
    unsigned short h = bf16rne(f);
    FW0h[gid] = h; FW0l[gid] = bf16rne(f - bf16tof(h));
    f = pW0[k * 512 + n];
    h = bf16rne(f);
    PW0h[gid] = h; PW0l[gid] = bf16rne(f - bf16tof(h));
  } else if (gid < 65536 + 32768) {
    int g = gid - 65536;
    int e = g & 7, c = (g >> 3) & 15, kg = (g >> 7) & 3, s = (g >> 9) & 15, t = g >> 13;
    int k = s * 32 + kg * 8 + e, n = t * 16 + c;
    float f = Wc1[k * 64 + n];
    unsigned short h = bf16rne(f);
    WC1h[g] = h; WC1l[g] = bf16rne(f - bf16tof(h));
  } else if (gid < 65536 + 32768 + 8192) {
    int g = gid - 98304;
    int e = g & 7, c = (g >> 3) & 15, kg = (g >> 7) & 3, s = (g >> 9) & 3, t = (g >> 11) & 3;
    int k = s * 32 + kg * 8 + e, n = t * 16 + c;
    float f = Wc2[k * 64 + n];
    unsigned short h = bf16rne(f);
    WC2h[g] = h; WC2l[g] = bf16rne(f - bf16tof(h));
  } else if (gid < 65536 + 32768 + 8192 + 512) {
    int j = gid - 106496;
    bsum[j] = fcb0[j] + pb0[j];
  }
}

__global__ void convmp_kernel(const float* __restrict__ W0, const float* __restrict__ W1,
                              const float* __restrict__ W2,
                              unsigned short* __restrict__ M0h, unsigned short* __restrict__ M0l,
                              unsigned short* __restrict__ M1h, unsigned short* __restrict__ M1l,
                              unsigned short* __restrict__ M2h, unsigned short* __restrict__ M2l) {
  int gid = blockIdx.x * blockDim.x + threadIdx.x;
  if (gid >= 3 * 16384) return;
  const int m = gid >> 14, g = gid & 16383;
  int e = g & 7, c = (g >> 3) & 15, kg = (g >> 7) & 3, s = (g >> 9) & 3, t = g >> 11;
  int k = s * 32 + kg * 8 + e, n = t * 16 + c;
  const float* W = (m == 0) ? W0 : (m == 1) ? W1 : W2;
  unsigned short* Mh = (m == 0) ? M0h : (m == 1) ? M1h : M2h;
  unsigned short* Ml = (m == 0) ? M0l : (m == 1) ? M1l : M2l;
  float f = W[k * 128 + n];
  unsigned short h = bf16rne(f);
  Mh[g] = h; Ml[g] = bf16rne(f - bf16tof(h));
}

// ---------------- MP layer GEMM, split-bf16 MFMA (verified R5/R9) ----------
__global__ __launch_bounds__(256) void mp_gemm_mfma(
    const float* __restrict__ A,
    const unsigned short* __restrict__ Wh, const unsigned short* __restrict__ Wl,
    const float* __restrict__ bias, const float* __restrict__ norm,
    _Float16* __restrict__ h2h, int nrows)
{
  __shared__ __attribute__((aligned(16))) char smem[33792];
  const int tid  = threadIdx.x;
  const int row0 = blockIdx.x * 64;

  {
    const int m = tid >> 2, q = tid & 3;
    const int gr = row0 + m;
    const int Mt = m >> 4, r16 = m & 15;
#pragma unroll
    for (int it = 0; it < 8; ++it) {
      const int k = it * 16 + q * 4;
      float4 v = make_float4(0.f, 0.f, 0.f, 0.f);
      if (gr < nrows) v = *(const float4*)(A + (size_t)gr * 128 + k);
      const unsigned short h0 = bf16rne(v.x), h1 = bf16rne(v.y);
      const unsigned short h2v = bf16rne(v.z), h3 = bf16rne(v.w);
      const unsigned short l0 = bf16rne(v.x - bf16tof(h0));
      const unsigned short l1 = bf16rne(v.y - bf16tof(h1));
      const unsigned short l2 = bf16rne(v.z - bf16tof(h2v));
      const unsigned short l3 = bf16rne(v.w - bf16tof(h3));
      const int k3 = it * 2 + (q >> 1);
      const int kg = k3 & 3, ks = k3 >> 2;
      const int eb = (q & 1) * 8;
      const int fb = ((Mt * 4 + ks) * 64 + kg * 16 + r16) * 16 + eb;
      *(uint2*)(smem + fb) =
          make_uint2((unsigned)h0 | ((unsigned)h1 << 16), (unsigned)h2v | ((unsigned)h3 << 16));
      *(uint2*)(smem + 16384 + fb) =
          make_uint2((unsigned)l0 | ((unsigned)l1 << 16), (unsigned)l2 | ((unsigned)l3 << 16));
    }
  }
  __syncthreads();

  const int w = tid >> 6, lane = tid & 63;
  f32x4 acc[4][2] = {};

#pragma unroll
  for (int ks = 0; ks < 4; ++ks) {
    short8 bh[2], bl[2];
#pragma unroll
    for (int nt = 0; nt < 2; ++nt) {
      const int t = w * 2 + nt;
      const size_t ofs = (size_t)(t * 4 + ks) * 512 + lane * 8;
      bh[nt] = *(const short8*)(Wh + ofs);
      bl[nt] = *(const short8*)(Wl + ofs);
    }
#pragma unroll
    for (int Mt = 0; Mt < 4; ++Mt) {
      const int fb = ((Mt * 4 + ks) * 64 + lane) * 16;
      short8 hh = *(const short8*)(smem + fb);
      short8 hl = *(const short8*)(smem + 16384 + fb);
#pragma unroll
      for (int nt = 0; nt < 2; ++nt) {
        f32x4 a = acc[Mt][nt];
        a = __builtin_amdgcn_mfma_f32_16x16x32_bf16(hh, bh[nt], a, 0, 0, 0);
        a = __builtin_amdgcn_mfma_f32_16x16x32_bf16(hh, bl[nt], a, 0, 0, 0);
        a = __builtin_amdgcn_mfma_f32_16x16x32_bf16(hl, bh[nt], a, 0, 0, 0);
        acc[Mt][nt] = a;
      }
    }
  }

  __syncthreads();
  float* ob = (float*)smem;
#pragma unroll
  for (int Mt = 0; Mt < 4; ++Mt)
#pragma unroll
    for (int nt = 0; nt < 2; ++nt) {
      const int col = w * 32 + nt * 16 + (lane & 15);
#pragma unroll
      for (int reg = 0; reg < 4; ++reg) {
        const int row = Mt * 16 + (lane >> 4) * 4 + reg;
        ob[row * 132 + col] = acc[Mt][nt][reg];
      }
    }
  __syncthreads();
  {
    const int r = tid >> 2;
    const int gr = row0 + r;
    if (gr < nrows) {
      const float sc = RS / norm[gr];
      const int cb = (tid & 3) * 32;
#pragma unroll
      for (int j = 0; j < 32; j += 4) {
        float4 v = *(const float4*)&ob[r * 132 + cb + j];
        const float4 b = *(const float4*)&bias[cb + j];
        h16x4 pk;
        pk[0] = (_Float16)(fmaxf(v.x + b.x, 0.f) * sc);
        pk[1] = (_Float16)(fmaxf(v.y + b.y, 0.f) * sc);
        pk[2] = (_Float16)(fmaxf(v.z + b.z, 0.f) * sc);
        pk[3] = (_Float16)(fmaxf(v.w + b.w, 0.f) * sc);
        *(h16x4*)(h2h + (size_t)gr * 128 + cb + j) = pk;
      }
    }
  }
}

// out[t] = (1+eps)*h2[t] + sum_{e in CSR[t]} h2[src[e]]   (fp16 gather, fp32 acc)
__global__ __launch_bounds__(256) void agg_kernel(
    const _Float16* __restrict__ h2h, const int* __restrict__ rowptr,
    const int* __restrict__ ssrc, float* __restrict__ out, int N)
{
  const int wv   = (blockIdx.x * 256 + threadIdx.x) >> 6;
  const int lane = threadIdx.x & 63;
  const int node = wv * 4 + (lane >> 4);
  const int col  = (lane & 15) * 8;
  if (node >= N) return;
  float acc[8];
  {
    const h16x8 sv = *(const h16x8*)(h2h + (size_t)node * 128 + col);
#pragma unroll
    for (int j = 0; j < 8; ++j) acc[j] = ONE_EPS * (float)sv[j];
  }
  const int beg = rowptr[node], end = rowptr[node + 1];
  int i = beg;
  for (; i + 1 < end; i += 2) {
    const int s0 = ssrc[i], s1 = ssrc[i + 1];
    const h16x8 v0 = *(const h16x8*)(h2h + (size_t)s0 * 128 + col);
    const h16x8 v1 = *(const h16x8*)(h2h + (size_t)s1 * 128 + col);
#pragma unroll
    for (int j = 0; j < 8; ++j) acc[j] += (float)v0[j] + (float)v1[j];
  }
  if (i < end) {
    const int s = ssrc[i];
    const h16x8 v = *(const h16x8*)(h2h + (size_t)s * 128 + col);
#pragma unroll
    for (int j = 0; j < 8; ++j) acc[j] += (float)v[j];
  }
  f32x4 o0 = {acc[0], acc[1], acc[2], acc[3]};
  f32x4 o1 = {acc[4], acc[5], acc[6], acc[7]};
  __builtin_nontemporal_store(o0, (f32x4*)(out + (size_t)node * 128 + col));
  __builtin_nontemporal_store(o1, (f32x4*)(out + (size_t)node * 128 + col + 4));
}

// ---------------- fused output MLP, split-bf16 MFMA (verified R4) ----------
__global__ __launch_bounds__(256) void fused_out_mfma(
    const float* __restrict__ h,
    const unsigned short* __restrict__ FW0h, const unsigned short* __restrict__ FW0l,
    const unsigned short* __restrict__ PW0h, const unsigned short* __restrict__ PW0l,
    const unsigned short* __restrict__ WC1h, const unsigned short* __restrict__ WC1l,
    const unsigned short* __restrict__ WC2h, const unsigned short* __restrict__ WC2l,
    const float* __restrict__ bsum, const float* __restrict__ bc,
    float* __restrict__ out, int nrows)
{
  __shared__ __attribute__((aligned(16))) char smem[65536];
  const int tid  = threadIdx.x;
  const int row0 = blockIdx.x * 64;

  {
    const int m = tid >> 2, q = tid & 3;
    const int gr = row0 + m;
    const int Mt = m >> 4, r16 = m & 15;
#pragma unroll
    for (int it = 0; it < 8; ++it) {
      const int k  = it * 16 + q * 4;
      float4 v = make_float4(0.f, 0.f, 0.f, 0.f);
      if (gr < nrows) v = *(const float4*)(h + (size_t)gr * 128 + k);
      const unsigned short h0 = bf16rne(v.x), h1 = bf16rne(v.y);
      const unsigned short h2 = bf16rne(v.z), h3 = bf16rne(v.w);
      const unsigned short l0 = bf16rne(v.x - bf16tof(h0));
      const unsigned short l1 = bf16rne(v.y - bf16tof(h1));
      const unsigned short l2 = bf16rne(v.z - bf16tof(h2));
      const unsigned short l3 = bf16rne(v.w - bf16tof(h3));
      const int k3 = it * 2 + (q >> 1);
      const int kg = k3 & 3, ks = k3 >> 2;
      const int eb = (q & 1) * 8;
      const int fb = ((Mt * 4 + ks) * 64 + kg * 16 + r16) * 16 + eb;
      *(uint2*)(smem + fb) =
          make_uint2((unsigned)h0 | ((unsigned)h1 << 16), (unsigned)h2 | ((unsigned)h3 << 16));
      *(uint2*)(smem + 16384 + fb) =
          make_uint2((unsigned)l0 | ((unsigned)l1 << 16), (unsigned)l2 | ((unsigned)l3 << 16));
    }
  }
  __syncthreads();

  const int w = tid >> 6, lane = tid & 63;
  union U8 { short8 s; unsigned int u[4]; };

  f32x4 oacc[4][4] = {};

  for (int sc = 0; sc < 4; ++sc) {
    f32x4 zacc[4][2] = {};
#pragma unroll
    for (int ks = 0; ks < 4; ++ks) {
      short8 w0h[2], w0l[2], p0h[2], p0l[2];
#pragma unroll
      for (int nt = 0; nt < 2; ++nt) {
        const int t = w * 8 + sc * 2 + nt;
        const size_t ofs = (size_t)(t * 4 + ks) * 512 + lane * 8;
        w0h[nt] = *(const short8*)(FW0h + ofs);
        w0l[nt] = *(const short8*)(FW0l + ofs);
        p0h[nt] = *(const short8*)(PW0h + ofs);
        p0l[nt] = *(const short8*)(PW0l + ofs);
      }
#pragma unroll
      for (int Mt = 0; Mt < 4; ++Mt) {
        const int fb = ((Mt * 4 + ks) * 64 + lane) * 16;
        U8 hh, hl, rh, rl;
        hh.s = *(const short8*)(smem + fb);
        hl.s = *(const short8*)(smem + 16384 + fb);
#pragma unroll
        for (int u = 0; u < 4; ++u) {
          unsigned int msk = ((hh.u[u] & 0x80008000u) >> 15) * 0xFFFFu;
          rh.u[u] = hh.u[u] & ~msk;
          rl.u[u] = hl.u[u] & ~msk;
        }
#pragma unroll
        for (int nt = 0; nt < 2; ++nt) {
          f32x4 a = zacc[Mt][nt];
          a = __builtin_amdgcn_mfma_f32_16x16x32_bf16(rh.s, w0h[nt], a, 0, 0, 0);
          a = __builtin_amdgcn_mfma_f32_16x16x32_bf16(rh.s, w0l[nt], a, 0, 0, 0);
          a = __builtin_amdgcn_mfma_f32_16x16x32_bf16(rl.s, w0h[nt], a, 0, 0, 0);
          a = __builtin_amdgcn_mfma_f32_16x16x32_bf16(hh.s, p0h[nt], a, 0, 0, 0);
          a = __builtin_amdgcn_mfma_f32_16x16x32_bf16(hh.s, p0l[nt], a, 0, 0, 0);
          a = __builtin_amdgcn_mfma_f32_16x16x32_bf16(hl.s, p0h[nt], a, 0, 0, 0);
          zacc[Mt][nt] = a;
        }
      }
    }
    const float bs0 = bsum[w * 128 + sc * 32 + (lane & 15)];
    const float bs1 = bsum[w * 128 + sc * 32 + 16 + (lane & 15)];
#pragma unroll
    for (int Mt = 0; Mt < 4; ++Mt) {
#pragma unroll
      for (int nt = 0; nt < 2; ++nt) {
        const float bs = nt ? bs1 : bs0;
        const int kg = nt * 2 + ((lane >> 3) & 1);
        const int eb = (lane & 7) * 2;
#pragma unroll
        for (int reg = 0; reg < 4; ++reg) {
          const float zv = fmaxf(zacc[Mt][nt][reg] + bs, 0.f);
          const unsigned short zhi = bf16rne(zv);
          const unsigned short zlo = bf16rne(zv - bf16tof(zhi));
          const int r16 = (lane >> 4) * 4 + reg;
          const int fb = ((w * 4 + Mt) * 64 + kg * 16 + r16) * 16 + eb;
          *(unsigned short*)(smem + 32768 + fb) = zhi;
          *(unsigned short*)(smem + 49152 + fb) = zlo;
        }
      }
    }
    asm volatile("s_waitcnt lgkmcnt(0)" ::: "memory");
    const int s2 = w * 4 + sc;
    short8 c1h[4], c1l[4];
#pragma unroll
    for (int t2 = 0; t2 < 4; ++t2) {
      const size_t ofs = (size_t)(t2 * 16 + s2) * 512 + lane * 8;
      c1h[t2] = *(const short8*)(WC1h + ofs);
      c1l[t2] = *(const short8*)(WC1l + ofs);
    }
#pragma unroll
    for (int Mt = 0; Mt < 4; ++Mt) {
      const int fb = ((w * 4 + Mt) * 64 + lane) * 16;
      short8 zh8 = *(const short8*)(smem + 32768 + fb);
      short8 zl8 = *(const short8*)(smem + 49152 + fb);
#pragma unroll
      for (int t2 = 0; t2 < 4; ++t2) {
        f32x4 a = oacc[Mt][t2];
        a = __builtin_amdgcn_mfma_f32_16x16x32_bf16(zh8, c1h[t2], a, 0, 0, 0);
        a = __builtin_amdgcn_mfma_f32_16x16x32_bf16(zh8, c1l[t2], a, 0, 0, 0);
        a = __builtin_amdgcn_mfma_f32_16x16x32_bf16(zl8, c1h[t2], a, 0, 0, 0);
        oacc[Mt][t2] = a;
      }
    }
  }

  {
    short8 c2h[4], c2l[4];
#pragma unroll
    for (int t = 0; t < 4; ++t) {
      const size_t ofs = (size_t)(t * 4 + w) * 512 + lane * 8;
      c2h[t] = *(const short8*)(WC2h + ofs);
      c2l[t] = *(const short8*)(WC2l + ofs);
    }
#pragma unroll
    for (int Mt = 0; Mt < 4; ++Mt) {
      const int fb = ((Mt * 4 + w) * 64 + lane) * 16;
      short8 hh = *(const short8*)(smem + fb);
      short8 hl = *(const short8*)(smem + 16384 + fb);
#pragma unroll
      for (int t = 0; t < 4; ++t) {
        f32x4 a = oacc[Mt][t];
        a = __builtin_amdgcn_mfma_f32_16x16x32_bf16(hh, c2h[t], a, 0, 0, 0);
        a = __builtin_amdgcn_mfma_f32_16x16x32_bf16(hh, c2l[t], a, 0, 0, 0);
        a = __builtin_amdgcn_mfma_f32_16x16x32_bf16(hl, c2h[t], a, 0, 0, 0);
        oacc[Mt][t] = a;
      }
    }
  }

  __syncthreads();
  float* red = (float*)smem;
#pragma unroll
  for (int Mt = 0; Mt < 4; ++Mt)
#pragma unroll
    for (int Nt = 0; Nt < 4; ++Nt)
#pragma unroll
      for (int reg = 0; reg < 4; ++reg) {
        const int row = Mt * 16 + (lane >> 4) * 4 + reg;
        const int col = Nt * 16 + (lane & 15);
        red[(w * 64 + row) * 64 + col] = oacc[Mt][Nt][reg];
      }
  __syncthreads();
  {
    const int c4 = (tid & 15) * 4;
    const int rb = tid >> 4;
    const float4 bcv = *(const float4*)(bc + c4);
#pragma unroll
    for (int rr = 0; rr < 4; ++rr) {
      const int r = rr * 16 + rb;
      const int gr = row0 + r;
      if (gr < nrows) {
        float4 s = bcv;
#pragma unroll
        for (int wv = 0; wv < 4; ++wv) {
          const float4 p = *(const float4*)&red[(wv * 64 + r) * 64 + c4];
          s.x += p.x; s.y += p.y; s.z += p.z; s.w += p.w;
        }
        *(float4*)(out + (size_t)gr * 64 + c4) = s;
      }
    }
  }
}

// ---------------------------------------------------------------------------
extern "C" void kernel_launch(void* const* d_in, const int* in_sizes, int n_in,
                              void* d_out, int out_size, void* d_ws, size_t ws_size,
                              hipStream_t stream) {
  const float* x    = (const float*)d_in[0];
  const int*   ei   = (const int*)d_in[1];   // [2][E] int32
  const float* mpW0 = (const float*)d_in[2];
  const float* mpb0 = (const float*)d_in[3];
  const float* mpW1 = (const float*)d_in[4];
  const float* mpb1 = (const float*)d_in[5];
  const float* mpW2 = (const float*)d_in[6];
  const float* mpb2 = (const float*)d_in[7];
  const float* fcW0 = (const float*)d_in[8];
  const float* fcb0 = (const float*)d_in[9];
  const float* fcW1 = (const float*)d_in[10];
  const float* fcb1 = (const float*)d_in[11];
  const float* pW0  = (const float*)d_in[12];
  const float* pb0  = (const float*)d_in[13];
  const float* pW1  = (const float*)d_in[14];
  const float* pb1  = (const float*)d_in[15];
  const float* outW = (const float*)d_in[16];
  const float* outb = (const float*)d_in[17];

  const int N = in_sizes[0] / 128;
  const int E = in_sizes[1] / 2;
  const int NB   = (N + 127) / 128;          // coarse buckets (<=1024)
  const int NBLK = (E + CH - 1) / CH;        // P1/P3 blocks

  char* ws = (char*)d_ws;
  size_t off = 0;
  auto alloc = [&](size_t bytes) -> char* {
    char* p = ws + off;
    off += (bytes + 255) & ~(size_t)255;
    return p;
  };
  float* norm   = (float*)alloc((size_t)N * 4);
  int*   rowptr = (int*)alloc((size_t)(N + 1) * 4);
  int*   bcnt_t = (int*)alloc((size_t)NB * NBLK * 4);
  int*   bcnt_s = (int*)alloc((size_t)NB * NBLK * 4);
  int*   ofs_t  = (int*)alloc((size_t)NB * NBLK * 4);
  int*   ofs_s  = (int*)alloc((size_t)NB * NBLK * 4);
  int*   tot_t  = (int*)alloc((size_t)NB * 4);
  int*   tot_s  = (int*)alloc((size_t)NB * 4);
  int*   barr_t = (int*)alloc((size_t)(NB + 1) * 4);
  int*   barr_s = (int*)alloc((size_t)(NB + 1) * 4);
  int*   ssrc   = (int*)alloc((size_t)E * 4);
  int*   ssbin  = (int*)alloc((size_t)E * 4);
  unsigned long long* sorted = (unsigned long long*)alloc((size_t)E * 8);
  _Float16* h2h = (_Float16*)alloc((size_t)N * 128 * 2);
  float* hbuf   = (float*)alloc((size_t)N * 128 * 4);
  float* Wc1    = (float*)alloc(512 * 64 * 4);
  float* Wc2    = (float*)alloc(128 * 64 * 4);
  float* bc     = (float*)alloc(64 * 4);
  unsigned short* FW0h = (unsigned short*)alloc(65536 * 2);
  unsigned short* FW0l = (unsigned short*)alloc(65536 * 2);
  unsigned short* PW0h = (unsigned short*)alloc(65536 * 2);
  unsigned short* PW0l = (unsigned short*)alloc(65536 * 2);
  unsigned short* WC1h = (unsigned short*)alloc(32768 * 2);
  unsigned short* WC1l = (unsigned short*)alloc(32768 * 2);
  unsigned short* WC2h = (unsigned short*)alloc(8192 * 2);
  unsigned short* WC2l = (unsigned short*)alloc(8192 * 2);
  float* bsum   = (float*)alloc(512 * 4);
  unsigned short* M0h = (unsigned short*)alloc(16384 * 2);
  unsigned short* M0l = (unsigned short*)alloc(16384 * 2);
  unsigned short* M1h = (unsigned short*)alloc(16384 * 2);
  unsigned short* M1l = (unsigned short*)alloc(16384 * 2);
  unsigned short* M2h = (unsigned short*)alloc(16384 * 2);
  unsigned short* M2l = (unsigned short*)alloc(16384 * 2);
  // total ~= 120 MiB

  const int scblocks = (NB + 3) / 4;

  p1_kernel<<<NBLK, 256, 0, stream>>>(ei, E, NB, NBLK, bcnt_t, bcnt_s);
  scan_tot<<<scblocks, 256, 0, stream>>>(bcnt_t, tot_t, NBLK, NB);
  scan_tot<<<scblocks, 256, 0, stream>>>(bcnt_s, tot_s, NBLK, NB);
  scan_base<<<1, 1024, 0, stream>>>(tot_t, barr_t, NB, E, rowptr, N);
  scan_base<<<1, 1024, 0, stream>>>(tot_s, barr_s, NB, E, nullptr, 0);
  scan_ofs<<<scblocks, 256, 0, stream>>>(bcnt_t, barr_t, ofs_t, NBLK, NB);
  scan_ofs<<<scblocks, 256, 0, stream>>>(bcnt_s, barr_s, ofs_s, NBLK, NB);
  p3_kernel<<<NBLK, 256, 0, stream>>>(ei, E, NB, NBLK, ofs_t, ofs_s, sorted, ssbin);
  p4_kernel<<<NB, 256, 0, stream>>>(sorted, barr_t, rowptr, ssrc, N);
  p4b_kernel<<<NB, 256, 0, stream>>>(ssbin, barr_s, norm, N);
  combine_kernel<<<(512 * 64 + 128 * 64 + 64 + 255) / 256, 256, 0, stream>>>(
      fcW1, fcb1, pW1, pb1, outW, outb, Wc1, Wc2, bc);
  convw_kernel<<<(65536 + 32768 + 8192 + 512 + 255) / 256, 256, 0, stream>>>(
      fcW0, pW0, Wc1, Wc2, fcb0, pb0,
      FW0h, FW0l, PW0h, PW0l, WC1h, WC1l, WC2h, WC2l, bsum);
  convmp_kernel<<<(3 * 16384 + 255) / 256, 256, 0, stream>>>(
      mpW0, mpW1, mpW2, M0h, M0l, M1h, M1l, M2h, M2l);

  const int gx = (N + 63) / 64;
  const int ablocks = (N + 15) / 16;   // 4 waves/block, 4 nodes/wave

  mp_gemm_mfma<<<gx, 256, 0, stream>>>(x,    M0h, M0l, mpb0, norm, h2h, N);
  agg_kernel<<<ablocks, 256, 0, stream>>>(h2h, rowptr, ssrc, hbuf, N);
  mp_gemm_mfma<<<gx, 256, 0, stream>>>(hbuf, M1h, M1l, mpb1, norm, h2h, N);
  agg_kernel<<<ablocks, 256, 0, stream>>>(h2h, rowptr, ssrc, hbuf, N);
  mp_gemm_mfma<<<gx, 256, 0, stream>>>(hbuf, M2h, M2l, mpb2, norm, h2h, N);
  agg_kernel<<<ablocks, 256, 0, stream>>>(h2h, rowptr, ssrc, hbuf, N);

  fused_out_mfma<<<gx, 256, 0, stream>>>(
      hbuf, FW0h, FW0l, PW0h, PW0l, WC1h, WC1l, WC2h, WC2l, bsum, bc,
      (float*)d_out, N);
}